// Round 1
// baseline (7380.505 us; speedup 1.0000x reference)
//
#include <hip/hip_runtime.h>
#include <math.h>

// BiMambaEncoder: 8-layer bidirectional Mamba2 stack, fp32, correctness-first.
// B=4, L=2048, D_MODEL=256, D_INNER=512, NHEADS=16, HEADDIM=32, D_STATE=64,
// CONV_DIM=640, D_IN_PROJ=1168, CHUNK=64 (K=32 chunks).

namespace {

constexpr int kL = 2048;
constexpr int kDM = 256;
constexpr int kDI = 512;
constexpr int kNH = 16;
constexpr int kDS = 64;
constexpr int kCDIM = 640;
constexpr int kDPROJ = 1168;
constexpr int kCH = 64;       // chunk length
constexpr int kKC = 32;       // number of chunks
constexpr int kBB = 8;        // combined batch: 4 fwd + 4 bwd
constexpr int kRowsD = 4 * kL;       // 8192 rows per direction
constexpr int kRows = kBB * kL;      // 16384 rows total

// ---------------- init: h[0..3]=x, h[4..7]=flip(x) ----------------
__global__ __launch_bounds__(256) void init_h_kernel(const float* __restrict__ x,
                                                     float* __restrict__ h) {
  int idx = blockIdx.x * 256 + threadIdx.x;
  if (idx >= 4 * kL * kDM) return;
  int d = idx & (kDM - 1);
  int l = (idx >> 8) & (kL - 1);
  int b = idx >> 19;
  float v = x[idx];
  h[idx] = v;
  h[((size_t)((4 + b) * kL + (kL - 1 - l))) * kDM + d] = v;
}

// ---------------- LayerNorm over D_MODEL=256, one block per row ----------------
__global__ __launch_bounds__(256) void ln_kernel(const float* __restrict__ h,
                                                 const float* __restrict__ w0,
                                                 const float* __restrict__ b0,
                                                 const float* __restrict__ w1,
                                                 const float* __restrict__ b1,
                                                 float* __restrict__ xn) {
  int row = blockIdx.x;
  int dir = (row >= kRowsD) ? 1 : 0;
  const float* w = dir ? w1 : w0;
  const float* b = dir ? b1 : b0;
  int t = threadIdx.x;
  float v = h[(size_t)row * kDM + t];
  __shared__ float red[256];
  red[t] = v;
  __syncthreads();
  for (int s = 128; s > 0; s >>= 1) {
    if (t < s) red[t] += red[t + s];
    __syncthreads();
  }
  float mu = red[0] * (1.0f / kDM);
  __syncthreads();
  float d = v - mu;
  red[t] = d * d;
  __syncthreads();
  for (int s = 128; s > 0; s >>= 1) {
    if (t < s) red[t] += red[t + s];
    __syncthreads();
  }
  float var = red[0] * (1.0f / kDM);
  float r = rsqrtf(var + 1e-5f);
  xn[(size_t)row * kDM + t] = d * r * w[t] + b[t];
}

// ---------------- GEMM: C[Md,N] (+)= A[Md,K] @ W[N,K]^T, per-direction W ----------------
__global__ __launch_bounds__(256) void gemm_awt(const float* __restrict__ A,
                                                const float* __restrict__ W0,
                                                const float* __restrict__ W1,
                                                float* __restrict__ C, int Md, int N,
                                                int K, int accumulate) {
  int dir = blockIdx.z;
  const float* W = dir ? W1 : W0;
  const float* Ab = A + (size_t)dir * Md * K;
  float* Cb = C + (size_t)dir * Md * N;
  int m0 = blockIdx.y * 64;
  int n0 = blockIdx.x * 64;
  __shared__ float As[16][64];
  __shared__ float Ws[16][64];
  int tid = threadIdx.x;
  int tm = tid & 15, tn = tid >> 4;
  float accv[4][4] = {};
  for (int k0 = 0; k0 < K; k0 += 16) {
#pragma unroll
    for (int i = 0; i < 4; i++) {
      int e = tid + i * 256;
      int m = e >> 4, kk = e & 15;
      As[kk][m] = Ab[(size_t)(m0 + m) * K + (k0 + kk)];
      float v = 0.f;
      if (n0 + m < N) v = W[(size_t)(n0 + m) * K + (k0 + kk)];
      Ws[kk][m] = v;
    }
    __syncthreads();
#pragma unroll
    for (int kk = 0; kk < 16; kk++) {
      float a[4], bv[4];
#pragma unroll
      for (int i = 0; i < 4; i++) a[i] = As[kk][tm * 4 + i];
#pragma unroll
      for (int j = 0; j < 4; j++) bv[j] = Ws[kk][tn * 4 + j];
#pragma unroll
      for (int i = 0; i < 4; i++)
#pragma unroll
        for (int j = 0; j < 4; j++) accv[i][j] += a[i] * bv[j];
    }
    __syncthreads();
  }
#pragma unroll
  for (int i = 0; i < 4; i++) {
    int m = m0 + tm * 4 + i;
#pragma unroll
    for (int j = 0; j < 4; j++) {
      int n = n0 + tn * 4 + j;
      if (n < N) {
        size_t idx = (size_t)m * N + n;
        if (accumulate) Cb[idx] += accv[i][j];
        else Cb[idx] = accv[i][j];
      }
    }
  }
}

// ---------------- causal depthwise conv (width 4) + silu over CONV_DIM ----------------
__global__ __launch_bounds__(256) void conv_kernel(const float* __restrict__ zx,
                                                   const float* __restrict__ cw0,
                                                   const float* __restrict__ cb0,
                                                   const float* __restrict__ cw1,
                                                   const float* __restrict__ cb1,
                                                   float* __restrict__ xc) {
  int idx = blockIdx.x * 256 + threadIdx.x;
  if (idx >= kRows * kCDIM) return;
  int c = idx % kCDIM;
  int row = idx / kCDIM;
  int l = row & (kL - 1);
  int bb = row >> 11;
  int dir = bb >> 2;
  const float* cw = dir ? cw1 : cw0;
  const float* cb = dir ? cb1 : cb0;
  float s = cb[c];
#pragma unroll
  for (int k = 0; k < 4; k++) {
    int ll = l - 3 + k;
    if (ll >= 0) s += zx[((size_t)(bb * kL + ll)) * kDPROJ + kDI + c] * cw[c * 4 + k];
  }
  float sig = 1.f / (1.f + expf(-s));
  xc[(size_t)row * kCDIM + c] = s * sig;
}

// ---------------- dt = softplus(dt_raw + dt_bias) ----------------
__global__ __launch_bounds__(256) void dt_kernel(const float* __restrict__ zx,
                                                 const float* __restrict__ db0,
                                                 const float* __restrict__ db1,
                                                 float* __restrict__ dt) {
  int idx = blockIdx.x * 256 + threadIdx.x;
  if (idx >= kRows * kNH) return;
  int h = idx & (kNH - 1);
  int row = idx >> 4;
  int dir = (row >= kRowsD) ? 1 : 0;
  float x = zx[(size_t)row * kDPROJ + 2 * kDI + 2 * kDS + h] + (dir ? db1 : db0)[h];
  dt[idx] = (x > 20.f) ? x : log1pf(expf(x));
}

// ---------------- per-chunk cumsum of dt*A; g = exp(cs[63]) ----------------
__global__ __launch_bounds__(256) void cumsum_kernel(const float* __restrict__ dt,
                                                     const float* __restrict__ al0,
                                                     const float* __restrict__ al1,
                                                     float* __restrict__ cs,
                                                     float* __restrict__ g) {
  int idx = blockIdx.x * 256 + threadIdx.x;  // bb*512 + k*16 + h
  if (idx >= kBB * kKC * kNH) return;
  int h = idx & (kNH - 1);
  int k = (idx >> 4) & (kKC - 1);
  int bb = idx >> 9;
  int dir = bb >> 2;
  float A = -expf((dir ? al1 : al0)[h]);
  float s = 0.f;
  for (int c = 0; c < kCH; c++) {
    s += dt[((size_t)(bb * kL + k * kCH + c)) * kNH + h] * A;
    cs[(size_t)idx * kCH + c] = s;
  }
  g[idx] = expf(s);
}

// ---------------- CB[b,k,i,j] = sum_n C[i,n]*B[j,n], one block per (b,k) ----------------
__global__ __launch_bounds__(256) void cb_kernel(const float* __restrict__ xc,
                                                 float* __restrict__ CB) {
  int bk = blockIdx.x;
  int k = bk & (kKC - 1);
  int bb = bk >> 5;
  __shared__ float Cs[64][65], Bs[64][65];
  int t = threadIdx.x;
#pragma unroll
  for (int i = 0; i < 16; i++) {
    int e = t + i * 256;
    int r = e >> 6, c = e & 63;
    size_t base = ((size_t)(bb * kL + k * kCH + r)) * kCDIM;
    Bs[r][c] = xc[base + kDI + c];
    Cs[r][c] = xc[base + kDI + kDS + c];
  }
  __syncthreads();
#pragma unroll
  for (int o = 0; o < 16; o++) {
    int e = t + o * 256;
    int i = e >> 6, j = e & 63;
    float s = 0.f;
    for (int n = 0; n < 64; n++) s += Cs[i][n] * Bs[j][n];
    CB[(size_t)bk * 4096 + e] = s;
  }
}

// ---------------- chunk states[b,k,h,p,n], one block per (b,k,h) ----------------
__global__ __launch_bounds__(256) void states_kernel(const float* __restrict__ xc,
                                                     const float* __restrict__ dt,
                                                     const float* __restrict__ cs,
                                                     float* __restrict__ states) {
  int bkh = blockIdx.x;  // bb*512 + k*16 + h
  int h = bkh & (kNH - 1);
  int k = (bkh >> 4) & (kKC - 1);
  int bb = bkh >> 9;
  __shared__ float xs_s[64][33];
  __shared__ float Bs[64][65];
  __shared__ float w_s[64];
  int t = threadIdx.x;
  const float* csb = cs + (size_t)bkh * kCH;
  float cs63 = csb[63];
#pragma unroll
  for (int i = 0; i < 8; i++) {
    int e = t + i * 256;
    int j = e >> 5, p = e & 31;
    xs_s[j][p] = xc[((size_t)(bb * kL + k * kCH + j)) * kCDIM + h * 32 + p];
  }
#pragma unroll
  for (int i = 0; i < 16; i++) {
    int e = t + i * 256;
    int j = e >> 6, n = e & 63;
    Bs[j][n] = xc[((size_t)(bb * kL + k * kCH + j)) * kCDIM + kDI + n];
  }
  if (t < 64)
    w_s[t] = expf(cs63 - csb[t]) * dt[((size_t)(bb * kL + k * kCH + t)) * kNH + h];
  __syncthreads();
#pragma unroll
  for (int o = 0; o < 8; o++) {
    int e = t + o * 256;
    int p = e >> 6, n = e & 63;
    float s = 0.f;
    for (int j = 0; j < 64; j++) s += w_s[j] * xs_s[j][p] * Bs[j][n];
    states[(size_t)bkh * 2048 + e] = s;
  }
}

// ---------------- sequential chunk scan: Sprev[k]=S; S = g*S + states ----------------
__global__ __launch_bounds__(256) void scan_kernel(const float* __restrict__ states,
                                                   const float* __restrict__ g,
                                                   float* __restrict__ sprev) {
  int idx = blockIdx.x * 256 + threadIdx.x;  // bb*16*2048 + h*2048 + pn
  if (idx >= kBB * kNH * 2048) return;
  int pn = idx & 2047;
  int h = (idx >> 11) & (kNH - 1);
  int bb = idx >> 15;
  float S = 0.f;
  for (int k = 0; k < kKC; k++) {
    size_t off = (((size_t)(bb * kKC + k) * kNH + h) * 2048) + pn;
    sprev[off] = S;
    S = g[(bb * kKC + k) * kNH + h] * S + states[off];
  }
}

// ---------------- y = att@xh + exp(cs)*(C@Sprev^T) + D*xh, one block per (b,k,h) ----------------
__global__ __launch_bounds__(256) void y_kernel(const float* __restrict__ xc,
                                                const float* __restrict__ dt,
                                                const float* __restrict__ cs,
                                                const float* __restrict__ CB,
                                                const float* __restrict__ sprev,
                                                const float* __restrict__ D0,
                                                const float* __restrict__ D1,
                                                float* __restrict__ y) {
  int bkh = blockIdx.x;
  int h = bkh & (kNH - 1);
  int k = (bkh >> 4) & (kKC - 1);
  int bb = bkh >> 9;
  int dir = bb >> 2;
  float Dp = (dir ? D1 : D0)[h];
  __shared__ float xs_s[64][33];
  __shared__ float CBs[64][65];
  __shared__ float Cs[64][65];
  __shared__ float sp_s[32][65];
  __shared__ float cs_s[64], dt_s[64];
  int t = threadIdx.x;
#pragma unroll
  for (int i = 0; i < 8; i++) {
    int e = t + i * 256;
    int j = e >> 5, p = e & 31;
    xs_s[j][p] = xc[((size_t)(bb * kL + k * kCH + j)) * kCDIM + h * 32 + p];
  }
#pragma unroll
  for (int i = 0; i < 16; i++) {
    int e = t + i * 256;
    int r = e >> 6, c = e & 63;
    CBs[r][c] = CB[((size_t)(bb * kKC + k)) * 4096 + e];
    Cs[r][c] = xc[((size_t)(bb * kL + k * kCH + r)) * kCDIM + kDI + kDS + c];
  }
#pragma unroll
  for (int i = 0; i < 8; i++) {
    int e = t + i * 256;
    int p = e >> 6, n = e & 63;
    sp_s[p][n] = sprev[(size_t)bkh * 2048 + e];
  }
  if (t < 64) {
    cs_s[t] = cs[(size_t)bkh * kCH + t];
    dt_s[t] = dt[((size_t)(bb * kL + k * kCH + t)) * kNH + h];
  }
  __syncthreads();
  int i = t >> 2;
  int p0 = (t & 3) * 8;
  float acc[8] = {}, accint[8] = {};
  float csi = cs_s[i];
  for (int j = 0; j <= i; j++) {
    float f = expf(csi - cs_s[j]) * dt_s[j] * CBs[i][j];
#pragma unroll
    for (int q = 0; q < 8; q++) acc[q] += f * xs_s[j][p0 + q];
  }
  for (int n = 0; n < 64; n++) {
    float c = Cs[i][n];
#pragma unroll
    for (int q = 0; q < 8; q++) accint[q] += c * sp_s[p0 + q][n];
  }
  float ecsi = expf(csi);
#pragma unroll
  for (int q = 0; q < 8; q++) {
    int p = p0 + q;
    float v = acc[q] + ecsi * accint[q] + Dp * xs_s[i][p];
    y[((size_t)(bb * kL + k * kCH + i)) * kDI + h * 32 + p] = v;
  }
}

// ---------------- y *= silu(z); RMSNorm over 512; *norm_w ----------------
__global__ __launch_bounds__(256) void gate_norm_kernel(const float* __restrict__ zx,
                                                        const float* __restrict__ nw0,
                                                        const float* __restrict__ nw1,
                                                        float* __restrict__ y) {
  int row = blockIdx.x;
  int dir = (row >= kRowsD) ? 1 : 0;
  const float* nw = dir ? nw1 : nw0;
  int t = threadIdx.x;
  float v[2];
  float ss = 0.f;
#pragma unroll
  for (int q = 0; q < 2; q++) {
    int e = t + q * 256;
    float z = zx[(size_t)row * kDPROJ + e];
    float gz = z / (1.f + expf(-z));
    float val = y[(size_t)row * kDI + e] * gz;
    v[q] = val;
    ss += val * val;
  }
  __shared__ float red[256];
  red[t] = ss;
  __syncthreads();
  for (int s = 128; s > 0; s >>= 1) {
    if (t < s) red[t] += red[t + s];
    __syncthreads();
  }
  float scale = rsqrtf(red[0] * (1.0f / kDI) + 1e-5f);
#pragma unroll
  for (int q = 0; q < 2; q++) {
    int e = t + q * 256;
    y[(size_t)row * kDI + e] = v[q] * scale * nw[e];
  }
}

// ---------------- hcat[b,l, 0:256]=h_fw[b,l]; [256:512]=h_bw[b,L-1-l] ----------------
__global__ __launch_bounds__(256) void concat_kernel(const float* __restrict__ h,
                                                     float* __restrict__ hcat) {
  int idx = blockIdx.x * 256 + threadIdx.x;
  if (idx >= 4 * kL * 2 * kDM) return;
  int e = idx & 511;
  int l = (idx >> 9) & (kL - 1);
  int b = idx >> 20;
  float v;
  if (e < kDM)
    v = h[((size_t)(b * kL + l)) * kDM + e];
  else
    v = h[((size_t)((4 + b) * kL + (kL - 1 - l))) * kDM + (e - kDM)];
  hcat[idx] = v;
}

}  // namespace

extern "C" void kernel_launch(void* const* d_in, const int* in_sizes, int n_in,
                              void* d_out, int out_size, void* d_ws, size_t ws_size,
                              hipStream_t stream) {
  const float* x = (const float*)d_in[0];
  const float* fw_ln_w = (const float*)d_in[1];
  const float* fw_ln_b = (const float*)d_in[2];
  const float* fw_win = (const float*)d_in[3];
  const float* fw_convw = (const float*)d_in[4];
  const float* fw_convb = (const float*)d_in[5];
  const float* fw_alog = (const float*)d_in[6];
  const float* fw_dtb = (const float*)d_in[7];
  const float* fw_D = (const float*)d_in[8];
  const float* fw_nw = (const float*)d_in[9];
  const float* fw_wout = (const float*)d_in[10];
  const float* bw_ln_w = (const float*)d_in[11];
  const float* bw_ln_b = (const float*)d_in[12];
  const float* bw_win = (const float*)d_in[13];
  const float* bw_convw = (const float*)d_in[14];
  const float* bw_convb = (const float*)d_in[15];
  const float* bw_alog = (const float*)d_in[16];
  const float* bw_dtb = (const float*)d_in[17];
  const float* bw_D = (const float*)d_in[18];
  const float* bw_nw = (const float*)d_in[19];
  const float* bw_wout = (const float*)d_in[20];
  const float* fusion_w = (const float*)d_in[21];
  float* out = (float*)d_out;

  float* ws = (float*)d_ws;
  // workspace layout (floats); total 64,753,664 floats = ~247 MB
  float* h = ws;                                // 8*2048*256   = 4,194,304
  float* xn = h + (size_t)kRows * kDM;          // 4,194,304
  float* zx = xn + (size_t)kRows * kDM;         // 8*2048*1168 = 19,136,512
  float* xc = zx + (size_t)kRows * kDPROJ;      // 8*2048*640  = 10,485,760
  float* dt = xc + (size_t)kRows * kCDIM;       // 8*2048*16   = 262,144
  float* cs = dt + (size_t)kRows * kNH;         // 8*32*16*64  = 262,144
  float* g = cs + (size_t)kBB * kKC * kNH * kCH;    // 4096
  float* CB = g + (size_t)kBB * kKC * kNH;          // 8*32*64*64 = 1,048,576
  float* states = CB + (size_t)kBB * kKC * 4096;    // 8*32*16*32*64 = 8,388,608
  float* sprev = states + (size_t)kBB * kKC * kNH * 2048;  // 8,388,608
  float* y = sprev + (size_t)kBB * kKC * kNH * 2048;       // 8*2048*512 = 8,388,608
  float* hcat = xn;  // reuse xn for fusion concat (4*2048*512 = 4,194,304)

  init_h_kernel<<<(4 * kL * kDM + 255) / 256, 256, 0, stream>>>(x, h);

  for (int i = 0; i < 8; i++) {
    const size_t oLN = (size_t)i * kDM;
    const size_t oWIN = (size_t)i * kDPROJ * kDM;
    const size_t oCW = (size_t)i * kCDIM * 4;
    const size_t oCB = (size_t)i * kCDIM;
    const size_t oH = (size_t)i * kNH;
    const size_t oNW = (size_t)i * kDI;
    const size_t oWO = (size_t)i * kDM * kDI;

    ln_kernel<<<kRows, 256, 0, stream>>>(h, fw_ln_w + oLN, fw_ln_b + oLN,
                                         bw_ln_w + oLN, bw_ln_b + oLN, xn);
    {
      dim3 grid((kDPROJ + 63) / 64, kRowsD / 64, 2);
      gemm_awt<<<grid, 256, 0, stream>>>(xn, fw_win + oWIN, bw_win + oWIN, zx,
                                         kRowsD, kDPROJ, kDM, 0);
    }
    conv_kernel<<<(kRows * kCDIM + 255) / 256, 256, 0, stream>>>(
        zx, fw_convw + oCW, fw_convb + oCB, bw_convw + oCW, bw_convb + oCB, xc);
    dt_kernel<<<(kRows * kNH + 255) / 256, 256, 0, stream>>>(zx, fw_dtb + oH,
                                                             bw_dtb + oH, dt);
    cumsum_kernel<<<(kBB * kKC * kNH + 255) / 256, 256, 0, stream>>>(
        dt, fw_alog + oH, bw_alog + oH, cs, g);
    cb_kernel<<<kBB * kKC, 256, 0, stream>>>(xc, CB);
    states_kernel<<<kBB * kKC * kNH, 256, 0, stream>>>(xc, dt, cs, states);
    scan_kernel<<<(kBB * kNH * 2048 + 255) / 256, 256, 0, stream>>>(states, g, sprev);
    y_kernel<<<kBB * kKC * kNH, 256, 0, stream>>>(xc, dt, cs, CB, sprev, fw_D + oH,
                                                  bw_D + oH, y);
    gate_norm_kernel<<<kRows, 256, 0, stream>>>(zx, fw_nw + oNW, bw_nw + oNW, y);
    {
      dim3 grid(kDM / 64, kRowsD / 64, 2);
      gemm_awt<<<grid, 256, 0, stream>>>(y, fw_wout + oWO, bw_wout + oWO, h, kRowsD,
                                         kDM, kDI, 1);
    }
  }

  concat_kernel<<<(4 * kL * 2 * kDM + 255) / 256, 256, 0, stream>>>(h, hcat);
  {
    dim3 grid(kDM / 64, kRowsD / 64, 1);
    gemm_awt<<<grid, 256, 0, stream>>>(hcat, fusion_w, fusion_w, out, kRowsD, kDM,
                                       2 * kDM, 0);
  }
}

// Round 2
// 4396.143 us; speedup vs baseline: 1.6789x; 1.6789x over previous
//
#include <hip/hip_runtime.h>
#include <math.h>

// BiMambaEncoder: 8-layer bidirectional Mamba2 stack, fp32.
// Round 2: restructured SSD kernels (states/y/cb) for vector LDS reads +
// occupancy; wave-scan cumsum fused with softplus(dt); shfl reductions.

namespace {

constexpr int kL = 2048;
constexpr int kDM = 256;
constexpr int kDI = 512;
constexpr int kNH = 16;
constexpr int kDS = 64;
constexpr int kCDIM = 640;
constexpr int kDPROJ = 1168;
constexpr int kCH = 64;       // chunk length
constexpr int kKC = 32;       // number of chunks
constexpr int kBB = 8;        // combined batch: 4 fwd + 4 bwd
constexpr int kRowsD = 4 * kL;       // 8192 rows per direction
constexpr int kRows = kBB * kL;      // 16384 rows total

// ---------------- init: h[0..3]=x, h[4..7]=flip(x) ----------------
__global__ __launch_bounds__(256) void init_h_kernel(const float* __restrict__ x,
                                                     float* __restrict__ h) {
  int idx = blockIdx.x * 256 + threadIdx.x;
  if (idx >= 4 * kL * kDM) return;
  int d = idx & (kDM - 1);
  int l = (idx >> 8) & (kL - 1);
  int b = idx >> 19;
  float v = x[idx];
  h[idx] = v;
  h[((size_t)((4 + b) * kL + (kL - 1 - l))) * kDM + d] = v;
}

// ---------------- LayerNorm over D_MODEL=256, one block per row ----------------
__global__ __launch_bounds__(256) void ln_kernel(const float* __restrict__ h,
                                                 const float* __restrict__ w0,
                                                 const float* __restrict__ b0,
                                                 const float* __restrict__ w1,
                                                 const float* __restrict__ b1,
                                                 float* __restrict__ xn) {
  int row = blockIdx.x;
  int dir = (row >= kRowsD) ? 1 : 0;
  const float* w = dir ? w1 : w0;
  const float* b = dir ? b1 : b0;
  int t = threadIdx.x;
  float v = h[(size_t)row * kDM + t];
  __shared__ float red[4];
  float s = v;
#pragma unroll
  for (int o = 32; o > 0; o >>= 1) s += __shfl_down(s, o);
  if ((t & 63) == 0) red[t >> 6] = s;
  __syncthreads();
  float mu = (red[0] + red[1] + red[2] + red[3]) * (1.0f / kDM);
  __syncthreads();
  float d = v - mu;
  s = d * d;
#pragma unroll
  for (int o = 32; o > 0; o >>= 1) s += __shfl_down(s, o);
  if ((t & 63) == 0) red[t >> 6] = s;
  __syncthreads();
  float var = (red[0] + red[1] + red[2] + red[3]) * (1.0f / kDM);
  float r = rsqrtf(var + 1e-5f);
  xn[(size_t)row * kDM + t] = d * r * w[t] + b[t];
}

// ---------------- GEMM: C[Md,N] (+)= A[Md,K] @ W[N,K]^T, per-direction W ----------------
__global__ __launch_bounds__(256) void gemm_awt(const float* __restrict__ A,
                                                const float* __restrict__ W0,
                                                const float* __restrict__ W1,
                                                float* __restrict__ C, int Md, int N,
                                                int K, int accumulate) {
  int dir = blockIdx.z;
  const float* W = dir ? W1 : W0;
  const float* Ab = A + (size_t)dir * Md * K;
  float* Cb = C + (size_t)dir * Md * N;
  int m0 = blockIdx.y * 64;
  int n0 = blockIdx.x * 64;
  __shared__ __align__(16) float As[16][64];
  __shared__ __align__(16) float Ws[16][64];
  int tid = threadIdx.x;
  int tm = tid & 15, tn = tid >> 4;
  float accv[4][4] = {};
  for (int k0 = 0; k0 < K; k0 += 16) {
#pragma unroll
    for (int i = 0; i < 4; i++) {
      int e = tid + i * 256;
      int m = e >> 4, kk = e & 15;
      As[kk][m] = Ab[(size_t)(m0 + m) * K + (k0 + kk)];
      float v = 0.f;
      if (n0 + m < N) v = W[(size_t)(n0 + m) * K + (k0 + kk)];
      Ws[kk][m] = v;
    }
    __syncthreads();
#pragma unroll
    for (int kk = 0; kk < 16; kk++) {
      float a[4], bv[4];
#pragma unroll
      for (int i = 0; i < 4; i++) a[i] = As[kk][tm * 4 + i];
#pragma unroll
      for (int j = 0; j < 4; j++) bv[j] = Ws[kk][tn * 4 + j];
#pragma unroll
      for (int i = 0; i < 4; i++)
#pragma unroll
        for (int j = 0; j < 4; j++) accv[i][j] += a[i] * bv[j];
    }
    __syncthreads();
  }
#pragma unroll
  for (int i = 0; i < 4; i++) {
    int m = m0 + tm * 4 + i;
#pragma unroll
    for (int j = 0; j < 4; j++) {
      int n = n0 + tn * 4 + j;
      if (n < N) {
        size_t idx = (size_t)m * N + n;
        if (accumulate) Cb[idx] += accv[i][j];
        else Cb[idx] = accv[i][j];
      }
    }
  }
}

// ---------------- causal depthwise conv (width 4) + silu over CONV_DIM ----------------
__global__ __launch_bounds__(256) void conv_kernel(const float* __restrict__ zx,
                                                   const float* __restrict__ cw0,
                                                   const float* __restrict__ cb0,
                                                   const float* __restrict__ cw1,
                                                   const float* __restrict__ cb1,
                                                   float* __restrict__ xc) {
  int idx = blockIdx.x * 256 + threadIdx.x;
  if (idx >= kRows * kCDIM) return;
  int c = idx % kCDIM;
  int row = idx / kCDIM;
  int l = row & (kL - 1);
  int bb = row >> 11;
  int dir = bb >> 2;
  const float* cw = dir ? cw1 : cw0;
  const float* cb = dir ? cb1 : cb0;
  float s = cb[c];
#pragma unroll
  for (int k = 0; k < 4; k++) {
    int ll = l - 3 + k;
    if (ll >= 0) s += zx[((size_t)(bb * kL + ll)) * kDPROJ + kDI + c] * cw[c * 4 + k];
  }
  float sig = 1.f / (1.f + __expf(-s));
  xc[(size_t)row * kCDIM + c] = s * sig;
}

// ---------------- fused softplus(dt) + per-chunk wave-scan cumsum ----------------
// one 64-lane wave per (bb,k,h); 4 waves per block
__global__ __launch_bounds__(256) void cumsum_kernel(const float* __restrict__ zx,
                                                     const float* __restrict__ db0,
                                                     const float* __restrict__ db1,
                                                     const float* __restrict__ al0,
                                                     const float* __restrict__ al1,
                                                     float* __restrict__ dt,
                                                     float* __restrict__ cs,
                                                     float* __restrict__ g) {
  int t = threadIdx.x;
  int c = t & 63;
  int wid = blockIdx.x * 4 + (t >> 6);  // bb*512 + k*16 + h
  int h = wid & (kNH - 1);
  int k = (wid >> 4) & (kKC - 1);
  int bb = wid >> 9;
  int dir = bb >> 2;
  int row = bb * kL + k * kCH + c;
  float x = zx[(size_t)row * kDPROJ + 2 * kDI + 2 * kDS + h] + (dir ? db1 : db0)[h];
  float dtv = (x > 20.f) ? x : log1pf(expf(x));
  dt[(size_t)row * kNH + h] = dtv;
  float A = -__expf((dir ? al1 : al0)[h]);
  float s = dtv * A;
#pragma unroll
  for (int off = 1; off < 64; off <<= 1) {
    float u = __shfl_up(s, off);
    if (c >= off) s += u;
  }
  cs[(size_t)wid * kCH + c] = s;
  if (c == 63) g[wid] = __expf(s);
}

// ---------------- CB[b,k,i,j] = sum_n C[i,n]*B[j,n], one block per (b,k) ----------------
__global__ __launch_bounds__(256, 4) void cb_kernel(const float* __restrict__ xc,
                                                    float* __restrict__ CB) {
  int bk = blockIdx.x;
  int k = bk & (kKC - 1);
  int bb = bk >> 5;
  __shared__ __align__(16) float Ct[64][72];  // Ct[n][i] = C[i][n]
  __shared__ __align__(16) float Bt[64][72];  // Bt[n][j] = B[j][n]
  int t = threadIdx.x;
#pragma unroll
  for (int o = 0; o < 16; o++) {
    int e = t + o * 256;
    int i = e >> 6, n = e & 63;
    size_t base = ((size_t)(bb * kL + k * kCH + i)) * kCDIM;
    Bt[n][i] = xc[base + kDI + n];
    Ct[n][i] = xc[base + kDI + kDS + n];
  }
  __syncthreads();
  int i0 = (t & 15) * 4, j0 = (t >> 4) * 4;
  float acc[4][4] = {};
  for (int n = 0; n < 64; n++) {
    float4 cv = *(const float4*)&Ct[n][i0];
    float4 bv = *(const float4*)&Bt[n][j0];
    float ca[4] = {cv.x, cv.y, cv.z, cv.w};
    float ba[4] = {bv.x, bv.y, bv.z, bv.w};
#pragma unroll
    for (int a = 0; a < 4; a++)
#pragma unroll
      for (int b = 0; b < 4; b++) acc[a][b] += ca[a] * ba[b];
  }
#pragma unroll
  for (int a = 0; a < 4; a++) {
    float4 st = {acc[a][0], acc[a][1], acc[a][2], acc[a][3]};
    *(float4*)&CB[(size_t)bk * 4096 + (i0 + a) * 64 + j0] = st;
  }
}

// ---------------- chunk states[b,k,h,p,n], one block per (b,k,h) ----------------
__global__ __launch_bounds__(256, 6) void states_kernel(const float* __restrict__ xc,
                                                        const float* __restrict__ dt,
                                                        const float* __restrict__ cs,
                                                        float* __restrict__ states) {
  int bkh = blockIdx.x;  // bb*512 + k*16 + h
  int h = bkh & (kNH - 1);
  int k = (bkh >> 4) & (kKC - 1);
  int bb = bkh >> 9;
  __shared__ __align__(16) float xs_s[64][32];
  __shared__ __align__(16) float Bs[64][64];
  __shared__ float w_s[64];
  int t = threadIdx.x;
  const float* csb = cs + (size_t)bkh * kCH;
  size_t rowbase = (size_t)(bb * kL + k * kCH);
#pragma unroll
  for (int o = 0; o < 2; o++) {
    int f = t + o * 256;
    int j = f >> 3, p4 = (f & 7) * 4;
    *(float4*)&xs_s[j][p4] =
        *(const float4*)&xc[(rowbase + j) * kCDIM + h * 32 + p4];
  }
#pragma unroll
  for (int o = 0; o < 4; o++) {
    int f = t + o * 256;
    int j = f >> 4, n4 = (f & 15) * 4;
    *(float4*)&Bs[j][n4] = *(const float4*)&xc[(rowbase + j) * kCDIM + kDI + n4];
  }
  if (t < 64) {
    float cs63 = csb[63];
    w_s[t] = __expf(cs63 - csb[t]) * dt[(rowbase + t) * kNH + h];
  }
  __syncthreads();
  int p = t >> 3;
  int n0 = (t & 7) * 8;
  float acc[8] = {};
  for (int j = 0; j < 64; j++) {
    float a = w_s[j] * xs_s[j][p];
    float4 b0 = *(const float4*)&Bs[j][n0];
    float4 b1 = *(const float4*)&Bs[j][n0 + 4];
    acc[0] += a * b0.x; acc[1] += a * b0.y; acc[2] += a * b0.z; acc[3] += a * b0.w;
    acc[4] += a * b1.x; acc[5] += a * b1.y; acc[6] += a * b1.z; acc[7] += a * b1.w;
  }
  float4 s0 = {acc[0], acc[1], acc[2], acc[3]};
  float4 s1 = {acc[4], acc[5], acc[6], acc[7]};
  *(float4*)&states[(size_t)bkh * 2048 + p * 64 + n0] = s0;
  *(float4*)&states[(size_t)bkh * 2048 + p * 64 + n0 + 4] = s1;
}

// ---------------- sequential chunk scan: Sprev[k]=S; S = g*S + states ----------------
__global__ __launch_bounds__(256) void scan_kernel(const float* __restrict__ states,
                                                   const float* __restrict__ g,
                                                   float* __restrict__ sprev) {
  int idx = blockIdx.x * 256 + threadIdx.x;  // bb*16*2048 + h*2048 + pn
  if (idx >= kBB * kNH * 2048) return;
  int pn = idx & 2047;
  int h = (idx >> 11) & (kNH - 1);
  int bb = idx >> 15;
  float S = 0.f;
  for (int k = 0; k < kKC; k++) {
    size_t off = (((size_t)(bb * kKC + k) * kNH + h) * 2048) + pn;
    sprev[off] = S;
    S = g[(bb * kKC + k) * kNH + h] * S + states[off];
  }
}

// ---------------- y = att@xh + exp(cs)*(C@Sprev^T) + D*xh, one block per (b,k,h) ----------------
__global__ __launch_bounds__(256, 3) void y_kernel(const float* __restrict__ xc,
                                                   const float* __restrict__ dt,
                                                   const float* __restrict__ cs,
                                                   const float* __restrict__ CB,
                                                   const float* __restrict__ sprev,
                                                   const float* __restrict__ D0,
                                                   const float* __restrict__ D1,
                                                   float* __restrict__ y) {
  int bkh = blockIdx.x;
  int h = bkh & (kNH - 1);
  int k = (bkh >> 4) & (kKC - 1);
  int bb = bkh >> 9;
  int dir = bb >> 2;
  float Dp = (dir ? D1 : D0)[h];
  __shared__ __align__(16) float xs_s[64][32];
  __shared__ float CBs[64][65];
  __shared__ float Cs[64][65];
  __shared__ __align__(16) float sp_t[64][36];  // sp_t[n][p] = Sprev[p][n]
  __shared__ float cs_s[64], dt_s[64];
  int t = threadIdx.x;
  size_t rowbase = (size_t)(bb * kL + k * kCH);
#pragma unroll
  for (int o = 0; o < 2; o++) {
    int f = t + o * 256;
    int j = f >> 3, p4 = (f & 7) * 4;
    *(float4*)&xs_s[j][p4] =
        *(const float4*)&xc[(rowbase + j) * kCDIM + h * 32 + p4];
  }
  int bkq = bb * kKC + k;
#pragma unroll
  for (int o = 0; o < 16; o++) {
    int e = t + o * 256;
    int r = e >> 6, c = e & 63;
    CBs[r][c] = CB[(size_t)bkq * 4096 + e];
    Cs[r][c] = xc[(rowbase + r) * kCDIM + kDI + kDS + c];
  }
#pragma unroll
  for (int o = 0; o < 8; o++) {
    int e = t + o * 256;
    int p = e >> 6, n = e & 63;
    sp_t[n][p] = sprev[(size_t)bkh * 2048 + e];
  }
  if (t < 64) {
    cs_s[t] = cs[(size_t)bkh * kCH + t];
    dt_s[t] = dt[(rowbase + t) * kNH + h];
  }
  __syncthreads();
  int i = t >> 2;
  int p0 = (t & 3) * 8;
  float acc[8] = {};
  float csi = cs_s[i];
  for (int j = 0; j <= i; j++) {
    float f = __expf(csi - cs_s[j]) * dt_s[j] * CBs[i][j];
    float4 x0 = *(const float4*)&xs_s[j][p0];
    float4 x1 = *(const float4*)&xs_s[j][p0 + 4];
    acc[0] += f * x0.x; acc[1] += f * x0.y; acc[2] += f * x0.z; acc[3] += f * x0.w;
    acc[4] += f * x1.x; acc[5] += f * x1.y; acc[6] += f * x1.z; acc[7] += f * x1.w;
  }
  float ecsi = __expf(csi);
  for (int n = 0; n < 64; n++) {
    float cf = ecsi * Cs[i][n];
    float4 s0 = *(const float4*)&sp_t[n][p0];
    float4 s1 = *(const float4*)&sp_t[n][p0 + 4];
    acc[0] += cf * s0.x; acc[1] += cf * s0.y; acc[2] += cf * s0.z; acc[3] += cf * s0.w;
    acc[4] += cf * s1.x; acc[5] += cf * s1.y; acc[6] += cf * s1.z; acc[7] += cf * s1.w;
  }
  float4 xi0 = *(const float4*)&xs_s[i][p0];
  float4 xi1 = *(const float4*)&xs_s[i][p0 + 4];
  float4 o0 = {acc[0] + Dp * xi0.x, acc[1] + Dp * xi0.y, acc[2] + Dp * xi0.z,
               acc[3] + Dp * xi0.w};
  float4 o1 = {acc[4] + Dp * xi1.x, acc[5] + Dp * xi1.y, acc[6] + Dp * xi1.z,
               acc[7] + Dp * xi1.w};
  *(float4*)&y[(rowbase + i) * kDI + h * 32 + p0] = o0;
  *(float4*)&y[(rowbase + i) * kDI + h * 32 + p0 + 4] = o1;
}

// ---------------- y *= silu(z); RMSNorm over 512; *norm_w ----------------
__global__ __launch_bounds__(256) void gate_norm_kernel(const float* __restrict__ zx,
                                                        const float* __restrict__ nw0,
                                                        const float* __restrict__ nw1,
                                                        float* __restrict__ y) {
  int row = blockIdx.x;
  int dir = (row >= kRowsD) ? 1 : 0;
  const float* nw = dir ? nw1 : nw0;
  int t = threadIdx.x;
  float v[2];
  float ss = 0.f;
#pragma unroll
  for (int q = 0; q < 2; q++) {
    int e = t + q * 256;
    float z = zx[(size_t)row * kDPROJ + e];
    float gz = z / (1.f + __expf(-z));
    float val = y[(size_t)row * kDI + e] * gz;
    v[q] = val;
    ss += val * val;
  }
  __shared__ float red[4];
#pragma unroll
  for (int o = 32; o > 0; o >>= 1) ss += __shfl_down(ss, o);
  if ((t & 63) == 0) red[t >> 6] = ss;
  __syncthreads();
  float tot = red[0] + red[1] + red[2] + red[3];
  float scale = rsqrtf(tot * (1.0f / kDI) + 1e-5f);
#pragma unroll
  for (int q = 0; q < 2; q++) {
    int e = t + q * 256;
    y[(size_t)row * kDI + e] = v[q] * scale * nw[e];
  }
}

// ---------------- hcat[b,l, 0:256]=h_fw[b,l]; [256:512]=h_bw[b,L-1-l] ----------------
__global__ __launch_bounds__(256) void concat_kernel(const float* __restrict__ h,
                                                     float* __restrict__ hcat) {
  int idx = blockIdx.x * 256 + threadIdx.x;
  if (idx >= 4 * kL * 2 * kDM) return;
  int e = idx & 511;
  int l = (idx >> 9) & (kL - 1);
  int b = idx >> 20;
  float v;
  if (e < kDM)
    v = h[((size_t)(b * kL + l)) * kDM + e];
  else
    v = h[((size_t)((4 + b) * kL + (kL - 1 - l))) * kDM + (e - kDM)];
  hcat[idx] = v;
}

}  // namespace

extern "C" void kernel_launch(void* const* d_in, const int* in_sizes, int n_in,
                              void* d_out, int out_size, void* d_ws, size_t ws_size,
                              hipStream_t stream) {
  const float* x = (const float*)d_in[0];
  const float* fw_ln_w = (const float*)d_in[1];
  const float* fw_ln_b = (const float*)d_in[2];
  const float* fw_win = (const float*)d_in[3];
  const float* fw_convw = (const float*)d_in[4];
  const float* fw_convb = (const float*)d_in[5];
  const float* fw_alog = (const float*)d_in[6];
  const float* fw_dtb = (const float*)d_in[7];
  const float* fw_D = (const float*)d_in[8];
  const float* fw_nw = (const float*)d_in[9];
  const float* fw_wout = (const float*)d_in[10];
  const float* bw_ln_w = (const float*)d_in[11];
  const float* bw_ln_b = (const float*)d_in[12];
  const float* bw_win = (const float*)d_in[13];
  const float* bw_convw = (const float*)d_in[14];
  const float* bw_convb = (const float*)d_in[15];
  const float* bw_alog = (const float*)d_in[16];
  const float* bw_dtb = (const float*)d_in[17];
  const float* bw_D = (const float*)d_in[18];
  const float* bw_nw = (const float*)d_in[19];
  const float* bw_wout = (const float*)d_in[20];
  const float* fusion_w = (const float*)d_in[21];
  float* out = (float*)d_out;

  float* ws = (float*)d_ws;
  float* h = ws;                                // 16384*256
  float* xn = h + (size_t)kRows * kDM;          // 16384*256
  float* zx = xn + (size_t)kRows * kDM;         // 16384*1168
  float* xc = zx + (size_t)kRows * kDPROJ;      // 16384*640
  float* dt = xc + (size_t)kRows * kCDIM;       // 16384*16
  float* cs = dt + (size_t)kRows * kNH;         // 4096*64
  float* g = cs + (size_t)kBB * kKC * kNH * kCH;
  float* CB = g + (size_t)kBB * kKC * kNH;
  float* states = CB + (size_t)kBB * kKC * 4096;
  float* sprev = states + (size_t)kBB * kKC * kNH * 2048;
  float* y = sprev + (size_t)kBB * kKC * kNH * 2048;
  float* hcat = xn;

  init_h_kernel<<<(4 * kL * kDM + 255) / 256, 256, 0, stream>>>(x, h);

  for (int i = 0; i < 8; i++) {
    const size_t oLN = (size_t)i * kDM;
    const size_t oWIN = (size_t)i * kDPROJ * kDM;
    const size_t oCW = (size_t)i * kCDIM * 4;
    const size_t oCB = (size_t)i * kCDIM;
    const size_t oH = (size_t)i * kNH;
    const size_t oNW = (size_t)i * kDI;
    const size_t oWO = (size_t)i * kDM * kDI;

    ln_kernel<<<kRows, 256, 0, stream>>>(h, fw_ln_w + oLN, fw_ln_b + oLN,
                                         bw_ln_w + oLN, bw_ln_b + oLN, xn);
    {
      dim3 grid((kDPROJ + 63) / 64, kRowsD / 64, 2);
      gemm_awt<<<grid, 256, 0, stream>>>(xn, fw_win + oWIN, bw_win + oWIN, zx,
                                         kRowsD, kDPROJ, kDM, 0);
    }
    conv_kernel<<<(kRows * kCDIM + 255) / 256, 256, 0, stream>>>(
        zx, fw_convw + oCW, fw_convb + oCB, bw_convw + oCW, bw_convb + oCB, xc);
    cumsum_kernel<<<kBB * kKC * kNH / 4, 256, 0, stream>>>(
        zx, fw_dtb + oH, bw_dtb + oH, fw_alog + oH, bw_alog + oH, dt, cs, g);
    cb_kernel<<<kBB * kKC, 256, 0, stream>>>(xc, CB);
    states_kernel<<<kBB * kKC * kNH, 256, 0, stream>>>(xc, dt, cs, states);
    scan_kernel<<<(kBB * kNH * 2048 + 255) / 256, 256, 0, stream>>>(states, g, sprev);
    y_kernel<<<kBB * kKC * kNH, 256, 0, stream>>>(xc, dt, cs, CB, sprev, fw_D + oH,
                                                  bw_D + oH, y);
    gate_norm_kernel<<<kRows, 256, 0, stream>>>(zx, fw_nw + oNW, bw_nw + oNW, y);
    {
      dim3 grid(kDM / 64, kRowsD / 64, 2);
      gemm_awt<<<grid, 256, 0, stream>>>(y, fw_wout + oWO, bw_wout + oWO, h, kRowsD,
                                         kDM, kDI, 1);
    }
  }

  concat_kernel<<<(4 * kL * 2 * kDM + 255) / 256, 256, 0, stream>>>(h, hcat);
  {
    dim3 grid(kDM / 64, kRowsD / 64, 1);
    gemm_awt<<<grid, 256, 0, stream>>>(hcat, fusion_w, fusion_w, out, kRowsD, kDM,
                                       2 * kDM, 0);
  }
}

// Round 3
// 2021.150 us; speedup vs baseline: 3.6516x; 2.1751x over previous
//
#include <hip/hip_runtime.h>
#include <math.h>

// BiMambaEncoder: 8-layer bidirectional Mamba2 stack.
// Round 3: bf16 MFMA GEMMs (16x16x32, fp32 accum) for in_proj/out_proj/fusion;
// fp32 everywhere else. Scan made in-place to fit bf16 buffers in ws.

namespace {

constexpr int kL = 2048;
constexpr int kDM = 256;
constexpr int kDI = 512;
constexpr int kNH = 16;
constexpr int kDS = 64;
constexpr int kCDIM = 640;
constexpr int kDPROJ = 1168;
constexpr int kCH = 64;       // chunk length
constexpr int kKC = 32;       // number of chunks
constexpr int kBB = 8;        // combined batch: 4 fwd + 4 bwd
constexpr int kRowsD = 4 * kL;       // 8192 rows per direction
constexpr int kRows = kBB * kL;      // 16384 rows total

typedef __bf16 bf16x8 __attribute__((ext_vector_type(8)));
typedef float f32x4 __attribute__((ext_vector_type(4)));
typedef unsigned short ushort;

__device__ __forceinline__ ushort f2b(float x) {
  union { float f; unsigned u; } c;
  c.f = x;
  unsigned r = c.u + 0x7fffu + ((c.u >> 16) & 1u);
  return (ushort)(r >> 16);
}

__device__ __forceinline__ void gl_lds16(const void* g, void* l) {
  __builtin_amdgcn_global_load_lds(
      (const __attribute__((address_space(1))) unsigned int*)g,
      (__attribute__((address_space(3))) unsigned int*)l, 16, 0, 0);
}

// ---------------- fp32 -> bf16 conversion (4-wide) ----------------
__global__ __launch_bounds__(256) void f2b_kernel(const float* __restrict__ src,
                                                  ushort* __restrict__ dst, int n4) {
  int i = blockIdx.x * 256 + threadIdx.x;
  if (i >= n4) return;
  float4 v = *(const float4*)&src[i * 4];
  ushort4 o = {f2b(v.x), f2b(v.y), f2b(v.z), f2b(v.w)};
  *(ushort4*)&dst[i * 4] = o;
}

// ---------------- init: h[0..3]=x, h[4..7]=flip(x) ----------------
__global__ __launch_bounds__(256) void init_h_kernel(const float* __restrict__ x,
                                                     float* __restrict__ h) {
  int idx = blockIdx.x * 256 + threadIdx.x;
  if (idx >= 4 * kL * kDM) return;
  int d = idx & (kDM - 1);
  int l = (idx >> 8) & (kL - 1);
  int b = idx >> 19;
  float v = x[idx];
  h[idx] = v;
  h[((size_t)((4 + b) * kL + (kL - 1 - l))) * kDM + d] = v;
}

// ---------------- LayerNorm over 256, one block per row, bf16 out ----------------
__global__ __launch_bounds__(256) void ln_kernel(const float* __restrict__ h,
                                                 const float* __restrict__ w0,
                                                 const float* __restrict__ b0,
                                                 const float* __restrict__ w1,
                                                 const float* __restrict__ b1,
                                                 ushort* __restrict__ xn) {
  int row = blockIdx.x;
  int dir = (row >= kRowsD) ? 1 : 0;
  const float* w = dir ? w1 : w0;
  const float* b = dir ? b1 : b0;
  int t = threadIdx.x;
  float v = h[(size_t)row * kDM + t];
  __shared__ float red[4];
  float s = v;
#pragma unroll
  for (int o = 32; o > 0; o >>= 1) s += __shfl_down(s, o);
  if ((t & 63) == 0) red[t >> 6] = s;
  __syncthreads();
  float mu = (red[0] + red[1] + red[2] + red[3]) * (1.0f / kDM);
  __syncthreads();
  float d = v - mu;
  s = d * d;
#pragma unroll
  for (int o = 32; o > 0; o >>= 1) s += __shfl_down(s, o);
  if ((t & 63) == 0) red[t >> 6] = s;
  __syncthreads();
  float var = (red[0] + red[1] + red[2] + red[3]) * (1.0f / kDM);
  float r = rsqrtf(var + 1e-5f);
  xn[(size_t)row * kDM + t] = f2b(d * r * w[t] + b[t]);
}

// ---------------- bf16 MFMA GEMM: C[Md,N] (+)= A[Md,K] @ W[N,K]^T ----------------
// 128x128 tile, 4 waves (2x2 of 64x64), BK=32, global_load_lds staging.
__global__ __launch_bounds__(256) void gemm_bf16(const ushort* __restrict__ A,
                                                 const ushort* __restrict__ W0,
                                                 const ushort* __restrict__ W1,
                                                 float* __restrict__ C, int Md, int N,
                                                 int K, int accumulate) {
  int dir = blockIdx.z;
  const ushort* W = dir ? W1 : W0;
  const ushort* Ab = A + (size_t)dir * Md * K;
  float* Cb = C + (size_t)dir * Md * N;
  int m0 = blockIdx.y * 128;
  int n0 = blockIdx.x * 128;
  __shared__ __align__(16) ushort As[128 * 32];
  __shared__ __align__(16) ushort Ws[128 * 32];
  int tid = threadIdx.x;
  int lane = tid & 63;
  int wv = tid >> 6;
  int wr = (wv >> 1) * 64, wc = (wv & 1) * 64;
  int l16 = lane & 15, lk = lane >> 4;
  int rA = tid >> 2;          // staging row 0..63
  int cA = (tid & 3) * 8;     // staging col 0,8,16,24
  char* ldsA = (char*)As + wv * 1024;
  char* ldsB = (char*)Ws + wv * 1024;
  int rb0 = n0 + rA;       if (rb0 >= N) rb0 = N - 1;
  int rb1 = n0 + rA + 64;  if (rb1 >= N) rb1 = N - 1;

  f32x4 acc[4][4];
#pragma unroll
  for (int m = 0; m < 4; m++)
#pragma unroll
    for (int n = 0; n < 4; n++) acc[m][n] = {0.f, 0.f, 0.f, 0.f};

  for (int k0 = 0; k0 < K; k0 += 32) {
    gl_lds16(Ab + (size_t)(m0 + rA) * K + k0 + cA, ldsA);
    gl_lds16(Ab + (size_t)(m0 + rA + 64) * K + k0 + cA, ldsA + 4096);
    gl_lds16(W + (size_t)rb0 * K + k0 + cA, ldsB);
    gl_lds16(W + (size_t)rb1 * K + k0 + cA, ldsB + 4096);
    __syncthreads();
    bf16x8 a[4], b[4];
#pragma unroll
    for (int m = 0; m < 4; m++)
      a[m] = *(const bf16x8*)((const char*)As +
                              (((wr + m * 16 + l16) * 32 + lk * 8) << 1));
#pragma unroll
    for (int n = 0; n < 4; n++)
      b[n] = *(const bf16x8*)((const char*)Ws +
                              (((wc + n * 16 + l16) * 32 + lk * 8) << 1));
#pragma unroll
    for (int m = 0; m < 4; m++)
#pragma unroll
      for (int n = 0; n < 4; n++)
        acc[m][n] =
            __builtin_amdgcn_mfma_f32_16x16x32_bf16(a[m], b[n], acc[m][n], 0, 0, 0);
    __syncthreads();
  }
#pragma unroll
  for (int m = 0; m < 4; m++) {
#pragma unroll
    for (int n = 0; n < 4; n++) {
      int col = n0 + wc + n * 16 + l16;
      if (col < N) {
#pragma unroll
        for (int r = 0; r < 4; r++) {
          int row = m0 + wr + m * 16 + lk * 4 + r;
          size_t idx = (size_t)row * N + col;
          float v = acc[m][n][r];
          if (accumulate) Cb[idx] += v;
          else Cb[idx] = v;
        }
      }
    }
  }
}

// ---------------- causal depthwise conv (width 4) + silu over CONV_DIM ----------------
__global__ __launch_bounds__(256) void conv_kernel(const float* __restrict__ zx,
                                                   const float* __restrict__ cw0,
                                                   const float* __restrict__ cb0,
                                                   const float* __restrict__ cw1,
                                                   const float* __restrict__ cb1,
                                                   float* __restrict__ xc) {
  int idx = blockIdx.x * 256 + threadIdx.x;
  if (idx >= kRows * kCDIM) return;
  int c = idx % kCDIM;
  int row = idx / kCDIM;
  int l = row & (kL - 1);
  int bb = row >> 11;
  int dir = bb >> 2;
  const float* cw = dir ? cw1 : cw0;
  const float* cb = dir ? cb1 : cb0;
  float s = cb[c];
#pragma unroll
  for (int k = 0; k < 4; k++) {
    int ll = l - 3 + k;
    if (ll >= 0) s += zx[((size_t)(bb * kL + ll)) * kDPROJ + kDI + c] * cw[c * 4 + k];
  }
  float sig = 1.f / (1.f + __expf(-s));
  xc[(size_t)row * kCDIM + c] = s * sig;
}

// ---------------- fused softplus(dt) + per-chunk wave-scan cumsum ----------------
__global__ __launch_bounds__(256) void cumsum_kernel(const float* __restrict__ zx,
                                                     const float* __restrict__ db0,
                                                     const float* __restrict__ db1,
                                                     const float* __restrict__ al0,
                                                     const float* __restrict__ al1,
                                                     float* __restrict__ dt,
                                                     float* __restrict__ cs,
                                                     float* __restrict__ g) {
  int t = threadIdx.x;
  int c = t & 63;
  int wid = blockIdx.x * 4 + (t >> 6);  // bb*512 + k*16 + h
  int h = wid & (kNH - 1);
  int k = (wid >> 4) & (kKC - 1);
  int bb = wid >> 9;
  int dir = bb >> 2;
  int row = bb * kL + k * kCH + c;
  float x = zx[(size_t)row * kDPROJ + 2 * kDI + 2 * kDS + h] + (dir ? db1 : db0)[h];
  float dtv = (x > 20.f) ? x : log1pf(expf(x));
  dt[(size_t)row * kNH + h] = dtv;
  float A = -__expf((dir ? al1 : al0)[h]);
  float s = dtv * A;
#pragma unroll
  for (int off = 1; off < 64; off <<= 1) {
    float u = __shfl_up(s, off);
    if (c >= off) s += u;
  }
  cs[(size_t)wid * kCH + c] = s;
  if (c == 63) g[wid] = __expf(s);
}

// ---------------- CB[b,k,i,j] = sum_n C[i,n]*B[j,n], one block per (b,k) ----------------
__global__ __launch_bounds__(256, 4) void cb_kernel(const float* __restrict__ xc,
                                                    float* __restrict__ CB) {
  int bk = blockIdx.x;
  int k = bk & (kKC - 1);
  int bb = bk >> 5;
  __shared__ __align__(16) float Ct[64][72];
  __shared__ __align__(16) float Bt[64][72];
  int t = threadIdx.x;
#pragma unroll
  for (int o = 0; o < 16; o++) {
    int e = t + o * 256;
    int i = e >> 6, n = e & 63;
    size_t base = ((size_t)(bb * kL + k * kCH + i)) * kCDIM;
    Bt[n][i] = xc[base + kDI + n];
    Ct[n][i] = xc[base + kDI + kDS + n];
  }
  __syncthreads();
  int i0 = (t & 15) * 4, j0 = (t >> 4) * 4;
  float acc[4][4] = {};
  for (int n = 0; n < 64; n++) {
    float4 cv = *(const float4*)&Ct[n][i0];
    float4 bv = *(const float4*)&Bt[n][j0];
    float ca[4] = {cv.x, cv.y, cv.z, cv.w};
    float ba[4] = {bv.x, bv.y, bv.z, bv.w};
#pragma unroll
    for (int a = 0; a < 4; a++)
#pragma unroll
      for (int b = 0; b < 4; b++) acc[a][b] += ca[a] * ba[b];
  }
#pragma unroll
  for (int a = 0; a < 4; a++) {
    float4 st = {acc[a][0], acc[a][1], acc[a][2], acc[a][3]};
    *(float4*)&CB[(size_t)bk * 4096 + (i0 + a) * 64 + j0] = st;
  }
}

// ---------------- chunk states[b,k,h,p,n], one block per (b,k,h) ----------------
__global__ __launch_bounds__(256, 6) void states_kernel(const float* __restrict__ xc,
                                                        const float* __restrict__ dt,
                                                        const float* __restrict__ cs,
                                                        float* __restrict__ states) {
  int bkh = blockIdx.x;
  int h = bkh & (kNH - 1);
  int k = (bkh >> 4) & (kKC - 1);
  int bb = bkh >> 9;
  __shared__ __align__(16) float xs_s[64][32];
  __shared__ __align__(16) float Bs[64][64];
  __shared__ float w_s[64];
  int t = threadIdx.x;
  const float* csb = cs + (size_t)bkh * kCH;
  size_t rowbase = (size_t)(bb * kL + k * kCH);
#pragma unroll
  for (int o = 0; o < 2; o++) {
    int f = t + o * 256;
    int j = f >> 3, p4 = (f & 7) * 4;
    *(float4*)&xs_s[j][p4] =
        *(const float4*)&xc[(rowbase + j) * kCDIM + h * 32 + p4];
  }
#pragma unroll
  for (int o = 0; o < 4; o++) {
    int f = t + o * 256;
    int j = f >> 4, n4 = (f & 15) * 4;
    *(float4*)&Bs[j][n4] = *(const float4*)&xc[(rowbase + j) * kCDIM + kDI + n4];
  }
  if (t < 64) {
    float cs63 = csb[63];
    w_s[t] = __expf(cs63 - csb[t]) * dt[(rowbase + t) * kNH + h];
  }
  __syncthreads();
  int p = t >> 3;
  int n0 = (t & 7) * 8;
  float acc[8] = {};
  for (int j = 0; j < 64; j++) {
    float a = w_s[j] * xs_s[j][p];
    float4 b0 = *(const float4*)&Bs[j][n0];
    float4 b1 = *(const float4*)&Bs[j][n0 + 4];
    acc[0] += a * b0.x; acc[1] += a * b0.y; acc[2] += a * b0.z; acc[3] += a * b0.w;
    acc[4] += a * b1.x; acc[5] += a * b1.y; acc[6] += a * b1.z; acc[7] += a * b1.w;
  }
  float4 s0 = {acc[0], acc[1], acc[2], acc[3]};
  float4 s1 = {acc[4], acc[5], acc[6], acc[7]};
  *(float4*)&states[(size_t)bkh * 2048 + p * 64 + n0] = s0;
  *(float4*)&states[(size_t)bkh * 2048 + p * 64 + n0 + 4] = s1;
}

// ---------------- in-place chunk scan: sprev[k]=S; S = g*S + states[k] ----------------
__global__ __launch_bounds__(256) void scan_kernel(float* __restrict__ st,
                                                   const float* __restrict__ g) {
  int idx = blockIdx.x * 256 + threadIdx.x;
  if (idx >= kBB * kNH * 2048) return;
  int pn = idx & 2047;
  int h = (idx >> 11) & (kNH - 1);
  int bb = idx >> 15;
  float S = 0.f;
  for (int k = 0; k < kKC; k++) {
    size_t off = (((size_t)(bb * kKC + k) * kNH + h) * 2048) + pn;
    float v = st[off];
    st[off] = S;
    S = g[(bb * kKC + k) * kNH + h] * S + v;
  }
}

// ---------------- y = att@xh + exp(cs)*(C@Sprev^T) + D*xh, one block per (b,k,h) ----------------
__global__ __launch_bounds__(256, 3) void y_kernel(const float* __restrict__ xc,
                                                   const float* __restrict__ dt,
                                                   const float* __restrict__ cs,
                                                   const float* __restrict__ CB,
                                                   const float* __restrict__ sprev,
                                                   const float* __restrict__ D0,
                                                   const float* __restrict__ D1,
                                                   float* __restrict__ y) {
  int bkh = blockIdx.x;
  int h = bkh & (kNH - 1);
  int k = (bkh >> 4) & (kKC - 1);
  int bb = bkh >> 9;
  int dir = bb >> 2;
  float Dp = (dir ? D1 : D0)[h];
  __shared__ __align__(16) float xs_s[64][32];
  __shared__ float CBs[64][65];
  __shared__ float Cs[64][65];
  __shared__ __align__(16) float sp_t[64][36];
  __shared__ float cs_s[64], dt_s[64];
  int t = threadIdx.x;
  size_t rowbase = (size_t)(bb * kL + k * kCH);
#pragma unroll
  for (int o = 0; o < 2; o++) {
    int f = t + o * 256;
    int j = f >> 3, p4 = (f & 7) * 4;
    *(float4*)&xs_s[j][p4] =
        *(const float4*)&xc[(rowbase + j) * kCDIM + h * 32 + p4];
  }
  int bkq = bb * kKC + k;
#pragma unroll
  for (int o = 0; o < 16; o++) {
    int e = t + o * 256;
    int r = e >> 6, c = e & 63;
    CBs[r][c] = CB[(size_t)bkq * 4096 + e];
    Cs[r][c] = xc[(rowbase + r) * kCDIM + kDI + kDS + c];
  }
#pragma unroll
  for (int o = 0; o < 8; o++) {
    int e = t + o * 256;
    int p = e >> 6, n = e & 63;
    sp_t[n][p] = sprev[(size_t)bkh * 2048 + e];
  }
  if (t < 64) {
    cs_s[t] = cs[(size_t)bkh * kCH + t];
    dt_s[t] = dt[(rowbase + t) * kNH + h];
  }
  __syncthreads();
  int i = t >> 2;
  int p0 = (t & 3) * 8;
  float acc[8] = {};
  float csi = cs_s[i];
  for (int j = 0; j <= i; j++) {
    float f = __expf(csi - cs_s[j]) * dt_s[j] * CBs[i][j];
    float4 x0 = *(const float4*)&xs_s[j][p0];
    float4 x1 = *(const float4*)&xs_s[j][p0 + 4];
    acc[0] += f * x0.x; acc[1] += f * x0.y; acc[2] += f * x0.z; acc[3] += f * x0.w;
    acc[4] += f * x1.x; acc[5] += f * x1.y; acc[6] += f * x1.z; acc[7] += f * x1.w;
  }
  float ecsi = __expf(csi);
  for (int n = 0; n < 64; n++) {
    float cf = ecsi * Cs[i][n];
    float4 s0 = *(const float4*)&sp_t[n][p0];
    float4 s1 = *(const float4*)&sp_t[n][p0 + 4];
    acc[0] += cf * s0.x; acc[1] += cf * s0.y; acc[2] += cf * s0.z; acc[3] += cf * s0.w;
    acc[4] += cf * s1.x; acc[5] += cf * s1.y; acc[6] += cf * s1.z; acc[7] += cf * s1.w;
  }
  float4 xi0 = *(const float4*)&xs_s[i][p0];
  float4 xi1 = *(const float4*)&xs_s[i][p0 + 4];
  float4 o0 = {acc[0] + Dp * xi0.x, acc[1] + Dp * xi0.y, acc[2] + Dp * xi0.z,
               acc[3] + Dp * xi0.w};
  float4 o1 = {acc[4] + Dp * xi1.x, acc[5] + Dp * xi1.y, acc[6] + Dp * xi1.z,
               acc[7] + Dp * xi1.w};
  *(float4*)&y[(rowbase + i) * kDI + h * 32 + p0] = o0;
  *(float4*)&y[(rowbase + i) * kDI + h * 32 + p0 + 4] = o1;
}

// ---------------- y *= silu(z); RMSNorm over 512; *norm_w; bf16 out ----------------
__global__ __launch_bounds__(256) void gate_norm_kernel(const float* __restrict__ zx,
                                                        const float* __restrict__ nw0,
                                                        const float* __restrict__ nw1,
                                                        const float* __restrict__ y,
                                                        ushort* __restrict__ ybf) {
  int row = blockIdx.x;
  int dir = (row >= kRowsD) ? 1 : 0;
  const float* nw = dir ? nw1 : nw0;
  int t = threadIdx.x;
  float v[2];
  float ss = 0.f;
#pragma unroll
  for (int q = 0; q < 2; q++) {
    int e = t + q * 256;
    float z = zx[(size_t)row * kDPROJ + e];
    float gz = z / (1.f + __expf(-z));
    float val = y[(size_t)row * kDI + e] * gz;
    v[q] = val;
    ss += val * val;
  }
  __shared__ float red[4];
#pragma unroll
  for (int o = 32; o > 0; o >>= 1) ss += __shfl_down(ss, o);
  if ((t & 63) == 0) red[t >> 6] = ss;
  __syncthreads();
  float tot = red[0] + red[1] + red[2] + red[3];
  float scale = rsqrtf(tot * (1.0f / kDI) + 1e-5f);
#pragma unroll
  for (int q = 0; q < 2; q++) {
    int e = t + q * 256;
    ybf[(size_t)row * kDI + e] = f2b(v[q] * scale * nw[e]);
  }
}

// ---------------- hcat bf16: [0:256]=h_fw[b,l]; [256:512]=h_bw[b,L-1-l] ----------------
__global__ __launch_bounds__(256) void concat_kernel(const float* __restrict__ h,
                                                     ushort* __restrict__ hcat) {
  int idx = blockIdx.x * 256 + threadIdx.x;
  if (idx >= 4 * kL * 2 * kDM) return;
  int e = idx & 511;
  int l = (idx >> 9) & (kL - 1);
  int b = idx >> 20;
  float v;
  if (e < kDM)
    v = h[((size_t)(b * kL + l)) * kDM + e];
  else
    v = h[((size_t)((4 + b) * kL + (kL - 1 - l))) * kDM + (e - kDM)];
  hcat[idx] = f2b(v);
}

}  // namespace

extern "C" void kernel_launch(void* const* d_in, const int* in_sizes, int n_in,
                              void* d_out, int out_size, void* d_ws, size_t ws_size,
                              hipStream_t stream) {
  const float* x = (const float*)d_in[0];
  const float* fw_ln_w = (const float*)d_in[1];
  const float* fw_ln_b = (const float*)d_in[2];
  const float* fw_win = (const float*)d_in[3];
  const float* fw_convw = (const float*)d_in[4];
  const float* fw_convb = (const float*)d_in[5];
  const float* fw_alog = (const float*)d_in[6];
  const float* fw_dtb = (const float*)d_in[7];
  const float* fw_D = (const float*)d_in[8];
  const float* fw_nw = (const float*)d_in[9];
  const float* fw_wout = (const float*)d_in[10];
  const float* bw_ln_w = (const float*)d_in[11];
  const float* bw_ln_b = (const float*)d_in[12];
  const float* bw_win = (const float*)d_in[13];
  const float* bw_convw = (const float*)d_in[14];
  const float* bw_convb = (const float*)d_in[15];
  const float* bw_alog = (const float*)d_in[16];
  const float* bw_dtb = (const float*)d_in[17];
  const float* bw_D = (const float*)d_in[18];
  const float* bw_nw = (const float*)d_in[19];
  const float* bw_wout = (const float*)d_in[20];
  const float* fusion_w = (const float*)d_in[21];
  float* out = (float*)d_out;

  float* ws = (float*)d_ws;
  float* h = ws;                                   // 16384*256
  float* zx = h + (size_t)kRows * kDM;             // 16384*1168
  float* xc = zx + (size_t)kRows * kDPROJ;         // 16384*640
  float* dt = xc + (size_t)kRows * kCDIM;          // 16384*16
  float* cs = dt + (size_t)kRows * kNH;            // 4096*64
  float* g = cs + (size_t)kBB * kKC * kNH * kCH;   // 4096
  float* CB = g + (size_t)kBB * kKC * kNH;         // 256*4096
  float* states = CB + (size_t)kBB * kKC * 4096;   // 4096*2048 (doubles as sprev)
  float* y = states + (size_t)kBB * kKC * kNH * 2048;  // 16384*512
  ushort* xnbf = (ushort*)(y + (size_t)kRows * kDI);   // 16384*256 (also hcat)
  ushort* ybf = xnbf + (size_t)kRows * kDM;            // 16384*512
  ushort* winbf = ybf + (size_t)kRows * kDI;           // 2*8*1168*256
  ushort* woutbf = winbf + (size_t)2 * 8 * kDPROJ * kDM;  // 2*8*256*512
  ushort* fusbf = woutbf + (size_t)2 * 8 * kDM * kDI;     // 256*512
  ushort* hcatbf = xnbf;

  // weight conversion (once per launch)
  {
    int nw1 = 8 * kDPROJ * kDM / 4;
    f2b_kernel<<<(nw1 + 255) / 256, 256, 0, stream>>>(fw_win, winbf, nw1);
    f2b_kernel<<<(nw1 + 255) / 256, 256, 0, stream>>>(bw_win,
                                                      winbf + (size_t)8 * kDPROJ * kDM, nw1);
    int nw2 = 8 * kDM * kDI / 4;
    f2b_kernel<<<(nw2 + 255) / 256, 256, 0, stream>>>(fw_wout, woutbf, nw2);
    f2b_kernel<<<(nw2 + 255) / 256, 256, 0, stream>>>(bw_wout,
                                                      woutbf + (size_t)8 * kDM * kDI, nw2);
    int nw3 = kDM * kDI / 4;
    f2b_kernel<<<(nw3 + 255) / 256, 256, 0, stream>>>(fusion_w, fusbf, nw3);
  }

  init_h_kernel<<<(4 * kL * kDM + 255) / 256, 256, 0, stream>>>(x, h);

  for (int i = 0; i < 8; i++) {
    const size_t oLN = (size_t)i * kDM;
    const size_t oCW = (size_t)i * kCDIM * 4;
    const size_t oCB = (size_t)i * kCDIM;
    const size_t oH = (size_t)i * kNH;
    const size_t oNW = (size_t)i * kDI;
    const ushort* win0 = winbf + (size_t)i * kDPROJ * kDM;
    const ushort* win1 = winbf + (size_t)(8 + i) * kDPROJ * kDM;
    const ushort* wout0 = woutbf + (size_t)i * kDM * kDI;
    const ushort* wout1 = woutbf + (size_t)(8 + i) * kDM * kDI;

    ln_kernel<<<kRows, 256, 0, stream>>>(h, fw_ln_w + oLN, fw_ln_b + oLN,
                                         bw_ln_w + oLN, bw_ln_b + oLN, xnbf);
    {
      dim3 grid((kDPROJ + 127) / 128, kRowsD / 128, 2);
      gemm_bf16<<<grid, 256, 0, stream>>>(xnbf, win0, win1, zx, kRowsD, kDPROJ,
                                          kDM, 0);
    }
    conv_kernel<<<(kRows * kCDIM + 255) / 256, 256, 0, stream>>>(
        zx, fw_convw + oCW, fw_convb + oCB, bw_convw + oCW, bw_convb + oCB, xc);
    cumsum_kernel<<<kBB * kKC * kNH / 4, 256, 0, stream>>>(
        zx, fw_dtb + oH, bw_dtb + oH, fw_alog + oH, bw_alog + oH, dt, cs, g);
    cb_kernel<<<kBB * kKC, 256, 0, stream>>>(xc, CB);
    states_kernel<<<kBB * kKC * kNH, 256, 0, stream>>>(xc, dt, cs, states);
    scan_kernel<<<(kBB * kNH * 2048 + 255) / 256, 256, 0, stream>>>(states, g);
    y_kernel<<<kBB * kKC * kNH, 256, 0, stream>>>(xc, dt, cs, CB, states, fw_D + oH,
                                                  bw_D + oH, y);
    gate_norm_kernel<<<kRows, 256, 0, stream>>>(zx, fw_nw + oNW, bw_nw + oNW, y, ybf);
    {
      dim3 grid(kDM / 128, kRowsD / 128, 2);
      gemm_bf16<<<grid, 256, 0, stream>>>(ybf, wout0, wout1, h, kRowsD, kDM, kDI, 1);
    }
  }

  concat_kernel<<<(4 * kL * 2 * kDM + 255) / 256, 256, 0, stream>>>(h, hcatbf);
  {
    dim3 grid(kDM / 128, kRowsD / 128, 1);
    gemm_bf16<<<grid, 256, 0, stream>>>(hcatbf, fusbf, fusbf, out, kRowsD, kDM,
                                        2 * kDM, 0);
  }
}

// Round 5
// 1463.910 us; speedup vs baseline: 5.0416x; 1.3807x over previous
//
#include <hip/hip_runtime.h>
#include <math.h>

// BiMambaEncoder: 8-layer bidirectional Mamba2 stack.
// Round 5: round-4 MFMA SSD with the states_kernel B-transpose bug fixed
// (transpose loop covered only 2048 of 4096 elements -> Bt[32..63][*] garbage).

namespace {

constexpr int kL = 2048;
constexpr int kDM = 256;
constexpr int kDI = 512;
constexpr int kNH = 16;
constexpr int kDS = 64;
constexpr int kCDIM = 640;
constexpr int kDPROJ = 1168;
constexpr int kCH = 64;
constexpr int kKC = 32;
constexpr int kBB = 8;
constexpr int kRowsD = 4 * kL;
constexpr int kRows = kBB * kL;

typedef __bf16 bf16x8 __attribute__((ext_vector_type(8)));
typedef float f32x4 __attribute__((ext_vector_type(4)));
typedef unsigned short ushort;

union U16x8 {
  int4 v;
  ushort u[8];
  bf16x8 b;
};

__device__ __forceinline__ ushort f2b(float x) {
  union { float f; unsigned u; } c;
  c.f = x;
  unsigned r = c.u + 0x7fffu + ((c.u >> 16) & 1u);
  return (ushort)(r >> 16);
}
__device__ __forceinline__ float b2f(ushort u) {
  union { unsigned u; float f; } c;
  c.u = ((unsigned)u) << 16;
  return c.f;
}

__device__ __forceinline__ void gl_lds16(const void* g, void* l) {
  __builtin_amdgcn_global_load_lds(
      (const __attribute__((address_space(1))) unsigned int*)g,
      (__attribute__((address_space(3))) unsigned int*)l, 16, 0, 0);
}

// ---------------- fp32 -> bf16 conversion (4-wide) ----------------
__global__ __launch_bounds__(256) void f2b_kernel(const float* __restrict__ src,
                                                  ushort* __restrict__ dst, int n4) {
  int i = blockIdx.x * 256 + threadIdx.x;
  if (i >= n4) return;
  float4 v = *(const float4*)&src[i * 4];
  ushort4 o = {f2b(v.x), f2b(v.y), f2b(v.z), f2b(v.w)};
  *(ushort4*)&dst[i * 4] = o;
}

// ---------------- init: h[0..3]=x, h[4..7]=flip(x) ----------------
__global__ __launch_bounds__(256) void init_h_kernel(const float* __restrict__ x,
                                                     float* __restrict__ h) {
  int idx = blockIdx.x * 256 + threadIdx.x;
  if (idx >= 4 * kL * kDM) return;
  int d = idx & (kDM - 1);
  int l = (idx >> 8) & (kL - 1);
  int b = idx >> 19;
  float v = x[idx];
  h[idx] = v;
  h[((size_t)((4 + b) * kL + (kL - 1 - l))) * kDM + d] = v;
}

// ---------------- LayerNorm over 256, bf16 out ----------------
__global__ __launch_bounds__(256) void ln_kernel(const float* __restrict__ h,
                                                 const float* __restrict__ w0,
                                                 const float* __restrict__ b0,
                                                 const float* __restrict__ w1,
                                                 const float* __restrict__ b1,
                                                 ushort* __restrict__ xn) {
  int row = blockIdx.x;
  int dir = (row >= kRowsD) ? 1 : 0;
  const float* w = dir ? w1 : w0;
  const float* b = dir ? b1 : b0;
  int t = threadIdx.x;
  float v = h[(size_t)row * kDM + t];
  __shared__ float red[4];
  float s = v;
#pragma unroll
  for (int o = 32; o > 0; o >>= 1) s += __shfl_down(s, o);
  if ((t & 63) == 0) red[t >> 6] = s;
  __syncthreads();
  float mu = (red[0] + red[1] + red[2] + red[3]) * (1.0f / kDM);
  __syncthreads();
  float d = v - mu;
  s = d * d;
#pragma unroll
  for (int o = 32; o > 0; o >>= 1) s += __shfl_down(s, o);
  if ((t & 63) == 0) red[t >> 6] = s;
  __syncthreads();
  float var = (red[0] + red[1] + red[2] + red[3]) * (1.0f / kDM);
  float r = rsqrtf(var + 1e-5f);
  xn[(size_t)row * kDM + t] = f2b(d * r * w[t] + b[t]);
}

// ---------------- bf16 MFMA GEMM: C[Md,N] (+)= A[Md,K] @ W[N,K]^T ----------------
__global__ __launch_bounds__(256) void gemm_bf16(const ushort* __restrict__ A,
                                                 const ushort* __restrict__ W0,
                                                 const ushort* __restrict__ W1,
                                                 float* __restrict__ C, int Md, int N,
                                                 int K, int accumulate) {
  int dir = blockIdx.z;
  const ushort* W = dir ? W1 : W0;
  const ushort* Ab = A + (size_t)dir * Md * K;
  float* Cb = C + (size_t)dir * Md * N;
  int m0 = blockIdx.y * 128;
  int n0 = blockIdx.x * 128;
  __shared__ __align__(16) ushort As[128 * 32];
  __shared__ __align__(16) ushort Ws[128 * 32];
  int tid = threadIdx.x;
  int lane = tid & 63;
  int wv = tid >> 6;
  int wr = (wv >> 1) * 64, wc = (wv & 1) * 64;
  int l16 = lane & 15, lk = lane >> 4;
  int rA = tid >> 2;
  int cA = (tid & 3) * 8;
  char* ldsA = (char*)As + wv * 1024;
  char* ldsB = (char*)Ws + wv * 1024;
  int rb0 = n0 + rA;       if (rb0 >= N) rb0 = N - 1;
  int rb1 = n0 + rA + 64;  if (rb1 >= N) rb1 = N - 1;

  f32x4 acc[4][4];
#pragma unroll
  for (int m = 0; m < 4; m++)
#pragma unroll
    for (int n = 0; n < 4; n++) acc[m][n] = {0.f, 0.f, 0.f, 0.f};

  for (int k0 = 0; k0 < K; k0 += 32) {
    gl_lds16(Ab + (size_t)(m0 + rA) * K + k0 + cA, ldsA);
    gl_lds16(Ab + (size_t)(m0 + rA + 64) * K + k0 + cA, ldsA + 4096);
    gl_lds16(W + (size_t)rb0 * K + k0 + cA, ldsB);
    gl_lds16(W + (size_t)rb1 * K + k0 + cA, ldsB + 4096);
    __syncthreads();
    bf16x8 a[4], b[4];
#pragma unroll
    for (int m = 0; m < 4; m++)
      a[m] = *(const bf16x8*)((const char*)As +
                              (((wr + m * 16 + l16) * 32 + lk * 8) << 1));
#pragma unroll
    for (int n = 0; n < 4; n++)
      b[n] = *(const bf16x8*)((const char*)Ws +
                              (((wc + n * 16 + l16) * 32 + lk * 8) << 1));
#pragma unroll
    for (int m = 0; m < 4; m++)
#pragma unroll
      for (int n = 0; n < 4; n++)
        acc[m][n] =
            __builtin_amdgcn_mfma_f32_16x16x32_bf16(a[m], b[n], acc[m][n], 0, 0, 0);
    __syncthreads();
  }
#pragma unroll
  for (int m = 0; m < 4; m++) {
#pragma unroll
    for (int n = 0; n < 4; n++) {
      int col = n0 + wc + n * 16 + l16;
      if (col < N) {
#pragma unroll
        for (int r = 0; r < 4; r++) {
          int row = m0 + wr + m * 16 + lk * 4 + r;
          size_t idx = (size_t)row * N + col;
          float v = acc[m][n][r];
          if (accumulate) Cb[idx] += v;
          else Cb[idx] = v;
        }
      }
    }
  }
}

// ---------------- causal conv (width 4) + silu, bf16 out, 4 ch/thread ----------------
__global__ __launch_bounds__(256) void conv_kernel(const float* __restrict__ zx,
                                                   const float* __restrict__ cw0,
                                                   const float* __restrict__ cb0,
                                                   const float* __restrict__ cw1,
                                                   const float* __restrict__ cb1,
                                                   ushort* __restrict__ xcb) {
  int idx = blockIdx.x * 256 + threadIdx.x;
  if (idx >= kRows * (kCDIM / 4)) return;
  int c4 = (idx % (kCDIM / 4)) * 4;
  int row = idx / (kCDIM / 4);
  int l = row & (kL - 1);
  int bb = row >> 11;
  int dir = bb >> 2;
  const float* cw = dir ? cw1 : cw0;
  const float* cb = dir ? cb1 : cb0;
  float wt[4][4];
#pragma unroll
  for (int c = 0; c < 4; c++) {
    float4 w = *(const float4*)&cw[(c4 + c) * 4];
    wt[c][0] = w.x; wt[c][1] = w.y; wt[c][2] = w.z; wt[c][3] = w.w;
  }
  float4 bias = *(const float4*)&cb[c4];
  float acc[4] = {bias.x, bias.y, bias.z, bias.w};
#pragma unroll
  for (int kk = 0; kk < 4; kk++) {
    int ll = l - 3 + kk;
    if (ll < 0) continue;
    float4 v = *(const float4*)&zx[((size_t)(bb * kL + ll)) * kDPROJ + kDI + c4];
    acc[0] += v.x * wt[0][kk];
    acc[1] += v.y * wt[1][kk];
    acc[2] += v.z * wt[2][kk];
    acc[3] += v.w * wt[3][kk];
  }
  ushort4 o;
  {
    float s0 = acc[0] / (1.f + __expf(-acc[0]));
    float s1 = acc[1] / (1.f + __expf(-acc[1]));
    float s2 = acc[2] / (1.f + __expf(-acc[2]));
    float s3 = acc[3] / (1.f + __expf(-acc[3]));
    o = {f2b(s0), f2b(s1), f2b(s2), f2b(s3)};
  }
  *(ushort4*)&xcb[(size_t)row * kCDIM + c4] = o;
}

// ---------------- fused softplus(dt) + per-chunk wave-scan cumsum ----------------
__global__ __launch_bounds__(256) void cumsum_kernel(const float* __restrict__ zx,
                                                     const float* __restrict__ db0,
                                                     const float* __restrict__ db1,
                                                     const float* __restrict__ al0,
                                                     const float* __restrict__ al1,
                                                     float* __restrict__ dt,
                                                     float* __restrict__ cs,
                                                     float* __restrict__ g) {
  int t = threadIdx.x;
  int c = t & 63;
  int wid = blockIdx.x * 4 + (t >> 6);
  int h = wid & (kNH - 1);
  int k = (wid >> 4) & (kKC - 1);
  int bb = wid >> 9;
  int dir = bb >> 2;
  int row = bb * kL + k * kCH + c;
  float x = zx[(size_t)row * kDPROJ + 2 * kDI + 2 * kDS + h] + (dir ? db1 : db0)[h];
  float dtv = (x > 20.f) ? x : log1pf(expf(x));
  dt[(size_t)row * kNH + h] = dtv;
  float A = -__expf((dir ? al1 : al0)[h]);
  float s = dtv * A;
#pragma unroll
  for (int off = 1; off < 64; off <<= 1) {
    float u = __shfl_up(s, off);
    if (c >= off) s += u;
  }
  cs[(size_t)wid * kCH + c] = s;
  if (c == 63) g[wid] = __expf(s);
}

// ---------------- MFMA states: one block per (b,k), wave per head ----------------
__global__ __launch_bounds__(256) void states_kernel(const ushort* __restrict__ xcb,
                                                     const float* __restrict__ dt,
                                                     const float* __restrict__ cs,
                                                     float* __restrict__ states) {
  int bk = blockIdx.x;
  int k = bk & (kKC - 1);
  int bb = bk >> 5;
  __shared__ __align__(16) ushort Bstage[64][72];
  __shared__ __align__(16) ushort Bt[64][72];   // Bt[n][j]
  __shared__ __align__(16) ushort Ap[4][32][72];  // per-wave A' = w*xs^T
  __shared__ float w_s[16][64];
  int t = threadIdx.x;
  int lane = t & 63, wv = t >> 6;
  size_t rowbase = (size_t)(bb * kL + k * kCH);
  {
    int j = t >> 2, n0 = (t & 3) * 16;
    const ushort* src = xcb + (rowbase + j) * kCDIM + kDI + n0;
    *(int4*)&Bstage[j][n0] = *(const int4*)src;
    *(int4*)&Bstage[j][n0 + 8] = *(const int4*)(src + 8);
  }
#pragma unroll
  for (int i = 0; i < 4; i++) {
    int e = t + i * 256;
    int h = e >> 6, c = e & 63;
    const float* csb = cs + ((size_t)bk * 16 + h) * kCH;
    w_s[h][c] = __expf(csb[63] - csb[c]) * dt[(rowbase + c) * kNH + h];
  }
  __syncthreads();
  // transpose B -> Bt : 64x64 = 4096 elements needs 16 iterations (BUGFIX)
#pragma unroll
  for (int i = 0; i < 16; i++) {
    int e = t + i * 256;
    int j = e & 63, n = e >> 6;
    Bt[n][j] = Bstage[j][n];
  }
  __syncthreads();
  int l15 = lane & 15, lk8 = (lane >> 4) * 8;
  for (int hg = 0; hg < 4; hg++) {
    int h = hg * 4 + wv;
    float wl = w_s[h][lane];
    const ushort* xrow = xcb + (rowbase + lane) * kCDIM + h * 32;
#pragma unroll
    for (int q4 = 0; q4 < 4; q4++) {
      U16x8 v;
      v.v = *(const int4*)(xrow + q4 * 8);
#pragma unroll
      for (int q = 0; q < 8; q++)
        Ap[wv][q4 * 8 + q][lane] = f2b(b2f(v.u[q]) * wl);
    }
#pragma unroll
    for (int pt = 0; pt < 2; pt++) {
#pragma unroll
      for (int nt = 0; nt < 4; nt++) {
        f32x4 acc = {0.f, 0.f, 0.f, 0.f};
#pragma unroll
        for (int kt = 0; kt < 2; kt++) {
          bf16x8 a = *(const bf16x8*)&Ap[wv][pt * 16 + l15][kt * 32 + lk8];
          bf16x8 b = *(const bf16x8*)&Bt[nt * 16 + l15][kt * 32 + lk8];
          acc = __builtin_amdgcn_mfma_f32_16x16x32_bf16(a, b, acc, 0, 0, 0);
        }
        size_t base = ((size_t)bk * 16 + h) * 2048;
#pragma unroll
        for (int r = 0; r < 4; r++) {
          int p = pt * 16 + (lane >> 4) * 4 + r;
          states[base + p * 64 + nt * 16 + l15] = acc[r];
        }
      }
    }
  }
}

// ---------------- chunk scan: sprev (bf16) = running S; S = g*S + states ----------------
__global__ __launch_bounds__(256) void scan_kernel(const float* __restrict__ st,
                                                   const float* __restrict__ g,
                                                   ushort* __restrict__ spbf) {
  int idx = blockIdx.x * 256 + threadIdx.x;
  if (idx >= kBB * kNH * 2048) return;
  int pn = idx & 2047;
  int h = (idx >> 11) & (kNH - 1);
  int bb = idx >> 15;
  float S = 0.f;
  for (int k = 0; k < kKC; k++) {
    size_t off = (((size_t)(bb * kKC + k) * kNH + h) * 2048) + pn;
    spbf[off] = f2b(S);
    S = g[(bb * kKC + k) * kNH + h] * S + st[off];
  }
}

// ---------------- fused y: per (b,k,half-heads); CB in LDS; MFMA intra+inter ----------------
__global__ __launch_bounds__(256) void y_kernel(const ushort* __restrict__ xcb,
                                                const float* __restrict__ dt,
                                                const float* __restrict__ cs,
                                                const ushort* __restrict__ spbf,
                                                const float* __restrict__ D0,
                                                const float* __restrict__ D1,
                                                float* __restrict__ y) {
  int bid = blockIdx.x;
  int hh = bid & 1;
  int bk = bid >> 1;
  int k = bk & (kKC - 1);
  int bb = bk >> 5;
  int dir = bb >> 2;
  __shared__ __align__(16) ushort Cls[64][72];
  __shared__ __align__(16) ushort Bls[64][72];
  __shared__ float CBT[64][67];  // CBT[j][i] = CB[i][j]
  __shared__ __align__(16) ushort xs_s[64][40];
  __shared__ __align__(16) ushort xsT[32][72];
  __shared__ __align__(16) ushort sp_s[32][72];
  __shared__ float cs_s[64], dt_s[64], ecs_s[64];
  int t = threadIdx.x, lane = t & 63, wv = t >> 6;
  int l15 = lane & 15, lk8 = (lane >> 4) * 8;
  size_t rowbase = (size_t)(bb * kL + k * kCH);
  {
    int j = t >> 2, n0 = (t & 3) * 16;
    const ushort* pB = xcb + (rowbase + j) * kCDIM + kDI;
    *(int4*)&Bls[j][n0] = *(const int4*)(pB + n0);
    *(int4*)&Bls[j][n0 + 8] = *(const int4*)(pB + n0 + 8);
    *(int4*)&Cls[j][n0] = *(const int4*)(pB + kDS + n0);
    *(int4*)&Cls[j][n0 + 8] = *(const int4*)(pB + kDS + n0 + 8);
  }
  __syncthreads();
  {
    int i0 = wv * 16;
#pragma unroll
    for (int jt = 0; jt < 4; jt++) {
      f32x4 acc = {0.f, 0.f, 0.f, 0.f};
#pragma unroll
      for (int kt = 0; kt < 2; kt++) {
        bf16x8 a = *(const bf16x8*)&Cls[i0 + l15][kt * 32 + lk8];
        bf16x8 b = *(const bf16x8*)&Bls[jt * 16 + l15][kt * 32 + lk8];
        acc = __builtin_amdgcn_mfma_f32_16x16x32_bf16(a, b, acc, 0, 0, 0);
      }
#pragma unroll
      for (int r = 0; r < 4; r++)
        CBT[jt * 16 + l15][i0 + (lane >> 4) * 4 + r] = acc[r];
    }
  }
  for (int hi = 0; hi < 8; hi++) {
    int h = hh * 8 + hi;
    int bkh = bk * 16 + h;
    float Dp = (dir ? D1 : D0)[h];
    __syncthreads();
    {
      int j = t >> 2, p0 = (t & 3) * 8;
      U16x8 v;
      v.v = *(const int4*)(xcb + (rowbase + j) * kCDIM + h * 32 + p0);
      *(int4*)&xs_s[j][p0] = v.v;
#pragma unroll
      for (int q = 0; q < 8; q++) xsT[p0 + q][j] = v.u[q];
      int4 s = *(const int4*)(spbf + (size_t)bkh * 2048 + t * 8);
      *(int4*)&sp_s[t >> 3][(t & 7) * 8] = s;
      if (t < 64) {
        float cv = cs[(size_t)bkh * kCH + t];
        cs_s[t] = cv;
        ecs_s[t] = __expf(cv);
        dt_s[t] = dt[(rowbase + t) * kNH + h];
      }
    }
    __syncthreads();
    int i0 = wv * 16;
    int ia = i0 + l15;
    float csi = cs_s[ia];
    U16x8 af[2];
#pragma unroll
    for (int kt = 0; kt < 2; kt++) {
#pragma unroll
      for (int q = 0; q < 8; q++) {
        int j = kt * 32 + lk8 + q;
        float v = 0.f;
        if (j <= ia) v = __expf(csi - cs_s[j]) * dt_s[j] * CBT[j][ia];
        af[kt].u[q] = f2b(v);
      }
    }
#pragma unroll
    for (int pt = 0; pt < 2; pt++) {
      f32x4 acc = {0.f, 0.f, 0.f, 0.f};
      f32x4 acc2 = {0.f, 0.f, 0.f, 0.f};
#pragma unroll
      for (int kt = 0; kt < 2; kt++) {
        bf16x8 bx = *(const bf16x8*)&xsT[pt * 16 + l15][kt * 32 + lk8];
        acc = __builtin_amdgcn_mfma_f32_16x16x32_bf16(af[kt].b, bx, acc, 0, 0, 0);
        bf16x8 ac = *(const bf16x8*)&Cls[i0 + l15][kt * 32 + lk8];
        bf16x8 bs = *(const bf16x8*)&sp_s[pt * 16 + l15][kt * 32 + lk8];
        acc2 = __builtin_amdgcn_mfma_f32_16x16x32_bf16(ac, bs, acc2, 0, 0, 0);
      }
#pragma unroll
      for (int r = 0; r < 4; r++) {
        int io = i0 + (lane >> 4) * 4 + r;
        int p = pt * 16 + l15;
        float xsv = b2f(xs_s[io][p]);
        float v = acc[r] + ecs_s[io] * acc2[r] + Dp * xsv;
        y[(rowbase + io) * kDI + h * 32 + p] = v;
      }
    }
  }
}

// ---------------- y *= silu(z); RMSNorm over 512; *norm_w; bf16 out ----------------
__global__ __launch_bounds__(256) void gate_norm_kernel(const float* __restrict__ zx,
                                                        const float* __restrict__ nw0,
                                                        const float* __restrict__ nw1,
                                                        const float* __restrict__ y,
                                                        ushort* __restrict__ ybf) {
  int row = blockIdx.x;
  int dir = (row >= kRowsD) ? 1 : 0;
  const float* nw = dir ? nw1 : nw0;
  int t = threadIdx.x;
  float v[2];
  float ss = 0.f;
#pragma unroll
  for (int q = 0; q < 2; q++) {
    int e = t + q * 256;
    float z = zx[(size_t)row * kDPROJ + e];
    float gz = z / (1.f + __expf(-z));
    float val = y[(size_t)row * kDI + e] * gz;
    v[q] = val;
    ss += val * val;
  }
  __shared__ float red[4];
#pragma unroll
  for (int o = 32; o > 0; o >>= 1) ss += __shfl_down(ss, o);
  if ((t & 63) == 0) red[t >> 6] = ss;
  __syncthreads();
  float tot = red[0] + red[1] + red[2] + red[3];
  float scale = rsqrtf(tot * (1.0f / kDI) + 1e-5f);
#pragma unroll
  for (int q = 0; q < 2; q++) {
    int e = t + q * 256;
    ybf[(size_t)row * kDI + e] = f2b(v[q] * scale * nw[e]);
  }
}

// ---------------- hcat bf16 ----------------
__global__ __launch_bounds__(256) void concat_kernel(const float* __restrict__ h,
                                                     ushort* __restrict__ hcat) {
  int idx = blockIdx.x * 256 + threadIdx.x;
  if (idx >= 4 * kL * 2 * kDM) return;
  int e = idx & 511;
  int l = (idx >> 9) & (kL - 1);
  int b = idx >> 20;
  float v;
  if (e < kDM)
    v = h[((size_t)(b * kL + l)) * kDM + e];
  else
    v = h[((size_t)((4 + b) * kL + (kL - 1 - l))) * kDM + (e - kDM)];
  hcat[idx] = f2b(v);
}

}  // namespace

extern "C" void kernel_launch(void* const* d_in, const int* in_sizes, int n_in,
                              void* d_out, int out_size, void* d_ws, size_t ws_size,
                              hipStream_t stream) {
  const float* x = (const float*)d_in[0];
  const float* fw_ln_w = (const float*)d_in[1];
  const float* fw_ln_b = (const float*)d_in[2];
  const float* fw_win = (const float*)d_in[3];
  const float* fw_convw = (const float*)d_in[4];
  const float* fw_convb = (const float*)d_in[5];
  const float* fw_alog = (const float*)d_in[6];
  const float* fw_dtb = (const float*)d_in[7];
  const float* fw_D = (const float*)d_in[8];
  const float* fw_nw = (const float*)d_in[9];
  const float* fw_wout = (const float*)d_in[10];
  const float* bw_ln_w = (const float*)d_in[11];
  const float* bw_ln_b = (const float*)d_in[12];
  const float* bw_win = (const float*)d_in[13];
  const float* bw_convw = (const float*)d_in[14];
  const float* bw_convb = (const float*)d_in[15];
  const float* bw_alog = (const float*)d_in[16];
  const float* bw_dtb = (const float*)d_in[17];
  const float* bw_D = (const float*)d_in[18];
  const float* bw_nw = (const float*)d_in[19];
  const float* bw_wout = (const float*)d_in[20];
  const float* fusion_w = (const float*)d_in[21];
  float* out = (float*)d_out;

  float* ws = (float*)d_ws;
  float* h = ws;                                  // 16384*256
  float* zx = h + (size_t)kRows * kDM;            // 16384*1168
  float* dt = zx + (size_t)kRows * kDPROJ;        // 16384*16
  float* cs = dt + (size_t)kRows * kNH;           // 4096*64
  float* g = cs + (size_t)kBB * kKC * kNH * kCH;  // 4096
  float* states = g + (size_t)kBB * kKC * kNH;    // 4096*2048
  float* y = states + (size_t)kBB * kKC * kNH * 2048;  // 16384*512
  ushort* xcb = (ushort*)(y + (size_t)kRows * kDI);    // 16384*640
  ushort* spbf = xcb + (size_t)kRows * kCDIM;          // 4096*2048
  ushort* xnbf = spbf + (size_t)kBB * kKC * kNH * 2048;  // 16384*256 (also hcat)
  ushort* ybf = xnbf + (size_t)kRows * kDM;              // 16384*512
  ushort* winbf = ybf + (size_t)kRows * kDI;             // 2*8*1168*256
  ushort* woutbf = winbf + (size_t)2 * 8 * kDPROJ * kDM; // 2*8*256*512
  ushort* fusbf = woutbf + (size_t)2 * 8 * kDM * kDI;    // 256*512
  ushort* hcatbf = xnbf;

  {
    int nw1 = 8 * kDPROJ * kDM / 4;
    f2b_kernel<<<(nw1 + 255) / 256, 256, 0, stream>>>(fw_win, winbf, nw1);
    f2b_kernel<<<(nw1 + 255) / 256, 256, 0, stream>>>(
        bw_win, winbf + (size_t)8 * kDPROJ * kDM, nw1);
    int nw2 = 8 * kDM * kDI / 4;
    f2b_kernel<<<(nw2 + 255) / 256, 256, 0, stream>>>(fw_wout, woutbf, nw2);
    f2b_kernel<<<(nw2 + 255) / 256, 256, 0, stream>>>(
        bw_wout, woutbf + (size_t)8 * kDM * kDI, nw2);
    int nw3 = kDM * kDI / 4;
    f2b_kernel<<<(nw3 + 255) / 256, 256, 0, stream>>>(fusion_w, fusbf, nw3);
  }

  init_h_kernel<<<(4 * kL * kDM + 255) / 256, 256, 0, stream>>>(x, h);

  for (int i = 0; i < 8; i++) {
    const size_t oLN = (size_t)i * kDM;
    const size_t oCW = (size_t)i * kCDIM * 4;
    const size_t oCB = (size_t)i * kCDIM;
    const size_t oH = (size_t)i * kNH;
    const size_t oNW = (size_t)i * kDI;
    const ushort* win0 = winbf + (size_t)i * kDPROJ * kDM;
    const ushort* win1 = winbf + (size_t)(8 + i) * kDPROJ * kDM;
    const ushort* wout0 = woutbf + (size_t)i * kDM * kDI;
    const ushort* wout1 = woutbf + (size_t)(8 + i) * kDM * kDI;

    ln_kernel<<<kRows, 256, 0, stream>>>(h, fw_ln_w + oLN, fw_ln_b + oLN,
                                         bw_ln_w + oLN, bw_ln_b + oLN, xnbf);
    {
      dim3 grid((kDPROJ + 127) / 128, kRowsD / 128, 2);
      gemm_bf16<<<grid, 256, 0, stream>>>(xnbf, win0, win1, zx, kRowsD, kDPROJ,
                                          kDM, 0);
    }
    conv_kernel<<<(kRows * (kCDIM / 4) + 255) / 256, 256, 0, stream>>>(
        zx, fw_convw + oCW, fw_convb + oCB, bw_convw + oCW, bw_convb + oCB, xcb);
    cumsum_kernel<<<kBB * kKC * kNH / 4, 256, 0, stream>>>(
        zx, fw_dtb + oH, bw_dtb + oH, fw_alog + oH, bw_alog + oH, dt, cs, g);
    states_kernel<<<kBB * kKC, 256, 0, stream>>>(xcb, dt, cs, states);
    scan_kernel<<<(kBB * kNH * 2048 + 255) / 256, 256, 0, stream>>>(states, g, spbf);
    y_kernel<<<kBB * kKC * 2, 256, 0, stream>>>(xcb, dt, cs, spbf, fw_D + oH,
                                                bw_D + oH, y);
    gate_norm_kernel<<<kRows, 256, 0, stream>>>(zx, fw_nw + oNW, bw_nw + oNW, y, ybf);
    {
      dim3 grid(kDM / 128, kRowsD / 128, 2);
      gemm_bf16<<<grid, 256, 0, stream>>>(ybf, wout0, wout1, h, kRowsD, kDM, kDI, 1);
    }
  }

  concat_kernel<<<(4 * kL * 2 * kDM + 255) / 256, 256, 0, stream>>>(h, hcatbf);
  {
    dim3 grid(kDM / 128, kRowsD / 128, 1);
    gemm_bf16<<<grid, 256, 0, stream>>>(hcatbf, fusbf, fusbf, out, kRowsD, kDM,
                                        2 * kDM, 0);
  }
}

// Round 6
// 1204.303 us; speedup vs baseline: 6.1284x; 1.2156x over previous
//
#include <hip/hip_runtime.h>
#include <math.h>

// BiMambaEncoder: 8-layer bidirectional Mamba2 stack.
// Round 6: conv rewritten as 16-row/thread streaming (4x fewer vmem instrs);
// ln + gate_norm rewritten wave-per-row (shfl_xor reductions, no LDS).

namespace {

constexpr int kL = 2048;
constexpr int kDM = 256;
constexpr int kDI = 512;
constexpr int kNH = 16;
constexpr int kDS = 64;
constexpr int kCDIM = 640;
constexpr int kDPROJ = 1168;
constexpr int kCH = 64;
constexpr int kKC = 32;
constexpr int kBB = 8;
constexpr int kRowsD = 4 * kL;
constexpr int kRows = kBB * kL;

typedef __bf16 bf16x8 __attribute__((ext_vector_type(8)));
typedef float f32x4 __attribute__((ext_vector_type(4)));
typedef unsigned short ushort;

union U16x8 {
  int4 v;
  ushort u[8];
  bf16x8 b;
};

__device__ __forceinline__ ushort f2b(float x) {
  union { float f; unsigned u; } c;
  c.f = x;
  unsigned r = c.u + 0x7fffu + ((c.u >> 16) & 1u);
  return (ushort)(r >> 16);
}
__device__ __forceinline__ float b2f(ushort u) {
  union { unsigned u; float f; } c;
  c.u = ((unsigned)u) << 16;
  return c.f;
}

__device__ __forceinline__ void gl_lds16(const void* g, void* l) {
  __builtin_amdgcn_global_load_lds(
      (const __attribute__((address_space(1))) unsigned int*)g,
      (__attribute__((address_space(3))) unsigned int*)l, 16, 0, 0);
}

// ---------------- fp32 -> bf16 conversion (4-wide) ----------------
__global__ __launch_bounds__(256) void f2b_kernel(const float* __restrict__ src,
                                                  ushort* __restrict__ dst, int n4) {
  int i = blockIdx.x * 256 + threadIdx.x;
  if (i >= n4) return;
  float4 v = *(const float4*)&src[i * 4];
  ushort4 o = {f2b(v.x), f2b(v.y), f2b(v.z), f2b(v.w)};
  *(ushort4*)&dst[i * 4] = o;
}

// ---------------- init: h[0..3]=x, h[4..7]=flip(x) ----------------
__global__ __launch_bounds__(256) void init_h_kernel(const float* __restrict__ x,
                                                     float* __restrict__ h) {
  int idx = blockIdx.x * 256 + threadIdx.x;
  if (idx >= 4 * kL * kDM) return;
  int d = idx & (kDM - 1);
  int l = (idx >> 8) & (kL - 1);
  int b = idx >> 19;
  float v = x[idx];
  h[idx] = v;
  h[((size_t)((4 + b) * kL + (kL - 1 - l))) * kDM + d] = v;
}

// ---------------- LayerNorm over 256, wave per row, bf16 out ----------------
__global__ __launch_bounds__(256) void ln_kernel(const float* __restrict__ h,
                                                 const float* __restrict__ w0,
                                                 const float* __restrict__ b0,
                                                 const float* __restrict__ w1,
                                                 const float* __restrict__ b1,
                                                 ushort* __restrict__ xn) {
  int t = threadIdx.x;
  int lane = t & 63;
  int row = blockIdx.x * 4 + (t >> 6);
  int dir = (row >= kRowsD) ? 1 : 0;
  const float* w = dir ? w1 : w0;
  const float* b = dir ? b1 : b0;
  int e0 = lane * 4;
  float4 v = *(const float4*)&h[(size_t)row * kDM + e0];
  float s = v.x + v.y + v.z + v.w;
#pragma unroll
  for (int o = 32; o > 0; o >>= 1) s += __shfl_xor(s, o);
  float mu = s * (1.0f / kDM);
  float4 d = {v.x - mu, v.y - mu, v.z - mu, v.w - mu};
  float ss = d.x * d.x + d.y * d.y + d.z * d.z + d.w * d.w;
#pragma unroll
  for (int o = 32; o > 0; o >>= 1) ss += __shfl_xor(ss, o);
  float r = rsqrtf(ss * (1.0f / kDM) + 1e-5f);
  float4 wv = *(const float4*)&w[e0];
  float4 bv = *(const float4*)&b[e0];
  ushort4 o = {f2b(d.x * r * wv.x + bv.x), f2b(d.y * r * wv.y + bv.y),
               f2b(d.z * r * wv.z + bv.z), f2b(d.w * r * wv.w + bv.w)};
  *(ushort4*)&xn[(size_t)row * kDM + e0] = o;
}

// ---------------- bf16 MFMA GEMM: C[Md,N] (+)= A[Md,K] @ W[N,K]^T ----------------
__global__ __launch_bounds__(256) void gemm_bf16(const ushort* __restrict__ A,
                                                 const ushort* __restrict__ W0,
                                                 const ushort* __restrict__ W1,
                                                 float* __restrict__ C, int Md, int N,
                                                 int K, int accumulate) {
  int dir = blockIdx.z;
  const ushort* W = dir ? W1 : W0;
  const ushort* Ab = A + (size_t)dir * Md * K;
  float* Cb = C + (size_t)dir * Md * N;
  int m0 = blockIdx.y * 128;
  int n0 = blockIdx.x * 128;
  __shared__ __align__(16) ushort As[128 * 32];
  __shared__ __align__(16) ushort Ws[128 * 32];
  int tid = threadIdx.x;
  int lane = tid & 63;
  int wv = tid >> 6;
  int wr = (wv >> 1) * 64, wc = (wv & 1) * 64;
  int l16 = lane & 15, lk = lane >> 4;
  int rA = tid >> 2;
  int cA = (tid & 3) * 8;
  char* ldsA = (char*)As + wv * 1024;
  char* ldsB = (char*)Ws + wv * 1024;
  int rb0 = n0 + rA;       if (rb0 >= N) rb0 = N - 1;
  int rb1 = n0 + rA + 64;  if (rb1 >= N) rb1 = N - 1;

  f32x4 acc[4][4];
#pragma unroll
  for (int m = 0; m < 4; m++)
#pragma unroll
    for (int n = 0; n < 4; n++) acc[m][n] = {0.f, 0.f, 0.f, 0.f};

  for (int k0 = 0; k0 < K; k0 += 32) {
    gl_lds16(Ab + (size_t)(m0 + rA) * K + k0 + cA, ldsA);
    gl_lds16(Ab + (size_t)(m0 + rA + 64) * K + k0 + cA, ldsA + 4096);
    gl_lds16(W + (size_t)rb0 * K + k0 + cA, ldsB);
    gl_lds16(W + (size_t)rb1 * K + k0 + cA, ldsB + 4096);
    __syncthreads();
    bf16x8 a[4], b[4];
#pragma unroll
    for (int m = 0; m < 4; m++)
      a[m] = *(const bf16x8*)((const char*)As +
                              (((wr + m * 16 + l16) * 32 + lk * 8) << 1));
#pragma unroll
    for (int n = 0; n < 4; n++)
      b[n] = *(const bf16x8*)((const char*)Ws +
                              (((wc + n * 16 + l16) * 32 + lk * 8) << 1));
#pragma unroll
    for (int m = 0; m < 4; m++)
#pragma unroll
      for (int n = 0; n < 4; n++)
        acc[m][n] =
            __builtin_amdgcn_mfma_f32_16x16x32_bf16(a[m], b[n], acc[m][n], 0, 0, 0);
    __syncthreads();
  }
#pragma unroll
  for (int m = 0; m < 4; m++) {
#pragma unroll
    for (int n = 0; n < 4; n++) {
      int col = n0 + wc + n * 16 + l16;
      if (col < N) {
#pragma unroll
        for (int r = 0; r < 4; r++) {
          int row = m0 + wr + m * 16 + lk * 4 + r;
          size_t idx = (size_t)row * N + col;
          float v = acc[m][n][r];
          if (accumulate) Cb[idx] += v;
          else Cb[idx] = v;
        }
      }
    }
  }
}

// ---------------- causal conv + silu: 16 rows/thread streaming, bf16 out ----------------
// thread owns (row-tile of 16, 4 channels); rotating 4-row register window.
__global__ __launch_bounds__(256) void conv_kernel(const float* __restrict__ zx,
                                                   const float* __restrict__ cw0,
                                                   const float* __restrict__ cb0,
                                                   const float* __restrict__ cw1,
                                                   const float* __restrict__ cb1,
                                                   ushort* __restrict__ xcb) {
  constexpr int kCG = kCDIM / 4;  // 160 channel groups
  int idx = blockIdx.x * 256 + threadIdx.x;
  if (idx >= (kRows / 16) * kCG) return;
  int c4 = (idx % kCG) * 4;
  int rt = idx / kCG;
  int bb = rt >> 7;             // kL/16 = 128 tiles per bb
  int l0 = (rt & 127) << 4;
  int dir = bb >> 2;
  const float* cw = dir ? cw1 : cw0;
  const float* cb = dir ? cb1 : cb0;
  float wt[4][4];
#pragma unroll
  for (int c = 0; c < 4; c++) {
    float4 w = *(const float4*)&cw[(c4 + c) * 4];
    wt[c][0] = w.x; wt[c][1] = w.y; wt[c][2] = w.z; wt[c][3] = w.w;
  }
  float4 bias = *(const float4*)&cb[c4];
  const float* base = zx + ((size_t)(bb * kL)) * kDPROJ + kDI + c4;
  float4 rm3, rm2, rm1;
  if (l0 == 0) {
    rm3 = {0.f, 0.f, 0.f, 0.f};
    rm2 = rm3;
    rm1 = rm3;
  } else {
    rm3 = *(const float4*)(base + (size_t)(l0 - 3) * kDPROJ);
    rm2 = *(const float4*)(base + (size_t)(l0 - 2) * kDPROJ);
    rm1 = *(const float4*)(base + (size_t)(l0 - 1) * kDPROJ);
  }
  ushort* outp = xcb + (size_t)(bb * kL + l0) * kCDIM + c4;
#pragma unroll
  for (int r = 0; r < 16; r++) {
    float4 cur = *(const float4*)(base + (size_t)(l0 + r) * kDPROJ);
    float a0 = bias.x + wt[0][0] * rm3.x + wt[0][1] * rm2.x + wt[0][2] * rm1.x +
               wt[0][3] * cur.x;
    float a1 = bias.y + wt[1][0] * rm3.y + wt[1][1] * rm2.y + wt[1][2] * rm1.y +
               wt[1][3] * cur.y;
    float a2 = bias.z + wt[2][0] * rm3.z + wt[2][1] * rm2.z + wt[2][2] * rm1.z +
               wt[2][3] * cur.z;
    float a3 = bias.w + wt[3][0] * rm3.w + wt[3][1] * rm2.w + wt[3][2] * rm1.w +
               wt[3][3] * cur.w;
    ushort4 o = {f2b(a0 / (1.f + __expf(-a0))), f2b(a1 / (1.f + __expf(-a1))),
                 f2b(a2 / (1.f + __expf(-a2))), f2b(a3 / (1.f + __expf(-a3)))};
    *(ushort4*)(outp + (size_t)r * kCDIM) = o;
    rm3 = rm2;
    rm2 = rm1;
    rm1 = cur;
  }
}

// ---------------- fused softplus(dt) + per-chunk wave-scan cumsum ----------------
__global__ __launch_bounds__(256) void cumsum_kernel(const float* __restrict__ zx,
                                                     const float* __restrict__ db0,
                                                     const float* __restrict__ db1,
                                                     const float* __restrict__ al0,
                                                     const float* __restrict__ al1,
                                                     float* __restrict__ dt,
                                                     float* __restrict__ cs,
                                                     float* __restrict__ g) {
  int t = threadIdx.x;
  int c = t & 63;
  int wid = blockIdx.x * 4 + (t >> 6);
  int h = wid & (kNH - 1);
  int k = (wid >> 4) & (kKC - 1);
  int bb = wid >> 9;
  int dir = bb >> 2;
  int row = bb * kL + k * kCH + c;
  float x = zx[(size_t)row * kDPROJ + 2 * kDI + 2 * kDS + h] + (dir ? db1 : db0)[h];
  float dtv = (x > 20.f) ? x : log1pf(expf(x));
  dt[(size_t)row * kNH + h] = dtv;
  float A = -__expf((dir ? al1 : al0)[h]);
  float s = dtv * A;
#pragma unroll
  for (int off = 1; off < 64; off <<= 1) {
    float u = __shfl_up(s, off);
    if (c >= off) s += u;
  }
  cs[(size_t)wid * kCH + c] = s;
  if (c == 63) g[wid] = __expf(s);
}

// ---------------- MFMA states: one block per (b,k), wave per head ----------------
__global__ __launch_bounds__(256) void states_kernel(const ushort* __restrict__ xcb,
                                                     const float* __restrict__ dt,
                                                     const float* __restrict__ cs,
                                                     float* __restrict__ states) {
  int bk = blockIdx.x;
  int k = bk & (kKC - 1);
  int bb = bk >> 5;
  __shared__ __align__(16) ushort Bstage[64][72];
  __shared__ __align__(16) ushort Bt[64][72];   // Bt[n][j]
  __shared__ __align__(16) ushort Ap[4][32][72];  // per-wave A' = w*xs^T
  __shared__ float w_s[16][64];
  int t = threadIdx.x;
  int lane = t & 63, wv = t >> 6;
  size_t rowbase = (size_t)(bb * kL + k * kCH);
  {
    int j = t >> 2, n0 = (t & 3) * 16;
    const ushort* src = xcb + (rowbase + j) * kCDIM + kDI + n0;
    *(int4*)&Bstage[j][n0] = *(const int4*)src;
    *(int4*)&Bstage[j][n0 + 8] = *(const int4*)(src + 8);
  }
#pragma unroll
  for (int i = 0; i < 4; i++) {
    int e = t + i * 256;
    int h = e >> 6, c = e & 63;
    const float* csb = cs + ((size_t)bk * 16 + h) * kCH;
    w_s[h][c] = __expf(csb[63] - csb[c]) * dt[(rowbase + c) * kNH + h];
  }
  __syncthreads();
#pragma unroll
  for (int i = 0; i < 16; i++) {
    int e = t + i * 256;
    int j = e & 63, n = e >> 6;
    Bt[n][j] = Bstage[j][n];
  }
  __syncthreads();
  int l15 = lane & 15, lk8 = (lane >> 4) * 8;
  for (int hg = 0; hg < 4; hg++) {
    int h = hg * 4 + wv;
    float wl = w_s[h][lane];
    const ushort* xrow = xcb + (rowbase + lane) * kCDIM + h * 32;
#pragma unroll
    for (int q4 = 0; q4 < 4; q4++) {
      U16x8 v;
      v.v = *(const int4*)(xrow + q4 * 8);
#pragma unroll
      for (int q = 0; q < 8; q++)
        Ap[wv][q4 * 8 + q][lane] = f2b(b2f(v.u[q]) * wl);
    }
#pragma unroll
    for (int pt = 0; pt < 2; pt++) {
#pragma unroll
      for (int nt = 0; nt < 4; nt++) {
        f32x4 acc = {0.f, 0.f, 0.f, 0.f};
#pragma unroll
        for (int kt = 0; kt < 2; kt++) {
          bf16x8 a = *(const bf16x8*)&Ap[wv][pt * 16 + l15][kt * 32 + lk8];
          bf16x8 b = *(const bf16x8*)&Bt[nt * 16 + l15][kt * 32 + lk8];
          acc = __builtin_amdgcn_mfma_f32_16x16x32_bf16(a, b, acc, 0, 0, 0);
        }
        size_t base = ((size_t)bk * 16 + h) * 2048;
#pragma unroll
        for (int r = 0; r < 4; r++) {
          int p = pt * 16 + (lane >> 4) * 4 + r;
          states[base + p * 64 + nt * 16 + l15] = acc[r];
        }
      }
    }
  }
}

// ---------------- chunk scan: sprev (bf16) = running S; S = g*S + states ----------------
__global__ __launch_bounds__(256) void scan_kernel(const float* __restrict__ st,
                                                   const float* __restrict__ g,
                                                   ushort* __restrict__ spbf) {
  int idx = blockIdx.x * 256 + threadIdx.x;
  if (idx >= kBB * kNH * 2048) return;
  int pn = idx & 2047;
  int h = (idx >> 11) & (kNH - 1);
  int bb = idx >> 15;
  float S = 0.f;
  for (int k = 0; k < kKC; k++) {
    size_t off = (((size_t)(bb * kKC + k) * kNH + h) * 2048) + pn;
    spbf[off] = f2b(S);
    S = g[(bb * kKC + k) * kNH + h] * S + st[off];
  }
}

// ---------------- fused y: per (b,k,half-heads); CB in LDS; MFMA intra+inter ----------------
__global__ __launch_bounds__(256) void y_kernel(const ushort* __restrict__ xcb,
                                                const float* __restrict__ dt,
                                                const float* __restrict__ cs,
                                                const ushort* __restrict__ spbf,
                                                const float* __restrict__ D0,
                                                const float* __restrict__ D1,
                                                float* __restrict__ y) {
  int bid = blockIdx.x;
  int hh = bid & 1;
  int bk = bid >> 1;
  int k = bk & (kKC - 1);
  int bb = bk >> 5;
  int dir = bb >> 2;
  __shared__ __align__(16) ushort Cls[64][72];
  __shared__ __align__(16) ushort Bls[64][72];
  __shared__ float CBT[64][67];  // CBT[j][i] = CB[i][j]
  __shared__ __align__(16) ushort xs_s[64][40];
  __shared__ __align__(16) ushort xsT[32][72];
  __shared__ __align__(16) ushort sp_s[32][72];
  __shared__ float cs_s[64], dt_s[64], ecs_s[64];
  int t = threadIdx.x, lane = t & 63, wv = t >> 6;
  int l15 = lane & 15, lk8 = (lane >> 4) * 8;
  size_t rowbase = (size_t)(bb * kL + k * kCH);
  {
    int j = t >> 2, n0 = (t & 3) * 16;
    const ushort* pB = xcb + (rowbase + j) * kCDIM + kDI;
    *(int4*)&Bls[j][n0] = *(const int4*)(pB + n0);
    *(int4*)&Bls[j][n0 + 8] = *(const int4*)(pB + n0 + 8);
    *(int4*)&Cls[j][n0] = *(const int4*)(pB + kDS + n0);
    *(int4*)&Cls[j][n0 + 8] = *(const int4*)(pB + kDS + n0 + 8);
  }
  __syncthreads();
  {
    int i0 = wv * 16;
#pragma unroll
    for (int jt = 0; jt < 4; jt++) {
      f32x4 acc = {0.f, 0.f, 0.f, 0.f};
#pragma unroll
      for (int kt = 0; kt < 2; kt++) {
        bf16x8 a = *(const bf16x8*)&Cls[i0 + l15][kt * 32 + lk8];
        bf16x8 b = *(const bf16x8*)&Bls[jt * 16 + l15][kt * 32 + lk8];
        acc = __builtin_amdgcn_mfma_f32_16x16x32_bf16(a, b, acc, 0, 0, 0);
      }
#pragma unroll
      for (int r = 0; r < 4; r++)
        CBT[jt * 16 + l15][i0 + (lane >> 4) * 4 + r] = acc[r];
    }
  }
  for (int hi = 0; hi < 8; hi++) {
    int h = hh * 8 + hi;
    int bkh = bk * 16 + h;
    float Dp = (dir ? D1 : D0)[h];
    __syncthreads();
    {
      int j = t >> 2, p0 = (t & 3) * 8;
      U16x8 v;
      v.v = *(const int4*)(xcb + (rowbase + j) * kCDIM + h * 32 + p0);
      *(int4*)&xs_s[j][p0] = v.v;
#pragma unroll
      for (int q = 0; q < 8; q++) xsT[p0 + q][j] = v.u[q];
      int4 s = *(const int4*)(spbf + (size_t)bkh * 2048 + t * 8);
      *(int4*)&sp_s[t >> 3][(t & 7) * 8] = s;
      if (t < 64) {
        float cv = cs[(size_t)bkh * kCH + t];
        cs_s[t] = cv;
        ecs_s[t] = __expf(cv);
        dt_s[t] = dt[(rowbase + t) * kNH + h];
      }
    }
    __syncthreads();
    int i0 = wv * 16;
    int ia = i0 + l15;
    float csi = cs_s[ia];
    U16x8 af[2];
#pragma unroll
    for (int kt = 0; kt < 2; kt++) {
#pragma unroll
      for (int q = 0; q < 8; q++) {
        int j = kt * 32 + lk8 + q;
        float v = 0.f;
        if (j <= ia) v = __expf(csi - cs_s[j]) * dt_s[j] * CBT[j][ia];
        af[kt].u[q] = f2b(v);
      }
    }
#pragma unroll
    for (int pt = 0; pt < 2; pt++) {
      f32x4 acc = {0.f, 0.f, 0.f, 0.f};
      f32x4 acc2 = {0.f, 0.f, 0.f, 0.f};
#pragma unroll
      for (int kt = 0; kt < 2; kt++) {
        bf16x8 bx = *(const bf16x8*)&xsT[pt * 16 + l15][kt * 32 + lk8];
        acc = __builtin_amdgcn_mfma_f32_16x16x32_bf16(af[kt].b, bx, acc, 0, 0, 0);
        bf16x8 ac = *(const bf16x8*)&Cls[i0 + l15][kt * 32 + lk8];
        bf16x8 bs = *(const bf16x8*)&sp_s[pt * 16 + l15][kt * 32 + lk8];
        acc2 = __builtin_amdgcn_mfma_f32_16x16x32_bf16(ac, bs, acc2, 0, 0, 0);
      }
#pragma unroll
      for (int r = 0; r < 4; r++) {
        int io = i0 + (lane >> 4) * 4 + r;
        int p = pt * 16 + l15;
        float xsv = b2f(xs_s[io][p]);
        float v = acc[r] + ecs_s[io] * acc2[r] + Dp * xsv;
        y[(rowbase + io) * kDI + h * 32 + p] = v;
      }
    }
  }
}

// ---------------- gate+RMSNorm: wave per row; bf16 out ----------------
__global__ __launch_bounds__(256) void gate_norm_kernel(const float* __restrict__ zx,
                                                        const float* __restrict__ nw0,
                                                        const float* __restrict__ nw1,
                                                        const float* __restrict__ y,
                                                        ushort* __restrict__ ybf) {
  int t = threadIdx.x;
  int lane = t & 63;
  int row = blockIdx.x * 4 + (t >> 6);
  int dir = (row >= kRowsD) ? 1 : 0;
  const float* nw = dir ? nw1 : nw0;
  int e0 = lane * 8;
  const float* zp = zx + (size_t)row * kDPROJ + e0;
  const float* yp = y + (size_t)row * kDI + e0;
  float4 z0 = *(const float4*)zp;
  float4 z1 = *(const float4*)(zp + 4);
  float4 y0 = *(const float4*)yp;
  float4 y1 = *(const float4*)(yp + 4);
  float v[8];
  float za[8] = {z0.x, z0.y, z0.z, z0.w, z1.x, z1.y, z1.z, z1.w};
  float ya[8] = {y0.x, y0.y, y0.z, y0.w, y1.x, y1.y, y1.z, y1.w};
  float ss = 0.f;
#pragma unroll
  for (int q = 0; q < 8; q++) {
    float gz = za[q] / (1.f + __expf(-za[q]));
    v[q] = ya[q] * gz;
    ss += v[q] * v[q];
  }
#pragma unroll
  for (int o = 32; o > 0; o >>= 1) ss += __shfl_xor(ss, o);
  float scale = rsqrtf(ss * (1.0f / kDI) + 1e-5f);
  float4 n0 = *(const float4*)&nw[e0];
  float4 n1 = *(const float4*)&nw[e0 + 4];
  float na[8] = {n0.x, n0.y, n0.z, n0.w, n1.x, n1.y, n1.z, n1.w};
  U16x8 o;
#pragma unroll
  for (int q = 0; q < 8; q++) o.u[q] = f2b(v[q] * scale * na[q]);
  *(int4*)&ybf[(size_t)row * kDI + e0] = o.v;
}

// ---------------- hcat bf16 ----------------
__global__ __launch_bounds__(256) void concat_kernel(const float* __restrict__ h,
                                                     ushort* __restrict__ hcat) {
  int idx = blockIdx.x * 256 + threadIdx.x;
  if (idx >= 4 * kL * 2 * kDM) return;
  int e = idx & 511;
  int l = (idx >> 9) & (kL - 1);
  int b = idx >> 20;
  float v;
  if (e < kDM)
    v = h[((size_t)(b * kL + l)) * kDM + e];
  else
    v = h[((size_t)((4 + b) * kL + (kL - 1 - l))) * kDM + (e - kDM)];
  hcat[idx] = f2b(v);
}

}  // namespace

extern "C" void kernel_launch(void* const* d_in, const int* in_sizes, int n_in,
                              void* d_out, int out_size, void* d_ws, size_t ws_size,
                              hipStream_t stream) {
  const float* x = (const float*)d_in[0];
  const float* fw_ln_w = (const float*)d_in[1];
  const float* fw_ln_b = (const float*)d_in[2];
  const float* fw_win = (const float*)d_in[3];
  const float* fw_convw = (const float*)d_in[4];
  const float* fw_convb = (const float*)d_in[5];
  const float* fw_alog = (const float*)d_in[6];
  const float* fw_dtb = (const float*)d_in[7];
  const float* fw_D = (const float*)d_in[8];
  const float* fw_nw = (const float*)d_in[9];
  const float* fw_wout = (const float*)d_in[10];
  const float* bw_ln_w = (const float*)d_in[11];
  const float* bw_ln_b = (const float*)d_in[12];
  const float* bw_win = (const float*)d_in[13];
  const float* bw_convw = (const float*)d_in[14];
  const float* bw_convb = (const float*)d_in[15];
  const float* bw_alog = (const float*)d_in[16];
  const float* bw_dtb = (const float*)d_in[17];
  const float* bw_D = (const float*)d_in[18];
  const float* bw_nw = (const float*)d_in[19];
  const float* bw_wout = (const float*)d_in[20];
  const float* fusion_w = (const float*)d_in[21];
  float* out = (float*)d_out;

  float* ws = (float*)d_ws;
  float* h = ws;                                  // 16384*256
  float* zx = h + (size_t)kRows * kDM;            // 16384*1168
  float* dt = zx + (size_t)kRows * kDPROJ;        // 16384*16
  float* cs = dt + (size_t)kRows * kNH;           // 4096*64
  float* g = cs + (size_t)kBB * kKC * kNH * kCH;  // 4096
  float* states = g + (size_t)kBB * kKC * kNH;    // 4096*2048
  float* y = states + (size_t)kBB * kKC * kNH * 2048;  // 16384*512
  ushort* xcb = (ushort*)(y + (size_t)kRows * kDI);    // 16384*640
  ushort* spbf = xcb + (size_t)kRows * kCDIM;          // 4096*2048
  ushort* xnbf = spbf + (size_t)kBB * kKC * kNH * 2048;  // 16384*256 (also hcat)
  ushort* ybf = xnbf + (size_t)kRows * kDM;              // 16384*512
  ushort* winbf = ybf + (size_t)kRows * kDI;             // 2*8*1168*256
  ushort* woutbf = winbf + (size_t)2 * 8 * kDPROJ * kDM; // 2*8*256*512
  ushort* fusbf = woutbf + (size_t)2 * 8 * kDM * kDI;    // 256*512
  ushort* hcatbf = xnbf;

  {
    int nw1 = 8 * kDPROJ * kDM / 4;
    f2b_kernel<<<(nw1 + 255) / 256, 256, 0, stream>>>(fw_win, winbf, nw1);
    f2b_kernel<<<(nw1 + 255) / 256, 256, 0, stream>>>(
        bw_win, winbf + (size_t)8 * kDPROJ * kDM, nw1);
    int nw2 = 8 * kDM * kDI / 4;
    f2b_kernel<<<(nw2 + 255) / 256, 256, 0, stream>>>(fw_wout, woutbf, nw2);
    f2b_kernel<<<(nw2 + 255) / 256, 256, 0, stream>>>(
        bw_wout, woutbf + (size_t)8 * kDM * kDI, nw2);
    int nw3 = kDM * kDI / 4;
    f2b_kernel<<<(nw3 + 255) / 256, 256, 0, stream>>>(fusion_w, fusbf, nw3);
  }

  init_h_kernel<<<(4 * kL * kDM + 255) / 256, 256, 0, stream>>>(x, h);

  for (int i = 0; i < 8; i++) {
    const size_t oLN = (size_t)i * kDM;
    const size_t oCW = (size_t)i * kCDIM * 4;
    const size_t oCB = (size_t)i * kCDIM;
    const size_t oH = (size_t)i * kNH;
    const size_t oNW = (size_t)i * kDI;
    const ushort* win0 = winbf + (size_t)i * kDPROJ * kDM;
    const ushort* win1 = winbf + (size_t)(8 + i) * kDPROJ * kDM;
    const ushort* wout0 = woutbf + (size_t)i * kDM * kDI;
    const ushort* wout1 = woutbf + (size_t)(8 + i) * kDM * kDI;

    ln_kernel<<<kRows / 4, 256, 0, stream>>>(h, fw_ln_w + oLN, fw_ln_b + oLN,
                                             bw_ln_w + oLN, bw_ln_b + oLN, xnbf);
    {
      dim3 grid((kDPROJ + 127) / 128, kRowsD / 128, 2);
      gemm_bf16<<<grid, 256, 0, stream>>>(xnbf, win0, win1, zx, kRowsD, kDPROJ,
                                          kDM, 0);
    }
    conv_kernel<<<((kRows / 16) * (kCDIM / 4) + 255) / 256, 256, 0, stream>>>(
        zx, fw_convw + oCW, fw_convb + oCB, bw_convw + oCW, bw_convb + oCB, xcb);
    cumsum_kernel<<<kBB * kKC * kNH / 4, 256, 0, stream>>>(
        zx, fw_dtb + oH, bw_dtb + oH, fw_alog + oH, bw_alog + oH, dt, cs, g);
    states_kernel<<<kBB * kKC, 256, 0, stream>>>(xcb, dt, cs, states);
    scan_kernel<<<(kBB * kNH * 2048 + 255) / 256, 256, 0, stream>>>(states, g, spbf);
    y_kernel<<<kBB * kKC * 2, 256, 0, stream>>>(xcb, dt, cs, spbf, fw_D + oH,
                                                bw_D + oH, y);
    gate_norm_kernel<<<kRows / 4, 256, 0, stream>>>(zx, fw_nw + oNW, bw_nw + oNW, y,
                                                    ybf);
    {
      dim3 grid(kDM / 128, kRowsD / 128, 2);
      gemm_bf16<<<grid, 256, 0, stream>>>(ybf, wout0, wout1, h, kRowsD, kDM, kDI, 1);
    }
  }

  concat_kernel<<<(4 * kL * 2 * kDM + 255) / 256, 256, 0, stream>>>(h, hcatbf);
  {
    dim3 grid(kDM / 128, kRowsD / 128, 1);
    gemm_bf16<<<grid, 256, 0, stream>>>(hcatbf, fusbf, fusbf, out, kRowsD, kDM,
                                        2 * kDM, 0);
  }
}

// Round 7
// 1124.104 us; speedup vs baseline: 6.5657x; 1.0713x over previous
//
#include <hip/hip_runtime.h>
#include <math.h>

// BiMambaEncoder: 8-layer bidirectional Mamba2 stack.
// Round 7: bf16 intermediates (zx, y, states) to halve HBM traffic; fp32
// side-channel dtraw for the softplus/cumsum path; scan vectorized x4.

namespace {

constexpr int kL = 2048;
constexpr int kDM = 256;
constexpr int kDI = 512;
constexpr int kNH = 16;
constexpr int kDS = 64;
constexpr int kCDIM = 640;
constexpr int kDPROJ = 1168;
constexpr int kCH = 64;
constexpr int kKC = 32;
constexpr int kBB = 8;
constexpr int kRowsD = 4 * kL;
constexpr int kRows = kBB * kL;

typedef __bf16 bf16x8 __attribute__((ext_vector_type(8)));
typedef float f32x4 __attribute__((ext_vector_type(4)));
typedef unsigned short ushort;

union U16x8 {
  int4 v;
  ushort u[8];
  bf16x8 b;
};

__device__ __forceinline__ ushort f2b(float x) {
  union { float f; unsigned u; } c;
  c.f = x;
  unsigned r = c.u + 0x7fffu + ((c.u >> 16) & 1u);
  return (ushort)(r >> 16);
}
__device__ __forceinline__ float b2f(ushort u) {
  union { unsigned u; float f; } c;
  c.u = ((unsigned)u) << 16;
  return c.f;
}
__device__ __forceinline__ float4 ld4b(const ushort* p) {
  ushort4 u = *(const ushort4*)p;
  return {b2f(u.x), b2f(u.y), b2f(u.z), b2f(u.w)};
}

__device__ __forceinline__ void gl_lds16(const void* g, void* l) {
  __builtin_amdgcn_global_load_lds(
      (const __attribute__((address_space(1))) unsigned int*)g,
      (__attribute__((address_space(3))) unsigned int*)l, 16, 0, 0);
}

// ---------------- fp32 -> bf16 conversion (4-wide) ----------------
__global__ __launch_bounds__(256) void f2b_kernel(const float* __restrict__ src,
                                                  ushort* __restrict__ dst, int n4) {
  int i = blockIdx.x * 256 + threadIdx.x;
  if (i >= n4) return;
  float4 v = *(const float4*)&src[i * 4];
  ushort4 o = {f2b(v.x), f2b(v.y), f2b(v.z), f2b(v.w)};
  *(ushort4*)&dst[i * 4] = o;
}

// ---------------- init: h[0..3]=x, h[4..7]=flip(x) ----------------
__global__ __launch_bounds__(256) void init_h_kernel(const float* __restrict__ x,
                                                     float* __restrict__ h) {
  int idx = blockIdx.x * 256 + threadIdx.x;
  if (idx >= 4 * kL * kDM) return;
  int d = idx & (kDM - 1);
  int l = (idx >> 8) & (kL - 1);
  int b = idx >> 19;
  float v = x[idx];
  h[idx] = v;
  h[((size_t)((4 + b) * kL + (kL - 1 - l))) * kDM + d] = v;
}

// ---------------- LayerNorm over 256, wave per row, bf16 out ----------------
__global__ __launch_bounds__(256) void ln_kernel(const float* __restrict__ h,
                                                 const float* __restrict__ w0,
                                                 const float* __restrict__ b0,
                                                 const float* __restrict__ w1,
                                                 const float* __restrict__ b1,
                                                 ushort* __restrict__ xn) {
  int t = threadIdx.x;
  int lane = t & 63;
  int row = blockIdx.x * 4 + (t >> 6);
  int dir = (row >= kRowsD) ? 1 : 0;
  const float* w = dir ? w1 : w0;
  const float* b = dir ? b1 : b0;
  int e0 = lane * 4;
  float4 v = *(const float4*)&h[(size_t)row * kDM + e0];
  float s = v.x + v.y + v.z + v.w;
#pragma unroll
  for (int o = 32; o > 0; o >>= 1) s += __shfl_xor(s, o);
  float mu = s * (1.0f / kDM);
  float4 d = {v.x - mu, v.y - mu, v.z - mu, v.w - mu};
  float ss = d.x * d.x + d.y * d.y + d.z * d.z + d.w * d.w;
#pragma unroll
  for (int o = 32; o > 0; o >>= 1) ss += __shfl_xor(ss, o);
  float r = rsqrtf(ss * (1.0f / kDM) + 1e-5f);
  float4 wv = *(const float4*)&w[e0];
  float4 bv = *(const float4*)&b[e0];
  ushort4 o = {f2b(d.x * r * wv.x + bv.x), f2b(d.y * r * wv.y + bv.y),
               f2b(d.z * r * wv.z + bv.z), f2b(d.w * r * wv.w + bv.w)};
  *(ushort4*)&xn[(size_t)row * kDM + e0] = o;
}

// ---------------- bf16 MFMA GEMM ----------------
// mode 0: C=fp32 store; mode 1: C=fp32 accumulate; mode 2: bf16 store to C16
//         (+ fp32 copy of cols >= 1152 into dtraw[row*16 + col-1152]).
__global__ __launch_bounds__(256) void gemm_bf16(const ushort* __restrict__ A,
                                                 const ushort* __restrict__ W0,
                                                 const ushort* __restrict__ W1,
                                                 float* __restrict__ C,
                                                 ushort* __restrict__ C16,
                                                 float* __restrict__ dtraw, int Md,
                                                 int N, int K, int mode) {
  int dir = blockIdx.z;
  const ushort* W = dir ? W1 : W0;
  const ushort* Ab = A + (size_t)dir * Md * K;
  int m0 = blockIdx.y * 128;
  int n0 = blockIdx.x * 128;
  __shared__ __align__(16) ushort As[128 * 32];
  __shared__ __align__(16) ushort Ws[128 * 32];
  int tid = threadIdx.x;
  int lane = tid & 63;
  int wv = tid >> 6;
  int wr = (wv >> 1) * 64, wc = (wv & 1) * 64;
  int l16 = lane & 15, lk = lane >> 4;
  int rA = tid >> 2;
  int cA = (tid & 3) * 8;
  char* ldsA = (char*)As + wv * 1024;
  char* ldsB = (char*)Ws + wv * 1024;
  int rb0 = n0 + rA;       if (rb0 >= N) rb0 = N - 1;
  int rb1 = n0 + rA + 64;  if (rb1 >= N) rb1 = N - 1;

  f32x4 acc[4][4];
#pragma unroll
  for (int m = 0; m < 4; m++)
#pragma unroll
    for (int n = 0; n < 4; n++) acc[m][n] = {0.f, 0.f, 0.f, 0.f};

  for (int k0 = 0; k0 < K; k0 += 32) {
    gl_lds16(Ab + (size_t)(m0 + rA) * K + k0 + cA, ldsA);
    gl_lds16(Ab + (size_t)(m0 + rA + 64) * K + k0 + cA, ldsA + 4096);
    gl_lds16(W + (size_t)rb0 * K + k0 + cA, ldsB);
    gl_lds16(W + (size_t)rb1 * K + k0 + cA, ldsB + 4096);
    __syncthreads();
    bf16x8 a[4], b[4];
#pragma unroll
    for (int m = 0; m < 4; m++)
      a[m] = *(const bf16x8*)((const char*)As +
                              (((wr + m * 16 + l16) * 32 + lk * 8) << 1));
#pragma unroll
    for (int n = 0; n < 4; n++)
      b[n] = *(const bf16x8*)((const char*)Ws +
                              (((wc + n * 16 + l16) * 32 + lk * 8) << 1));
#pragma unroll
    for (int m = 0; m < 4; m++)
#pragma unroll
      for (int n = 0; n < 4; n++)
        acc[m][n] =
            __builtin_amdgcn_mfma_f32_16x16x32_bf16(a[m], b[n], acc[m][n], 0, 0, 0);
    __syncthreads();
  }
  if (mode == 2) {
    ushort* Cb = C16 + (size_t)dir * Md * N;
    float* dtb = dtraw + (size_t)dir * Md * kNH;
#pragma unroll
    for (int m = 0; m < 4; m++) {
#pragma unroll
      for (int n = 0; n < 4; n++) {
        int col = n0 + wc + n * 16 + l16;
        if (col < N) {
#pragma unroll
          for (int r = 0; r < 4; r++) {
            int row = m0 + wr + m * 16 + lk * 4 + r;
            float v = acc[m][n][r];
            Cb[(size_t)row * N + col] = f2b(v);
            if (col >= 2 * kDI + 2 * kDS)
              dtb[(size_t)row * kNH + (col - (2 * kDI + 2 * kDS))] = v;
          }
        }
      }
    }
  } else {
    float* Cb = C + (size_t)dir * Md * N;
#pragma unroll
    for (int m = 0; m < 4; m++) {
#pragma unroll
      for (int n = 0; n < 4; n++) {
        int col = n0 + wc + n * 16 + l16;
        if (col < N) {
#pragma unroll
          for (int r = 0; r < 4; r++) {
            int row = m0 + wr + m * 16 + lk * 4 + r;
            size_t idx = (size_t)row * N + col;
            float v = acc[m][n][r];
            if (mode == 1) Cb[idx] += v;
            else Cb[idx] = v;
          }
        }
      }
    }
  }
}

// ---------------- causal conv + silu: 16 rows/thread, bf16 in/out ----------------
__global__ __launch_bounds__(256) void conv_kernel(const ushort* __restrict__ zxb,
                                                   const float* __restrict__ cw0,
                                                   const float* __restrict__ cb0,
                                                   const float* __restrict__ cw1,
                                                   const float* __restrict__ cb1,
                                                   ushort* __restrict__ xcb) {
  constexpr int kCG = kCDIM / 4;  // 160 channel groups
  int idx = blockIdx.x * 256 + threadIdx.x;
  if (idx >= (kRows / 16) * kCG) return;
  int c4 = (idx % kCG) * 4;
  int rt = idx / kCG;
  int bb = rt >> 7;
  int l0 = (rt & 127) << 4;
  int dir = bb >> 2;
  const float* cw = dir ? cw1 : cw0;
  const float* cb = dir ? cb1 : cb0;
  float wt[4][4];
#pragma unroll
  for (int c = 0; c < 4; c++) {
    float4 w = *(const float4*)&cw[(c4 + c) * 4];
    wt[c][0] = w.x; wt[c][1] = w.y; wt[c][2] = w.z; wt[c][3] = w.w;
  }
  float4 bias = *(const float4*)&cb[c4];
  const ushort* base = zxb + ((size_t)(bb * kL)) * kDPROJ + kDI + c4;
  float4 rm3, rm2, rm1;
  if (l0 == 0) {
    rm3 = {0.f, 0.f, 0.f, 0.f};
    rm2 = rm3;
    rm1 = rm3;
  } else {
    rm3 = ld4b(base + (size_t)(l0 - 3) * kDPROJ);
    rm2 = ld4b(base + (size_t)(l0 - 2) * kDPROJ);
    rm1 = ld4b(base + (size_t)(l0 - 1) * kDPROJ);
  }
  ushort* outp = xcb + (size_t)(bb * kL + l0) * kCDIM + c4;
#pragma unroll
  for (int r = 0; r < 16; r++) {
    float4 cur = ld4b(base + (size_t)(l0 + r) * kDPROJ);
    float a0 = bias.x + wt[0][0] * rm3.x + wt[0][1] * rm2.x + wt[0][2] * rm1.x +
               wt[0][3] * cur.x;
    float a1 = bias.y + wt[1][0] * rm3.y + wt[1][1] * rm2.y + wt[1][2] * rm1.y +
               wt[1][3] * cur.y;
    float a2 = bias.z + wt[2][0] * rm3.z + wt[2][1] * rm2.z + wt[2][2] * rm1.z +
               wt[2][3] * cur.z;
    float a3 = bias.w + wt[3][0] * rm3.w + wt[3][1] * rm2.w + wt[3][2] * rm1.w +
               wt[3][3] * cur.w;
    ushort4 o = {f2b(a0 / (1.f + __expf(-a0))), f2b(a1 / (1.f + __expf(-a1))),
                 f2b(a2 / (1.f + __expf(-a2))), f2b(a3 / (1.f + __expf(-a3)))};
    *(ushort4*)(outp + (size_t)r * kCDIM) = o;
    rm3 = rm2;
    rm2 = rm1;
    rm1 = cur;
  }
}

// ---------------- fused softplus(dt) + per-chunk wave-scan cumsum ----------------
__global__ __launch_bounds__(256) void cumsum_kernel(const float* __restrict__ dtraw,
                                                     const float* __restrict__ db0,
                                                     const float* __restrict__ db1,
                                                     const float* __restrict__ al0,
                                                     const float* __restrict__ al1,
                                                     float* __restrict__ dt,
                                                     float* __restrict__ cs,
                                                     float* __restrict__ g) {
  int t = threadIdx.x;
  int c = t & 63;
  int wid = blockIdx.x * 4 + (t >> 6);
  int h = wid & (kNH - 1);
  int k = (wid >> 4) & (kKC - 1);
  int bb = wid >> 9;
  int dir = bb >> 2;
  int row = bb * kL + k * kCH + c;
  float x = dtraw[(size_t)row * kNH + h] + (dir ? db1 : db0)[h];
  float dtv = (x > 20.f) ? x : log1pf(expf(x));
  dt[(size_t)row * kNH + h] = dtv;
  float A = -__expf((dir ? al1 : al0)[h]);
  float s = dtv * A;
#pragma unroll
  for (int off = 1; off < 64; off <<= 1) {
    float u = __shfl_up(s, off);
    if (c >= off) s += u;
  }
  cs[(size_t)wid * kCH + c] = s;
  if (c == 63) g[wid] = __expf(s);
}

// ---------------- MFMA states: one block per (b,k), wave per head; bf16 out ----------------
__global__ __launch_bounds__(256) void states_kernel(const ushort* __restrict__ xcb,
                                                     const float* __restrict__ dt,
                                                     const float* __restrict__ cs,
                                                     ushort* __restrict__ states) {
  int bk = blockIdx.x;
  int k = bk & (kKC - 1);
  int bb = bk >> 5;
  __shared__ __align__(16) ushort Bstage[64][72];
  __shared__ __align__(16) ushort Bt[64][72];   // Bt[n][j]
  __shared__ __align__(16) ushort Ap[4][32][72];  // per-wave A' = w*xs^T
  __shared__ float w_s[16][64];
  int t = threadIdx.x;
  int lane = t & 63, wv = t >> 6;
  size_t rowbase = (size_t)(bb * kL + k * kCH);
  {
    int j = t >> 2, n0 = (t & 3) * 16;
    const ushort* src = xcb + (rowbase + j) * kCDIM + kDI + n0;
    *(int4*)&Bstage[j][n0] = *(const int4*)src;
    *(int4*)&Bstage[j][n0 + 8] = *(const int4*)(src + 8);
  }
#pragma unroll
  for (int i = 0; i < 4; i++) {
    int e = t + i * 256;
    int h = e >> 6, c = e & 63;
    const float* csb = cs + ((size_t)bk * 16 + h) * kCH;
    w_s[h][c] = __expf(csb[63] - csb[c]) * dt[(rowbase + c) * kNH + h];
  }
  __syncthreads();
#pragma unroll
  for (int i = 0; i < 16; i++) {
    int e = t + i * 256;
    int j = e & 63, n = e >> 6;
    Bt[n][j] = Bstage[j][n];
  }
  __syncthreads();
  int l15 = lane & 15, lk8 = (lane >> 4) * 8;
  for (int hg = 0; hg < 4; hg++) {
    int h = hg * 4 + wv;
    float wl = w_s[h][lane];
    const ushort* xrow = xcb + (rowbase + lane) * kCDIM + h * 32;
#pragma unroll
    for (int q4 = 0; q4 < 4; q4++) {
      U16x8 v;
      v.v = *(const int4*)(xrow + q4 * 8);
#pragma unroll
      for (int q = 0; q < 8; q++)
        Ap[wv][q4 * 8 + q][lane] = f2b(b2f(v.u[q]) * wl);
    }
#pragma unroll
    for (int pt = 0; pt < 2; pt++) {
#pragma unroll
      for (int nt = 0; nt < 4; nt++) {
        f32x4 acc = {0.f, 0.f, 0.f, 0.f};
#pragma unroll
        for (int kt = 0; kt < 2; kt++) {
          bf16x8 a = *(const bf16x8*)&Ap[wv][pt * 16 + l15][kt * 32 + lk8];
          bf16x8 b = *(const bf16x8*)&Bt[nt * 16 + l15][kt * 32 + lk8];
          acc = __builtin_amdgcn_mfma_f32_16x16x32_bf16(a, b, acc, 0, 0, 0);
        }
        size_t base = ((size_t)bk * 16 + h) * 2048;
#pragma unroll
        for (int r = 0; r < 4; r++) {
          int p = pt * 16 + (lane >> 4) * 4 + r;
          states[base + p * 64 + nt * 16 + l15] = f2b(acc[r]);
        }
      }
    }
  }
}

// ---------------- chunk scan (x4 vectorized): sprev=S (bf16); S=g*S+states ----------------
__global__ __launch_bounds__(256) void scan_kernel(const ushort* __restrict__ st,
                                                   const float* __restrict__ g,
                                                   ushort* __restrict__ spbf) {
  int idx = blockIdx.x * 256 + threadIdx.x;  // over kBB*kNH*512 quads
  if (idx >= kBB * kNH * 512) return;
  int pn4 = (idx & 511) * 4;
  int h = (idx >> 9) & (kNH - 1);
  int bb = idx >> 13;
  float S[4] = {0.f, 0.f, 0.f, 0.f};
  for (int k = 0; k < kKC; k++) {
    size_t off = (((size_t)(bb * kKC + k) * kNH + h) * 2048) + pn4;
    ushort4 so = {f2b(S[0]), f2b(S[1]), f2b(S[2]), f2b(S[3])};
    *(ushort4*)&spbf[off] = so;
    ushort4 sv = *(const ushort4*)&st[off];
    float gk = g[(bb * kKC + k) * kNH + h];
    S[0] = gk * S[0] + b2f(sv.x);
    S[1] = gk * S[1] + b2f(sv.y);
    S[2] = gk * S[2] + b2f(sv.z);
    S[3] = gk * S[3] + b2f(sv.w);
  }
}

// ---------------- fused y: per (b,k,half-heads); bf16 out ----------------
__global__ __launch_bounds__(256) void y_kernel(const ushort* __restrict__ xcb,
                                                const float* __restrict__ dt,
                                                const float* __restrict__ cs,
                                                const ushort* __restrict__ spbf,
                                                const float* __restrict__ D0,
                                                const float* __restrict__ D1,
                                                ushort* __restrict__ y) {
  int bid = blockIdx.x;
  int hh = bid & 1;
  int bk = bid >> 1;
  int k = bk & (kKC - 1);
  int bb = bk >> 5;
  int dir = bb >> 2;
  __shared__ __align__(16) ushort Cls[64][72];
  __shared__ __align__(16) ushort Bls[64][72];
  __shared__ float CBT[64][67];  // CBT[j][i] = CB[i][j]
  __shared__ __align__(16) ushort xs_s[64][40];
  __shared__ __align__(16) ushort xsT[32][72];
  __shared__ __align__(16) ushort sp_s[32][72];
  __shared__ float cs_s[64], dt_s[64], ecs_s[64];
  int t = threadIdx.x, lane = t & 63, wv = t >> 6;
  int l15 = lane & 15, lk8 = (lane >> 4) * 8;
  size_t rowbase = (size_t)(bb * kL + k * kCH);
  {
    int j = t >> 2, n0 = (t & 3) * 16;
    const ushort* pB = xcb + (rowbase + j) * kCDIM + kDI;
    *(int4*)&Bls[j][n0] = *(const int4*)(pB + n0);
    *(int4*)&Bls[j][n0 + 8] = *(const int4*)(pB + n0 + 8);
    *(int4*)&Cls[j][n0] = *(const int4*)(pB + kDS + n0);
    *(int4*)&Cls[j][n0 + 8] = *(const int4*)(pB + kDS + n0 + 8);
  }
  __syncthreads();
  {
    int i0 = wv * 16;
#pragma unroll
    for (int jt = 0; jt < 4; jt++) {
      f32x4 acc = {0.f, 0.f, 0.f, 0.f};
#pragma unroll
      for (int kt = 0; kt < 2; kt++) {
        bf16x8 a = *(const bf16x8*)&Cls[i0 + l15][kt * 32 + lk8];
        bf16x8 b = *(const bf16x8*)&Bls[jt * 16 + l15][kt * 32 + lk8];
        acc = __builtin_amdgcn_mfma_f32_16x16x32_bf16(a, b, acc, 0, 0, 0);
      }
#pragma unroll
      for (int r = 0; r < 4; r++)
        CBT[jt * 16 + l15][i0 + (lane >> 4) * 4 + r] = acc[r];
    }
  }
  for (int hi = 0; hi < 8; hi++) {
    int h = hh * 8 + hi;
    int bkh = bk * 16 + h;
    float Dp = (dir ? D1 : D0)[h];
    __syncthreads();
    {
      int j = t >> 2, p0 = (t & 3) * 8;
      U16x8 v;
      v.v = *(const int4*)(xcb + (rowbase + j) * kCDIM + h * 32 + p0);
      *(int4*)&xs_s[j][p0] = v.v;
#pragma unroll
      for (int q = 0; q < 8; q++) xsT[p0 + q][j] = v.u[q];
      int4 s = *(const int4*)(spbf + (size_t)bkh * 2048 + t * 8);
      *(int4*)&sp_s[t >> 3][(t & 7) * 8] = s;
      if (t < 64) {
        float cv = cs[(size_t)bkh * kCH + t];
        cs_s[t] = cv;
        ecs_s[t] = __expf(cv);
        dt_s[t] = dt[(rowbase + t) * kNH + h];
      }
    }
    __syncthreads();
    int i0 = wv * 16;
    int ia = i0 + l15;
    float csi = cs_s[ia];
    U16x8 af[2];
#pragma unroll
    for (int kt = 0; kt < 2; kt++) {
#pragma unroll
      for (int q = 0; q < 8; q++) {
        int j = kt * 32 + lk8 + q;
        float v = 0.f;
        if (j <= ia) v = __expf(csi - cs_s[j]) * dt_s[j] * CBT[j][ia];
        af[kt].u[q] = f2b(v);
      }
    }
#pragma unroll
    for (int pt = 0; pt < 2; pt++) {
      f32x4 acc = {0.f, 0.f, 0.f, 0.f};
      f32x4 acc2 = {0.f, 0.f, 0.f, 0.f};
#pragma unroll
      for (int kt = 0; kt < 2; kt++) {
        bf16x8 bx = *(const bf16x8*)&xsT[pt * 16 + l15][kt * 32 + lk8];
        acc = __builtin_amdgcn_mfma_f32_16x16x32_bf16(af[kt].b, bx, acc, 0, 0, 0);
        bf16x8 ac = *(const bf16x8*)&Cls[i0 + l15][kt * 32 + lk8];
        bf16x8 bs = *(const bf16x8*)&sp_s[pt * 16 + l15][kt * 32 + lk8];
        acc2 = __builtin_amdgcn_mfma_f32_16x16x32_bf16(ac, bs, acc2, 0, 0, 0);
      }
#pragma unroll
      for (int r = 0; r < 4; r++) {
        int io = i0 + (lane >> 4) * 4 + r;
        int p = pt * 16 + l15;
        float xsv = b2f(xs_s[io][p]);
        float v = acc[r] + ecs_s[io] * acc2[r] + Dp * xsv;
        y[(rowbase + io) * kDI + h * 32 + p] = f2b(v);
      }
    }
  }
}

// ---------------- gate+RMSNorm: wave per row; bf16 in/out ----------------
__global__ __launch_bounds__(256) void gate_norm_kernel(const ushort* __restrict__ zxb,
                                                        const float* __restrict__ nw0,
                                                        const float* __restrict__ nw1,
                                                        const ushort* __restrict__ y,
                                                        ushort* __restrict__ ybf) {
  int t = threadIdx.x;
  int lane = t & 63;
  int row = blockIdx.x * 4 + (t >> 6);
  int dir = (row >= kRowsD) ? 1 : 0;
  const float* nw = dir ? nw1 : nw0;
  int e0 = lane * 8;
  U16x8 zu, yu;
  zu.v = *(const int4*)(zxb + (size_t)row * kDPROJ + e0);
  yu.v = *(const int4*)(y + (size_t)row * kDI + e0);
  float v[8];
  float ss = 0.f;
#pragma unroll
  for (int q = 0; q < 8; q++) {
    float z = b2f(zu.u[q]);
    float gz = z / (1.f + __expf(-z));
    v[q] = b2f(yu.u[q]) * gz;
    ss += v[q] * v[q];
  }
#pragma unroll
  for (int o = 32; o > 0; o >>= 1) ss += __shfl_xor(ss, o);
  float scale = rsqrtf(ss * (1.0f / kDI) + 1e-5f);
  float4 n0 = *(const float4*)&nw[e0];
  float4 n1 = *(const float4*)&nw[e0 + 4];
  float na[8] = {n0.x, n0.y, n0.z, n0.w, n1.x, n1.y, n1.z, n1.w};
  U16x8 o;
#pragma unroll
  for (int q = 0; q < 8; q++) o.u[q] = f2b(v[q] * scale * na[q]);
  *(int4*)&ybf[(size_t)row * kDI + e0] = o.v;
}

// ---------------- hcat bf16 ----------------
__global__ __launch_bounds__(256) void concat_kernel(const float* __restrict__ h,
                                                     ushort* __restrict__ hcat) {
  int idx = blockIdx.x * 256 + threadIdx.x;
  if (idx >= 4 * kL * 2 * kDM) return;
  int e = idx & 511;
  int l = (idx >> 9) & (kL - 1);
  int b = idx >> 20;
  float v;
  if (e < kDM)
    v = h[((size_t)(b * kL + l)) * kDM + e];
  else
    v = h[((size_t)((4 + b) * kL + (kL - 1 - l))) * kDM + (e - kDM)];
  hcat[idx] = f2b(v);
}

}  // namespace

extern "C" void kernel_launch(void* const* d_in, const int* in_sizes, int n_in,
                              void* d_out, int out_size, void* d_ws, size_t ws_size,
                              hipStream_t stream) {
  const float* x = (const float*)d_in[0];
  const float* fw_ln_w = (const float*)d_in[1];
  const float* fw_ln_b = (const float*)d_in[2];
  const float* fw_win = (const float*)d_in[3];
  const float* fw_convw = (const float*)d_in[4];
  const float* fw_convb = (const float*)d_in[5];
  const float* fw_alog = (const float*)d_in[6];
  const float* fw_dtb = (const float*)d_in[7];
  const float* fw_D = (const float*)d_in[8];
  const float* fw_nw = (const float*)d_in[9];
  const float* fw_wout = (const float*)d_in[10];
  const float* bw_ln_w = (const float*)d_in[11];
  const float* bw_ln_b = (const float*)d_in[12];
  const float* bw_win = (const float*)d_in[13];
  const float* bw_convw = (const float*)d_in[14];
  const float* bw_convb = (const float*)d_in[15];
  const float* bw_alog = (const float*)d_in[16];
  const float* bw_dtb = (const float*)d_in[17];
  const float* bw_D = (const float*)d_in[18];
  const float* bw_nw = (const float*)d_in[19];
  const float* bw_wout = (const float*)d_in[20];
  const float* fusion_w = (const float*)d_in[21];
  float* out = (float*)d_out;

  float* ws = (float*)d_ws;
  float* h = ws;                                   // 16384*256 f32
  float* dtraw = h + (size_t)kRows * kDM;          // 16384*16 f32
  float* dt = dtraw + (size_t)kRows * kNH;         // 16384*16 f32
  float* cs = dt + (size_t)kRows * kNH;            // 4096*64 f32
  float* g = cs + (size_t)kBB * kKC * kNH * kCH;   // 4096 f32
  ushort* zxb = (ushort*)(g + (size_t)kBB * kKC * kNH);  // 16384*1168 bf16
  ushort* xcb = zxb + (size_t)kRows * kDPROJ;            // 16384*640
  ushort* states = xcb + (size_t)kRows * kCDIM;          // 4096*2048
  ushort* spbf = states + (size_t)kBB * kKC * kNH * 2048;  // 4096*2048
  ushort* ybuf = spbf + (size_t)kBB * kKC * kNH * 2048;    // 16384*512
  ushort* xnbf = ybuf + (size_t)kRows * kDI;               // 16384*256 (also hcat)
  ushort* ybf = xnbf + (size_t)kRows * kDM;                // 16384*512
  ushort* winbf = ybf + (size_t)kRows * kDI;               // 2*8*1168*256
  ushort* woutbf = winbf + (size_t)2 * 8 * kDPROJ * kDM;   // 2*8*256*512
  ushort* fusbf = woutbf + (size_t)2 * 8 * kDM * kDI;      // 256*512
  ushort* hcatbf = xnbf;

  {
    int nw1 = 8 * kDPROJ * kDM / 4;
    f2b_kernel<<<(nw1 + 255) / 256, 256, 0, stream>>>(fw_win, winbf, nw1);
    f2b_kernel<<<(nw1 + 255) / 256, 256, 0, stream>>>(
        bw_win, winbf + (size_t)8 * kDPROJ * kDM, nw1);
    int nw2 = 8 * kDM * kDI / 4;
    f2b_kernel<<<(nw2 + 255) / 256, 256, 0, stream>>>(fw_wout, woutbf, nw2);
    f2b_kernel<<<(nw2 + 255) / 256, 256, 0, stream>>>(
        bw_wout, woutbf + (size_t)8 * kDM * kDI, nw2);
    int nw3 = kDM * kDI / 4;
    f2b_kernel<<<(nw3 + 255) / 256, 256, 0, stream>>>(fusion_w, fusbf, nw3);
  }

  init_h_kernel<<<(4 * kL * kDM + 255) / 256, 256, 0, stream>>>(x, h);

  for (int i = 0; i < 8; i++) {
    const size_t oLN = (size_t)i * kDM;
    const size_t oCW = (size_t)i * kCDIM * 4;
    const size_t oCB = (size_t)i * kCDIM;
    const size_t oH = (size_t)i * kNH;
    const size_t oNW = (size_t)i * kDI;
    const ushort* win0 = winbf + (size_t)i * kDPROJ * kDM;
    const ushort* win1 = winbf + (size_t)(8 + i) * kDPROJ * kDM;
    const ushort* wout0 = woutbf + (size_t)i * kDM * kDI;
    const ushort* wout1 = woutbf + (size_t)(8 + i) * kDM * kDI;

    ln_kernel<<<kRows / 4, 256, 0, stream>>>(h, fw_ln_w + oLN, fw_ln_b + oLN,
                                             bw_ln_w + oLN, bw_ln_b + oLN, xnbf);
    {
      dim3 grid((kDPROJ + 127) / 128, kRowsD / 128, 2);
      gemm_bf16<<<grid, 256, 0, stream>>>(xnbf, win0, win1, nullptr, zxb, dtraw,
                                          kRowsD, kDPROJ, kDM, 2);
    }
    conv_kernel<<<((kRows / 16) * (kCDIM / 4) + 255) / 256, 256, 0, stream>>>(
        zxb, fw_convw + oCW, fw_convb + oCB, bw_convw + oCW, bw_convb + oCB, xcb);
    cumsum_kernel<<<kBB * kKC * kNH / 4, 256, 0, stream>>>(
        dtraw, fw_dtb + oH, bw_dtb + oH, fw_alog + oH, bw_alog + oH, dt, cs, g);
    states_kernel<<<kBB * kKC, 256, 0, stream>>>(xcb, dt, cs, states);
    scan_kernel<<<(kBB * kNH * 512 + 255) / 256, 256, 0, stream>>>(states, g, spbf);
    y_kernel<<<kBB * kKC * 2, 256, 0, stream>>>(xcb, dt, cs, spbf, fw_D + oH,
                                                bw_D + oH, ybuf);
    gate_norm_kernel<<<kRows / 4, 256, 0, stream>>>(zxb, fw_nw + oNW, bw_nw + oNW,
                                                    ybuf, ybf);
    {
      dim3 grid(kDM / 128, kRowsD / 128, 2);
      gemm_bf16<<<grid, 256, 0, stream>>>(ybf, wout0, wout1, h, nullptr, nullptr,
                                          kRowsD, kDM, kDI, 1);
    }
  }

  concat_kernel<<<(4 * kL * 2 * kDM + 255) / 256, 256, 0, stream>>>(h, hcatbf);
  {
    dim3 grid(kDM / 128, kRowsD / 128, 1);
    gemm_bf16<<<grid, 256, 0, stream>>>(hcatbf, fusbf, fusbf, out, nullptr, nullptr,
                                        kRowsD, kDM, 2 * kDM, 0);
  }
}

// Round 8
// 985.663 us; speedup vs baseline: 7.4879x; 1.1405x over previous
//
#include <hip/hip_runtime.h>
#include <math.h>

// BiMambaEncoder: 8-layer bidirectional Mamba2 stack.
// Round 8: 64x64-tile GEMM for out_proj/fusion (fixes 1-block/CU grid
// starvation at N=256); conv+cumsum merged; startup f2b merged.

namespace {

constexpr int kL = 2048;
constexpr int kDM = 256;
constexpr int kDI = 512;
constexpr int kNH = 16;
constexpr int kDS = 64;
constexpr int kCDIM = 640;
constexpr int kDPROJ = 1168;
constexpr int kCH = 64;
constexpr int kKC = 32;
constexpr int kBB = 8;
constexpr int kRowsD = 4 * kL;
constexpr int kRows = kBB * kL;

typedef __bf16 bf16x8 __attribute__((ext_vector_type(8)));
typedef float f32x4 __attribute__((ext_vector_type(4)));
typedef unsigned short ushort;

union U16x8 {
  int4 v;
  ushort u[8];
  bf16x8 b;
};

__device__ __forceinline__ ushort f2b(float x) {
  union { float f; unsigned u; } c;
  c.f = x;
  unsigned r = c.u + 0x7fffu + ((c.u >> 16) & 1u);
  return (ushort)(r >> 16);
}
__device__ __forceinline__ float b2f(ushort u) {
  union { unsigned u; float f; } c;
  c.u = ((unsigned)u) << 16;
  return c.f;
}
__device__ __forceinline__ float4 ld4b(const ushort* p) {
  ushort4 u = *(const ushort4*)p;
  return {b2f(u.x), b2f(u.y), b2f(u.z), b2f(u.w)};
}

__device__ __forceinline__ void gl_lds16(const void* g, void* l) {
  __builtin_amdgcn_global_load_lds(
      (const __attribute__((address_space(1))) unsigned int*)g,
      (__attribute__((address_space(3))) unsigned int*)l, 16, 0, 0);
}

// ---------------- merged fp32 -> bf16 weight conversion ----------------
// segments: fw_win, bw_win, fw_wout, bw_wout, fusion -> contiguous dst region.
constexpr int kQwin = 8 * kDPROJ * kDM / 4;   // 598016
constexpr int kQwout = 8 * kDM * kDI / 4;     // 262144
constexpr int kQfus = kDM * kDI / 4;          // 32768
constexpr int kQtot = 2 * kQwin + 2 * kQwout + kQfus;

__global__ __launch_bounds__(256) void f2b_all_kernel(
    const float* __restrict__ s0, const float* __restrict__ s1,
    const float* __restrict__ s2, const float* __restrict__ s3,
    const float* __restrict__ s4, ushort* __restrict__ dst) {
  int i = blockIdx.x * 256 + threadIdx.x;
  if (i >= kQtot) return;
  const float* src;
  int off;
  if (i < kQwin) { src = s0; off = i; }
  else if (i < 2 * kQwin) { src = s1; off = i - kQwin; }
  else if (i < 2 * kQwin + kQwout) { src = s2; off = i - 2 * kQwin; }
  else if (i < 2 * kQwin + 2 * kQwout) { src = s3; off = i - 2 * kQwin - kQwout; }
  else { src = s4; off = i - 2 * kQwin - 2 * kQwout; }
  float4 v = *(const float4*)&src[(size_t)off * 4];
  ushort4 o = {f2b(v.x), f2b(v.y), f2b(v.z), f2b(v.w)};
  *(ushort4*)&dst[(size_t)i * 4] = o;
}

// ---------------- init: h[0..3]=x, h[4..7]=flip(x) ----------------
__global__ __launch_bounds__(256) void init_h_kernel(const float* __restrict__ x,
                                                     float* __restrict__ h) {
  int idx = blockIdx.x * 256 + threadIdx.x;
  if (idx >= 4 * kL * kDM) return;
  int d = idx & (kDM - 1);
  int l = (idx >> 8) & (kL - 1);
  int b = idx >> 19;
  float v = x[idx];
  h[idx] = v;
  h[((size_t)((4 + b) * kL + (kL - 1 - l))) * kDM + d] = v;
}

// ---------------- LayerNorm over 256, wave per row, bf16 out ----------------
__global__ __launch_bounds__(256) void ln_kernel(const float* __restrict__ h,
                                                 const float* __restrict__ w0,
                                                 const float* __restrict__ b0,
                                                 const float* __restrict__ w1,
                                                 const float* __restrict__ b1,
                                                 ushort* __restrict__ xn) {
  int t = threadIdx.x;
  int lane = t & 63;
  int row = blockIdx.x * 4 + (t >> 6);
  int dir = (row >= kRowsD) ? 1 : 0;
  const float* w = dir ? w1 : w0;
  const float* b = dir ? b1 : b0;
  int e0 = lane * 4;
  float4 v = *(const float4*)&h[(size_t)row * kDM + e0];
  float s = v.x + v.y + v.z + v.w;
#pragma unroll
  for (int o = 32; o > 0; o >>= 1) s += __shfl_xor(s, o);
  float mu = s * (1.0f / kDM);
  float4 d = {v.x - mu, v.y - mu, v.z - mu, v.w - mu};
  float ss = d.x * d.x + d.y * d.y + d.z * d.z + d.w * d.w;
#pragma unroll
  for (int o = 32; o > 0; o >>= 1) ss += __shfl_xor(ss, o);
  float r = rsqrtf(ss * (1.0f / kDM) + 1e-5f);
  float4 wv = *(const float4*)&w[e0];
  float4 bv = *(const float4*)&b[e0];
  ushort4 o = {f2b(d.x * r * wv.x + bv.x), f2b(d.y * r * wv.y + bv.y),
               f2b(d.z * r * wv.z + bv.z), f2b(d.w * r * wv.w + bv.w)};
  *(ushort4*)&xn[(size_t)row * kDM + e0] = o;
}

// ---------------- 128x128 bf16 MFMA GEMM (in_proj) ----------------
// mode 2: bf16 store to C16 + fp32 dtraw side-channel for cols >= 1152.
__global__ __launch_bounds__(256) void gemm_bf16(const ushort* __restrict__ A,
                                                 const ushort* __restrict__ W0,
                                                 const ushort* __restrict__ W1,
                                                 ushort* __restrict__ C16,
                                                 float* __restrict__ dtraw, int Md,
                                                 int N, int K) {
  int dir = blockIdx.z;
  const ushort* W = dir ? W1 : W0;
  const ushort* Ab = A + (size_t)dir * Md * K;
  int m0 = blockIdx.y * 128;
  int n0 = blockIdx.x * 128;
  __shared__ __align__(16) ushort As[128 * 32];
  __shared__ __align__(16) ushort Ws[128 * 32];
  int tid = threadIdx.x;
  int lane = tid & 63;
  int wv = tid >> 6;
  int wr = (wv >> 1) * 64, wc = (wv & 1) * 64;
  int l16 = lane & 15, lk = lane >> 4;
  int rA = tid >> 2;
  int cA = (tid & 3) * 8;
  char* ldsA = (char*)As + wv * 1024;
  char* ldsB = (char*)Ws + wv * 1024;
  int rb0 = n0 + rA;       if (rb0 >= N) rb0 = N - 1;
  int rb1 = n0 + rA + 64;  if (rb1 >= N) rb1 = N - 1;

  f32x4 acc[4][4];
#pragma unroll
  for (int m = 0; m < 4; m++)
#pragma unroll
    for (int n = 0; n < 4; n++) acc[m][n] = {0.f, 0.f, 0.f, 0.f};

  for (int k0 = 0; k0 < K; k0 += 32) {
    gl_lds16(Ab + (size_t)(m0 + rA) * K + k0 + cA, ldsA);
    gl_lds16(Ab + (size_t)(m0 + rA + 64) * K + k0 + cA, ldsA + 4096);
    gl_lds16(W + (size_t)rb0 * K + k0 + cA, ldsB);
    gl_lds16(W + (size_t)rb1 * K + k0 + cA, ldsB + 4096);
    __syncthreads();
    bf16x8 a[4], b[4];
#pragma unroll
    for (int m = 0; m < 4; m++)
      a[m] = *(const bf16x8*)((const char*)As +
                              (((wr + m * 16 + l16) * 32 + lk * 8) << 1));
#pragma unroll
    for (int n = 0; n < 4; n++)
      b[n] = *(const bf16x8*)((const char*)Ws +
                              (((wc + n * 16 + l16) * 32 + lk * 8) << 1));
#pragma unroll
    for (int m = 0; m < 4; m++)
#pragma unroll
      for (int n = 0; n < 4; n++)
        acc[m][n] =
            __builtin_amdgcn_mfma_f32_16x16x32_bf16(a[m], b[n], acc[m][n], 0, 0, 0);
    __syncthreads();
  }
  ushort* Cb = C16 + (size_t)dir * Md * N;
  float* dtb = dtraw + (size_t)dir * Md * kNH;
#pragma unroll
  for (int m = 0; m < 4; m++) {
#pragma unroll
    for (int n = 0; n < 4; n++) {
      int col = n0 + wc + n * 16 + l16;
      if (col < N) {
#pragma unroll
        for (int r = 0; r < 4; r++) {
          int row = m0 + wr + m * 16 + lk * 4 + r;
          float v = acc[m][n][r];
          Cb[(size_t)row * N + col] = f2b(v);
          if (col >= 2 * kDI + 2 * kDS)
            dtb[(size_t)row * kNH + (col - (2 * kDI + 2 * kDS))] = v;
        }
      }
    }
  }
}

// ---------------- 64x64 bf16 MFMA GEMM (out_proj / fusion) ----------------
// mode 1: fp32 accumulate; mode 0: fp32 store. N must be multiple of 64.
__global__ __launch_bounds__(256) void gemm_bf16_64(const ushort* __restrict__ A,
                                                    const ushort* __restrict__ W0,
                                                    const ushort* __restrict__ W1,
                                                    float* __restrict__ C, int Md,
                                                    int N, int K, int accumulate) {
  int dir = blockIdx.z;
  const ushort* W = dir ? W1 : W0;
  const ushort* Ab = A + (size_t)dir * Md * K;
  float* Cb = C + (size_t)dir * Md * N;
  int m0 = blockIdx.y * 64;
  int n0 = blockIdx.x * 64;
  __shared__ __align__(16) ushort As[64 * 32];
  __shared__ __align__(16) ushort Ws[64 * 32];
  int tid = threadIdx.x;
  int lane = tid & 63;
  int wv = tid >> 6;
  int wr = (wv >> 1) * 32, wc = (wv & 1) * 32;
  int l16 = lane & 15, lk = lane >> 4;
  int rA = tid >> 2;
  int cA = (tid & 3) * 8;
  char* ldsA = (char*)As + wv * 1024;
  char* ldsB = (char*)Ws + wv * 1024;

  f32x4 acc[2][2];
#pragma unroll
  for (int m = 0; m < 2; m++)
#pragma unroll
    for (int n = 0; n < 2; n++) acc[m][n] = {0.f, 0.f, 0.f, 0.f};

  for (int k0 = 0; k0 < K; k0 += 32) {
    gl_lds16(Ab + (size_t)(m0 + rA) * K + k0 + cA, ldsA);
    gl_lds16(W + (size_t)(n0 + rA) * K + k0 + cA, ldsB);
    __syncthreads();
    bf16x8 a[2], b[2];
#pragma unroll
    for (int m = 0; m < 2; m++)
      a[m] = *(const bf16x8*)((const char*)As +
                              (((wr + m * 16 + l16) * 32 + lk * 8) << 1));
#pragma unroll
    for (int n = 0; n < 2; n++)
      b[n] = *(const bf16x8*)((const char*)Ws +
                              (((wc + n * 16 + l16) * 32 + lk * 8) << 1));
#pragma unroll
    for (int m = 0; m < 2; m++)
#pragma unroll
      for (int n = 0; n < 2; n++)
        acc[m][n] =
            __builtin_amdgcn_mfma_f32_16x16x32_bf16(a[m], b[n], acc[m][n], 0, 0, 0);
    __syncthreads();
  }
#pragma unroll
  for (int m = 0; m < 2; m++) {
#pragma unroll
    for (int n = 0; n < 2; n++) {
      int col = n0 + wc + n * 16 + l16;
#pragma unroll
      for (int r = 0; r < 4; r++) {
        int row = m0 + wr + m * 16 + lk * 4 + r;
        size_t idx = (size_t)row * N + col;
        float v = acc[m][n][r];
        if (accumulate) Cb[idx] += v;
        else Cb[idx] = v;
      }
    }
  }
}

// ---------------- merged: causal conv+silu (blocks 0..639) | softplus+cumsum ----------------
constexpr int kConvBlocks = (kRows / 16) * (kCDIM / 4) / 256;  // 640

__global__ __launch_bounds__(256) void conv_cumsum_kernel(
    const ushort* __restrict__ zxb, const float* __restrict__ cw0,
    const float* __restrict__ cb0, const float* __restrict__ cw1,
    const float* __restrict__ cb1, ushort* __restrict__ xcb,
    const float* __restrict__ dtraw, const float* __restrict__ db0,
    const float* __restrict__ db1, const float* __restrict__ al0,
    const float* __restrict__ al1, float* __restrict__ dt,
    float* __restrict__ cs, float* __restrict__ g) {
  if ((int)blockIdx.x < kConvBlocks) {
    constexpr int kCG = kCDIM / 4;
    int idx = blockIdx.x * 256 + threadIdx.x;
    int c4 = (idx % kCG) * 4;
    int rt = idx / kCG;
    int bb = rt >> 7;
    int l0 = (rt & 127) << 4;
    int dir = bb >> 2;
    const float* cw = dir ? cw1 : cw0;
    const float* cb = dir ? cb1 : cb0;
    float wt[4][4];
#pragma unroll
    for (int c = 0; c < 4; c++) {
      float4 w = *(const float4*)&cw[(c4 + c) * 4];
      wt[c][0] = w.x; wt[c][1] = w.y; wt[c][2] = w.z; wt[c][3] = w.w;
    }
    float4 bias = *(const float4*)&cb[c4];
    const ushort* base = zxb + ((size_t)(bb * kL)) * kDPROJ + kDI + c4;
    float4 rm3, rm2, rm1;
    if (l0 == 0) {
      rm3 = {0.f, 0.f, 0.f, 0.f};
      rm2 = rm3;
      rm1 = rm3;
    } else {
      rm3 = ld4b(base + (size_t)(l0 - 3) * kDPROJ);
      rm2 = ld4b(base + (size_t)(l0 - 2) * kDPROJ);
      rm1 = ld4b(base + (size_t)(l0 - 1) * kDPROJ);
    }
    ushort* outp = xcb + (size_t)(bb * kL + l0) * kCDIM + c4;
#pragma unroll
    for (int r = 0; r < 16; r++) {
      float4 cur = ld4b(base + (size_t)(l0 + r) * kDPROJ);
      float a0 = bias.x + wt[0][0] * rm3.x + wt[0][1] * rm2.x + wt[0][2] * rm1.x +
                 wt[0][3] * cur.x;
      float a1 = bias.y + wt[1][0] * rm3.y + wt[1][1] * rm2.y + wt[1][2] * rm1.y +
                 wt[1][3] * cur.y;
      float a2 = bias.z + wt[2][0] * rm3.z + wt[2][1] * rm2.z + wt[2][2] * rm1.z +
                 wt[2][3] * cur.z;
      float a3 = bias.w + wt[3][0] * rm3.w + wt[3][1] * rm2.w + wt[3][2] * rm1.w +
                 wt[3][3] * cur.w;
      ushort4 o = {f2b(a0 / (1.f + __expf(-a0))), f2b(a1 / (1.f + __expf(-a1))),
                   f2b(a2 / (1.f + __expf(-a2))), f2b(a3 / (1.f + __expf(-a3)))};
      *(ushort4*)(outp + (size_t)r * kCDIM) = o;
      rm3 = rm2;
      rm2 = rm1;
      rm1 = cur;
    }
  } else {
    int t = threadIdx.x;
    int c = t & 63;
    int wid = ((int)blockIdx.x - kConvBlocks) * 4 + (t >> 6);
    int h = wid & (kNH - 1);
    int k = (wid >> 4) & (kKC - 1);
    int bb = wid >> 9;
    int dir = bb >> 2;
    int row = bb * kL + k * kCH + c;
    float x = dtraw[(size_t)row * kNH + h] + (dir ? db1 : db0)[h];
    float dtv = (x > 20.f) ? x : log1pf(expf(x));
    dt[(size_t)row * kNH + h] = dtv;
    float A = -__expf((dir ? al1 : al0)[h]);
    float s = dtv * A;
#pragma unroll
    for (int off = 1; off < 64; off <<= 1) {
      float u = __shfl_up(s, off);
      if (c >= off) s += u;
    }
    cs[(size_t)wid * kCH + c] = s;
    if (c == 63) g[wid] = __expf(s);
  }
}

// ---------------- MFMA states: one block per (b,k), wave per head; bf16 out ----------------
__global__ __launch_bounds__(256) void states_kernel(const ushort* __restrict__ xcb,
                                                     const float* __restrict__ dt,
                                                     const float* __restrict__ cs,
                                                     ushort* __restrict__ states) {
  int bk = blockIdx.x;
  int k = bk & (kKC - 1);
  int bb = bk >> 5;
  __shared__ __align__(16) ushort Bstage[64][72];
  __shared__ __align__(16) ushort Bt[64][72];   // Bt[n][j]
  __shared__ __align__(16) ushort Ap[4][32][72];  // per-wave A' = w*xs^T
  __shared__ float w_s[16][64];
  int t = threadIdx.x;
  int lane = t & 63, wv = t >> 6;
  size_t rowbase = (size_t)(bb * kL + k * kCH);
  {
    int j = t >> 2, n0 = (t & 3) * 16;
    const ushort* src = xcb + (rowbase + j) * kCDIM + kDI + n0;
    *(int4*)&Bstage[j][n0] = *(const int4*)src;
    *(int4*)&Bstage[j][n0 + 8] = *(const int4*)(src + 8);
  }
#pragma unroll
  for (int i = 0; i < 4; i++) {
    int e = t + i * 256;
    int h = e >> 6, c = e & 63;
    const float* csb = cs + ((size_t)bk * 16 + h) * kCH;
    w_s[h][c] = __expf(csb[63] - csb[c]) * dt[(rowbase + c) * kNH + h];
  }
  __syncthreads();
#pragma unroll
  for (int i = 0; i < 16; i++) {
    int e = t + i * 256;
    int j = e & 63, n = e >> 6;
    Bt[n][j] = Bstage[j][n];
  }
  __syncthreads();
  int l15 = lane & 15, lk8 = (lane >> 4) * 8;
  for (int hg = 0; hg < 4; hg++) {
    int h = hg * 4 + wv;
    float wl = w_s[h][lane];
    const ushort* xrow = xcb + (rowbase + lane) * kCDIM + h * 32;
#pragma unroll
    for (int q4 = 0; q4 < 4; q4++) {
      U16x8 v;
      v.v = *(const int4*)(xrow + q4 * 8);
#pragma unroll
      for (int q = 0; q < 8; q++)
        Ap[wv][q4 * 8 + q][lane] = f2b(b2f(v.u[q]) * wl);
    }
#pragma unroll
    for (int pt = 0; pt < 2; pt++) {
#pragma unroll
      for (int nt = 0; nt < 4; nt++) {
        f32x4 acc = {0.f, 0.f, 0.f, 0.f};
#pragma unroll
        for (int kt = 0; kt < 2; kt++) {
          bf16x8 a = *(const bf16x8*)&Ap[wv][pt * 16 + l15][kt * 32 + lk8];
          bf16x8 b = *(const bf16x8*)&Bt[nt * 16 + l15][kt * 32 + lk8];
          acc = __builtin_amdgcn_mfma_f32_16x16x32_bf16(a, b, acc, 0, 0, 0);
        }
        size_t base = ((size_t)bk * 16 + h) * 2048;
#pragma unroll
        for (int r = 0; r < 4; r++) {
          int p = pt * 16 + (lane >> 4) * 4 + r;
          states[base + p * 64 + nt * 16 + l15] = f2b(acc[r]);
        }
      }
    }
  }
}

// ---------------- chunk scan (x4 vectorized): sprev=S (bf16); S=g*S+states ----------------
__global__ __launch_bounds__(256) void scan_kernel(const ushort* __restrict__ st,
                                                   const float* __restrict__ g,
                                                   ushort* __restrict__ spbf) {
  int idx = blockIdx.x * 256 + threadIdx.x;  // over kBB*kNH*512 quads
  if (idx >= kBB * kNH * 512) return;
  int pn4 = (idx & 511) * 4;
  int h = (idx >> 9) & (kNH - 1);
  int bb = idx >> 13;
  float S[4] = {0.f, 0.f, 0.f, 0.f};
  for (int k = 0; k < kKC; k++) {
    size_t off = (((size_t)(bb * kKC + k) * kNH + h) * 2048) + pn4;
    ushort4 so = {f2b(S[0]), f2b(S[1]), f2b(S[2]), f2b(S[3])};
    *(ushort4*)&spbf[off] = so;
    ushort4 sv = *(const ushort4*)&st[off];
    float gk = g[(bb * kKC + k) * kNH + h];
    S[0] = gk * S[0] + b2f(sv.x);
    S[1] = gk * S[1] + b2f(sv.y);
    S[2] = gk * S[2] + b2f(sv.z);
    S[3] = gk * S[3] + b2f(sv.w);
  }
}

// ---------------- fused y: per (b,k,half-heads); bf16 out ----------------
__global__ __launch_bounds__(256) void y_kernel(const ushort* __restrict__ xcb,
                                                const float* __restrict__ dt,
                                                const float* __restrict__ cs,
                                                const ushort* __restrict__ spbf,
                                                const float* __restrict__ D0,
                                                const float* __restrict__ D1,
                                                ushort* __restrict__ y) {
  int bid = blockIdx.x;
  int hh = bid & 1;
  int bk = bid >> 1;
  int k = bk & (kKC - 1);
  int bb = bk >> 5;
  int dir = bb >> 2;
  __shared__ __align__(16) ushort Cls[64][72];
  __shared__ __align__(16) ushort Bls[64][72];
  __shared__ float CBT[64][67];  // CBT[j][i] = CB[i][j]
  __shared__ __align__(16) ushort xs_s[64][40];
  __shared__ __align__(16) ushort xsT[32][72];
  __shared__ __align__(16) ushort sp_s[32][72];
  __shared__ float cs_s[64], dt_s[64], ecs_s[64];
  int t = threadIdx.x, lane = t & 63, wv = t >> 6;
  int l15 = lane & 15, lk8 = (lane >> 4) * 8;
  size_t rowbase = (size_t)(bb * kL + k * kCH);
  {
    int j = t >> 2, n0 = (t & 3) * 16;
    const ushort* pB = xcb + (rowbase + j) * kCDIM + kDI;
    *(int4*)&Bls[j][n0] = *(const int4*)(pB + n0);
    *(int4*)&Bls[j][n0 + 8] = *(const int4*)(pB + n0 + 8);
    *(int4*)&Cls[j][n0] = *(const int4*)(pB + kDS + n0);
    *(int4*)&Cls[j][n0 + 8] = *(const int4*)(pB + kDS + n0 + 8);
  }
  __syncthreads();
  {
    int i0 = wv * 16;
#pragma unroll
    for (int jt = 0; jt < 4; jt++) {
      f32x4 acc = {0.f, 0.f, 0.f, 0.f};
#pragma unroll
      for (int kt = 0; kt < 2; kt++) {
        bf16x8 a = *(const bf16x8*)&Cls[i0 + l15][kt * 32 + lk8];
        bf16x8 b = *(const bf16x8*)&Bls[jt * 16 + l15][kt * 32 + lk8];
        acc = __builtin_amdgcn_mfma_f32_16x16x32_bf16(a, b, acc, 0, 0, 0);
      }
#pragma unroll
      for (int r = 0; r < 4; r++)
        CBT[jt * 16 + l15][i0 + (lane >> 4) * 4 + r] = acc[r];
    }
  }
  for (int hi = 0; hi < 8; hi++) {
    int h = hh * 8 + hi;
    int bkh = bk * 16 + h;
    float Dp = (dir ? D1 : D0)[h];
    __syncthreads();
    {
      int j = t >> 2, p0 = (t & 3) * 8;
      U16x8 v;
      v.v = *(const int4*)(xcb + (rowbase + j) * kCDIM + h * 32 + p0);
      *(int4*)&xs_s[j][p0] = v.v;
#pragma unroll
      for (int q = 0; q < 8; q++) xsT[p0 + q][j] = v.u[q];
      int4 s = *(const int4*)(spbf + (size_t)bkh * 2048 + t * 8);
      *(int4*)&sp_s[t >> 3][(t & 7) * 8] = s;
      if (t < 64) {
        float cv = cs[(size_t)bkh * kCH + t];
        cs_s[t] = cv;
        ecs_s[t] = __expf(cv);
        dt_s[t] = dt[(rowbase + t) * kNH + h];
      }
    }
    __syncthreads();
    int i0 = wv * 16;
    int ia = i0 + l15;
    float csi = cs_s[ia];
    U16x8 af[2];
#pragma unroll
    for (int kt = 0; kt < 2; kt++) {
#pragma unroll
      for (int q = 0; q < 8; q++) {
        int j = kt * 32 + lk8 + q;
        float v = 0.f;
        if (j <= ia) v = __expf(csi - cs_s[j]) * dt_s[j] * CBT[j][ia];
        af[kt].u[q] = f2b(v);
      }
    }
#pragma unroll
    for (int pt = 0; pt < 2; pt++) {
      f32x4 acc = {0.f, 0.f, 0.f, 0.f};
      f32x4 acc2 = {0.f, 0.f, 0.f, 0.f};
#pragma unroll
      for (int kt = 0; kt < 2; kt++) {
        bf16x8 bx = *(const bf16x8*)&xsT[pt * 16 + l15][kt * 32 + lk8];
        acc = __builtin_amdgcn_mfma_f32_16x16x32_bf16(af[kt].b, bx, acc, 0, 0, 0);
        bf16x8 ac = *(const bf16x8*)&Cls[i0 + l15][kt * 32 + lk8];
        bf16x8 bs = *(const bf16x8*)&sp_s[pt * 16 + l15][kt * 32 + lk8];
        acc2 = __builtin_amdgcn_mfma_f32_16x16x32_bf16(ac, bs, acc2, 0, 0, 0);
      }
#pragma unroll
      for (int r = 0; r < 4; r++) {
        int io = i0 + (lane >> 4) * 4 + r;
        int p = pt * 16 + l15;
        float xsv = b2f(xs_s[io][p]);
        float v = acc[r] + ecs_s[io] * acc2[r] + Dp * xsv;
        y[(rowbase + io) * kDI + h * 32 + p] = f2b(v);
      }
    }
  }
}

// ---------------- gate+RMSNorm: wave per row; bf16 in/out ----------------
__global__ __launch_bounds__(256) void gate_norm_kernel(const ushort* __restrict__ zxb,
                                                        const float* __restrict__ nw0,
                                                        const float* __restrict__ nw1,
                                                        const ushort* __restrict__ y,
                                                        ushort* __restrict__ ybf) {
  int t = threadIdx.x;
  int lane = t & 63;
  int row = blockIdx.x * 4 + (t >> 6);
  int dir = (row >= kRowsD) ? 1 : 0;
  const float* nw = dir ? nw1 : nw0;
  int e0 = lane * 8;
  U16x8 zu, yu;
  zu.v = *(const int4*)(zxb + (size_t)row * kDPROJ + e0);
  yu.v = *(const int4*)(y + (size_t)row * kDI + e0);
  float v[8];
  float ss = 0.f;
#pragma unroll
  for (int q = 0; q < 8; q++) {
    float z = b2f(zu.u[q]);
    float gz = z / (1.f + __expf(-z));
    v[q] = b2f(yu.u[q]) * gz;
    ss += v[q] * v[q];
  }
#pragma unroll
  for (int o = 32; o > 0; o >>= 1) ss += __shfl_xor(ss, o);
  float scale = rsqrtf(ss * (1.0f / kDI) + 1e-5f);
  float4 n0 = *(const float4*)&nw[e0];
  float4 n1 = *(const float4*)&nw[e0 + 4];
  float na[8] = {n0.x, n0.y, n0.z, n0.w, n1.x, n1.y, n1.z, n1.w};
  U16x8 o;
#pragma unroll
  for (int q = 0; q < 8; q++) o.u[q] = f2b(v[q] * scale * na[q]);
  *(int4*)&ybf[(size_t)row * kDI + e0] = o.v;
}

// ---------------- hcat bf16 ----------------
__global__ __launch_bounds__(256) void concat_kernel(const float* __restrict__ h,
                                                     ushort* __restrict__ hcat) {
  int idx = blockIdx.x * 256 + threadIdx.x;
  if (idx >= 4 * kL * 2 * kDM) return;
  int e = idx & 511;
  int l = (idx >> 9) & (kL - 1);
  int b = idx >> 20;
  float v;
  if (e < kDM)
    v = h[((size_t)(b * kL + l)) * kDM + e];
  else
    v = h[((size_t)((4 + b) * kL + (kL - 1 - l))) * kDM + (e - kDM)];
  hcat[idx] = f2b(v);
}

}  // namespace

extern "C" void kernel_launch(void* const* d_in, const int* in_sizes, int n_in,
                              void* d_out, int out_size, void* d_ws, size_t ws_size,
                              hipStream_t stream) {
  const float* x = (const float*)d_in[0];
  const float* fw_ln_w = (const float*)d_in[1];
  const float* fw_ln_b = (const float*)d_in[2];
  const float* fw_win = (const float*)d_in[3];
  const float* fw_convw = (const float*)d_in[4];
  const float* fw_convb = (const float*)d_in[5];
  const float* fw_alog = (const float*)d_in[6];
  const float* fw_dtb = (const float*)d_in[7];
  const float* fw_D = (const float*)d_in[8];
  const float* fw_nw = (const float*)d_in[9];
  const float* fw_wout = (const float*)d_in[10];
  const float* bw_ln_w = (const float*)d_in[11];
  const float* bw_ln_b = (const float*)d_in[12];
  const float* bw_win = (const float*)d_in[13];
  const float* bw_convw = (const float*)d_in[14];
  const float* bw_convb = (const float*)d_in[15];
  const float* bw_alog = (const float*)d_in[16];
  const float* bw_dtb = (const float*)d_in[17];
  const float* bw_D = (const float*)d_in[18];
  const float* bw_nw = (const float*)d_in[19];
  const float* bw_wout = (const float*)d_in[20];
  const float* fusion_w = (const float*)d_in[21];
  float* out = (float*)d_out;

  float* ws = (float*)d_ws;
  float* h = ws;                                   // 16384*256 f32
  float* dtraw = h + (size_t)kRows * kDM;          // 16384*16 f32
  float* dt = dtraw + (size_t)kRows * kNH;         // 16384*16 f32
  float* cs = dt + (size_t)kRows * kNH;            // 4096*64 f32
  float* g = cs + (size_t)kBB * kKC * kNH * kCH;   // 4096 f32
  ushort* zxb = (ushort*)(g + (size_t)kBB * kKC * kNH);  // 16384*1168 bf16
  ushort* xcb = zxb + (size_t)kRows * kDPROJ;            // 16384*640
  ushort* states = xcb + (size_t)kRows * kCDIM;          // 4096*2048
  ushort* spbf = states + (size_t)kBB * kKC * kNH * 2048;  // 4096*2048
  ushort* ybuf = spbf + (size_t)kBB * kKC * kNH * 2048;    // 16384*512
  ushort* xnbf = ybuf + (size_t)kRows * kDI;               // 16384*256 (also hcat)
  ushort* ybf = xnbf + (size_t)kRows * kDM;                // 16384*512
  ushort* winbf = ybf + (size_t)kRows * kDI;               // 2*8*1168*256
  ushort* woutbf = winbf + (size_t)2 * 8 * kDPROJ * kDM;   // 2*8*256*512
  ushort* fusbf = woutbf + (size_t)2 * 8 * kDM * kDI;      // 256*512
  ushort* hcatbf = xnbf;

  f2b_all_kernel<<<(kQtot + 255) / 256, 256, 0, stream>>>(fw_win, bw_win, fw_wout,
                                                          bw_wout, fusion_w, winbf);
  init_h_kernel<<<(4 * kL * kDM + 255) / 256, 256, 0, stream>>>(x, h);

  for (int i = 0; i < 8; i++) {
    const size_t oLN = (size_t)i * kDM;
    const size_t oCW = (size_t)i * kCDIM * 4;
    const size_t oCB = (size_t)i * kCDIM;
    const size_t oH = (size_t)i * kNH;
    const size_t oNW = (size_t)i * kDI;
    const ushort* win0 = winbf + (size_t)i * kDPROJ * kDM;
    const ushort* win1 = winbf + (size_t)(8 + i) * kDPROJ * kDM;
    const ushort* wout0 = woutbf + (size_t)i * kDM * kDI;
    const ushort* wout1 = woutbf + (size_t)(8 + i) * kDM * kDI;

    ln_kernel<<<kRows / 4, 256, 0, stream>>>(h, fw_ln_w + oLN, fw_ln_b + oLN,
                                             bw_ln_w + oLN, bw_ln_b + oLN, xnbf);
    {
      dim3 grid((kDPROJ + 127) / 128, kRowsD / 128, 2);
      gemm_bf16<<<grid, 256, 0, stream>>>(xnbf, win0, win1, zxb, dtraw, kRowsD,
                                          kDPROJ, kDM);
    }
    {
      int cumsumBlocks = kBB * kKC * kNH / 4;
      conv_cumsum_kernel<<<kConvBlocks + cumsumBlocks, 256, 0, stream>>>(
          zxb, fw_convw + oCW, fw_convb + oCB, bw_convw + oCW, bw_convb + oCB, xcb,
          dtraw, fw_dtb + oH, bw_dtb + oH, fw_alog + oH, bw_alog + oH, dt, cs, g);
    }
    states_kernel<<<kBB * kKC, 256, 0, stream>>>(xcb, dt, cs, states);
    scan_kernel<<<(kBB * kNH * 512 + 255) / 256, 256, 0, stream>>>(states, g, spbf);
    y_kernel<<<kBB * kKC * 2, 256, 0, stream>>>(xcb, dt, cs, spbf, fw_D + oH,
                                                bw_D + oH, ybuf);
    gate_norm_kernel<<<kRows / 4, 256, 0, stream>>>(zxb, fw_nw + oNW, bw_nw + oNW,
                                                    ybuf, ybf);
    {
      dim3 grid(kDM / 64, kRowsD / 64, 2);
      gemm_bf16_64<<<grid, 256, 0, stream>>>(ybf, wout0, wout1, h, kRowsD, kDM, kDI,
                                             1);
    }
  }

  concat_kernel<<<(4 * kL * 2 * kDM + 255) / 256, 256, 0, stream>>>(h, hcatbf);
  {
    dim3 grid(kDM / 64, kRowsD / 64, 1);
    gemm_bf16_64<<<grid, 256, 0, stream>>>(hcatbf, fusbf, fusbf, out, kRowsD, kDM,
                                           2 * kDM, 0);
  }
}

// Round 9
// 954.368 us; speedup vs baseline: 7.7334x; 1.0328x over previous
//
#include <hip/hip_runtime.h>
#include <math.h>

// BiMambaEncoder: 8-layer bidirectional Mamba2 stack.
// Round 9: XCD-aware m-major swizzle on all GEMMs (per-XCD L2 reuse of A);
// conv widened to 8 channels/thread (16B loads).

namespace {

constexpr int kL = 2048;
constexpr int kDM = 256;
constexpr int kDI = 512;
constexpr int kNH = 16;
constexpr int kDS = 64;
constexpr int kCDIM = 640;
constexpr int kDPROJ = 1168;
constexpr int kCH = 64;
constexpr int kKC = 32;
constexpr int kBB = 8;
constexpr int kRowsD = 4 * kL;
constexpr int kRows = kBB * kL;

typedef __bf16 bf16x8 __attribute__((ext_vector_type(8)));
typedef float f32x4 __attribute__((ext_vector_type(4)));
typedef unsigned short ushort;

union U16x8 {
  int4 v;
  ushort u[8];
  bf16x8 b;
};

__device__ __forceinline__ ushort f2b(float x) {
  union { float f; unsigned u; } c;
  c.f = x;
  unsigned r = c.u + 0x7fffu + ((c.u >> 16) & 1u);
  return (ushort)(r >> 16);
}
__device__ __forceinline__ float b2f(ushort u) {
  union { unsigned u; float f; } c;
  c.u = ((unsigned)u) << 16;
  return c.f;
}

__device__ __forceinline__ void gl_lds16(const void* g, void* l) {
  __builtin_amdgcn_global_load_lds(
      (const __attribute__((address_space(1))) unsigned int*)g,
      (__attribute__((address_space(3))) unsigned int*)l, 16, 0, 0);
}

// ---------------- merged fp32 -> bf16 weight conversion ----------------
constexpr int kQwin = 8 * kDPROJ * kDM / 4;
constexpr int kQwout = 8 * kDM * kDI / 4;
constexpr int kQfus = kDM * kDI / 4;
constexpr int kQtot = 2 * kQwin + 2 * kQwout + kQfus;

__global__ __launch_bounds__(256) void f2b_all_kernel(
    const float* __restrict__ s0, const float* __restrict__ s1,
    const float* __restrict__ s2, const float* __restrict__ s3,
    const float* __restrict__ s4, ushort* __restrict__ dst) {
  int i = blockIdx.x * 256 + threadIdx.x;
  if (i >= kQtot) return;
  const float* src;
  int off;
  if (i < kQwin) { src = s0; off = i; }
  else if (i < 2 * kQwin) { src = s1; off = i - kQwin; }
  else if (i < 2 * kQwin + kQwout) { src = s2; off = i - 2 * kQwin; }
  else if (i < 2 * kQwin + 2 * kQwout) { src = s3; off = i - 2 * kQwin - kQwout; }
  else { src = s4; off = i - 2 * kQwin - 2 * kQwout; }
  float4 v = *(const float4*)&src[(size_t)off * 4];
  ushort4 o = {f2b(v.x), f2b(v.y), f2b(v.z), f2b(v.w)};
  *(ushort4*)&dst[(size_t)i * 4] = o;
}

// ---------------- init: h[0..3]=x, h[4..7]=flip(x) ----------------
__global__ __launch_bounds__(256) void init_h_kernel(const float* __restrict__ x,
                                                     float* __restrict__ h) {
  int idx = blockIdx.x * 256 + threadIdx.x;
  if (idx >= 4 * kL * kDM) return;
  int d = idx & (kDM - 1);
  int l = (idx >> 8) & (kL - 1);
  int b = idx >> 19;
  float v = x[idx];
  h[idx] = v;
  h[((size_t)((4 + b) * kL + (kL - 1 - l))) * kDM + d] = v;
}

// ---------------- LayerNorm over 256, wave per row, bf16 out ----------------
__global__ __launch_bounds__(256) void ln_kernel(const float* __restrict__ h,
                                                 const float* __restrict__ w0,
                                                 const float* __restrict__ b0,
                                                 const float* __restrict__ w1,
                                                 const float* __restrict__ b1,
                                                 ushort* __restrict__ xn) {
  int t = threadIdx.x;
  int lane = t & 63;
  int row = blockIdx.x * 4 + (t >> 6);
  int dir = (row >= kRowsD) ? 1 : 0;
  const float* w = dir ? w1 : w0;
  const float* b = dir ? b1 : b0;
  int e0 = lane * 4;
  float4 v = *(const float4*)&h[(size_t)row * kDM + e0];
  float s = v.x + v.y + v.z + v.w;
#pragma unroll
  for (int o = 32; o > 0; o >>= 1) s += __shfl_xor(s, o);
  float mu = s * (1.0f / kDM);
  float4 d = {v.x - mu, v.y - mu, v.z - mu, v.w - mu};
  float ss = d.x * d.x + d.y * d.y + d.z * d.z + d.w * d.w;
#pragma unroll
  for (int o = 32; o > 0; o >>= 1) ss += __shfl_xor(ss, o);
  float r = rsqrtf(ss * (1.0f / kDM) + 1e-5f);
  float4 wv = *(const float4*)&w[e0];
  float4 bv = *(const float4*)&b[e0];
  ushort4 o = {f2b(d.x * r * wv.x + bv.x), f2b(d.y * r * wv.y + bv.y),
               f2b(d.z * r * wv.z + bv.z), f2b(d.w * r * wv.w + bv.w)};
  *(ushort4*)&xn[(size_t)row * kDM + e0] = o;
}

// ---------------- 128x128 bf16 MFMA GEMM (in_proj) ----------------
// 1D grid.x = NT * (Md/128), XCD-swizzled m-major; grid.z = dir.
// bf16 store to C16 + fp32 dtraw side-channel for cols >= 1152.
__global__ __launch_bounds__(256) void gemm_bf16(const ushort* __restrict__ A,
                                                 const ushort* __restrict__ W0,
                                                 const ushort* __restrict__ W1,
                                                 ushort* __restrict__ C16,
                                                 float* __restrict__ dtraw, int Md,
                                                 int N, int K, int NT) {
  int dir = blockIdx.z;
  const ushort* W = dir ? W1 : W0;
  const ushort* Ab = A + (size_t)dir * Md * K;
  // XCD swizzle: blocks with wg%8==c run on XCD c; give XCD c a contiguous
  // m-major chunk so its L2 re-serves the A rows across all n-tiles.
  int wg = blockIdx.x;
  int chunk = gridDim.x >> 3;
  int swz = (wg & 7) * chunk + (wg >> 3);
  int m0 = (swz / NT) * 128;
  int n0 = (swz % NT) * 128;
  __shared__ __align__(16) ushort As[128 * 32];
  __shared__ __align__(16) ushort Ws[128 * 32];
  int tid = threadIdx.x;
  int lane = tid & 63;
  int wv = tid >> 6;
  int wr = (wv >> 1) * 64, wc = (wv & 1) * 64;
  int l16 = lane & 15, lk = lane >> 4;
  int rA = tid >> 2;
  int cA = (tid & 3) * 8;
  char* ldsA = (char*)As + wv * 1024;
  char* ldsB = (char*)Ws + wv * 1024;
  int rb0 = n0 + rA;       if (rb0 >= N) rb0 = N - 1;
  int rb1 = n0 + rA + 64;  if (rb1 >= N) rb1 = N - 1;

  f32x4 acc[4][4];
#pragma unroll
  for (int m = 0; m < 4; m++)
#pragma unroll
    for (int n = 0; n < 4; n++) acc[m][n] = {0.f, 0.f, 0.f, 0.f};

  for (int k0 = 0; k0 < K; k0 += 32) {
    gl_lds16(Ab + (size_t)(m0 + rA) * K + k0 + cA, ldsA);
    gl_lds16(Ab + (size_t)(m0 + rA + 64) * K + k0 + cA, ldsA + 4096);
    gl_lds16(W + (size_t)rb0 * K + k0 + cA, ldsB);
    gl_lds16(W + (size_t)rb1 * K + k0 + cA, ldsB + 4096);
    __syncthreads();
    bf16x8 a[4], b[4];
#pragma unroll
    for (int m = 0; m < 4; m++)
      a[m] = *(const bf16x8*)((const char*)As +
                              (((wr + m * 16 + l16) * 32 + lk * 8) << 1));
#pragma unroll
    for (int n = 0; n < 4; n++)
      b[n] = *(const bf16x8*)((const char*)Ws +
                              (((wc + n * 16 + l16) * 32 + lk * 8) << 1));
#pragma unroll
    for (int m = 0; m < 4; m++)
#pragma unroll
      for (int n = 0; n < 4; n++)
        acc[m][n] =
            __builtin_amdgcn_mfma_f32_16x16x32_bf16(a[m], b[n], acc[m][n], 0, 0, 0);
    __syncthreads();
  }
  ushort* Cb = C16 + (size_t)dir * Md * N;
  float* dtb = dtraw + (size_t)dir * Md * kNH;
#pragma unroll
  for (int m = 0; m < 4; m++) {
#pragma unroll
    for (int n = 0; n < 4; n++) {
      int col = n0 + wc + n * 16 + l16;
      if (col < N) {
#pragma unroll
        for (int r = 0; r < 4; r++) {
          int row = m0 + wr + m * 16 + lk * 4 + r;
          float v = acc[m][n][r];
          Cb[(size_t)row * N + col] = f2b(v);
          if (col >= 2 * kDI + 2 * kDS)
            dtb[(size_t)row * kNH + (col - (2 * kDI + 2 * kDS))] = v;
        }
      }
    }
  }
}

// ---------------- 64x64 bf16 MFMA GEMM (out_proj / fusion), XCD-swizzled ----------------
__global__ __launch_bounds__(256) void gemm_bf16_64(const ushort* __restrict__ A,
                                                    const ushort* __restrict__ W0,
                                                    const ushort* __restrict__ W1,
                                                    float* __restrict__ C, int Md,
                                                    int N, int K, int NT,
                                                    int accumulate) {
  int dir = blockIdx.z;
  const ushort* W = dir ? W1 : W0;
  const ushort* Ab = A + (size_t)dir * Md * K;
  float* Cb = C + (size_t)dir * Md * N;
  int wg = blockIdx.x;
  int chunk = gridDim.x >> 3;
  int swz = (wg & 7) * chunk + (wg >> 3);
  int m0 = (swz / NT) * 64;
  int n0 = (swz % NT) * 64;
  __shared__ __align__(16) ushort As[64 * 32];
  __shared__ __align__(16) ushort Ws[64 * 32];
  int tid = threadIdx.x;
  int lane = tid & 63;
  int wv = tid >> 6;
  int wr = (wv >> 1) * 32, wc = (wv & 1) * 32;
  int l16 = lane & 15, lk = lane >> 4;
  int rA = tid >> 2;
  int cA = (tid & 3) * 8;
  char* ldsA = (char*)As + wv * 1024;
  char* ldsB = (char*)Ws + wv * 1024;

  f32x4 acc[2][2];
#pragma unroll
  for (int m = 0; m < 2; m++)
#pragma unroll
    for (int n = 0; n < 2; n++) acc[m][n] = {0.f, 0.f, 0.f, 0.f};

  for (int k0 = 0; k0 < K; k0 += 32) {
    gl_lds16(Ab + (size_t)(m0 + rA) * K + k0 + cA, ldsA);
    gl_lds16(W + (size_t)(n0 + rA) * K + k0 + cA, ldsB);
    __syncthreads();
    bf16x8 a[2], b[2];
#pragma unroll
    for (int m = 0; m < 2; m++)
      a[m] = *(const bf16x8*)((const char*)As +
                              (((wr + m * 16 + l16) * 32 + lk * 8) << 1));
#pragma unroll
    for (int n = 0; n < 2; n++)
      b[n] = *(const bf16x8*)((const char*)Ws +
                              (((wc + n * 16 + l16) * 32 + lk * 8) << 1));
#pragma unroll
    for (int m = 0; m < 2; m++)
#pragma unroll
      for (int n = 0; n < 2; n++)
        acc[m][n] =
            __builtin_amdgcn_mfma_f32_16x16x32_bf16(a[m], b[n], acc[m][n], 0, 0, 0);
    __syncthreads();
  }
#pragma unroll
  for (int m = 0; m < 2; m++) {
#pragma unroll
    for (int n = 0; n < 2; n++) {
      int col = n0 + wc + n * 16 + l16;
#pragma unroll
      for (int r = 0; r < 4; r++) {
        int row = m0 + wr + m * 16 + lk * 4 + r;
        size_t idx = (size_t)row * N + col;
        float v = acc[m][n][r];
        if (accumulate) Cb[idx] += v;
        else Cb[idx] = v;
      }
    }
  }
}

// ---------------- merged: conv+silu (8 ch/thread) | softplus+cumsum ----------------
constexpr int kConvBlocks = (kRows / 16) * (kCDIM / 8) / 256;  // 320

__global__ __launch_bounds__(256) void conv_cumsum_kernel(
    const ushort* __restrict__ zxb, const float* __restrict__ cw0,
    const float* __restrict__ cb0, const float* __restrict__ cw1,
    const float* __restrict__ cb1, ushort* __restrict__ xcb,
    const float* __restrict__ dtraw, const float* __restrict__ db0,
    const float* __restrict__ db1, const float* __restrict__ al0,
    const float* __restrict__ al1, float* __restrict__ dt,
    float* __restrict__ cs, float* __restrict__ g) {
  if ((int)blockIdx.x < kConvBlocks) {
    constexpr int kCG = kCDIM / 8;  // 80 channel groups
    int idx = blockIdx.x * 256 + threadIdx.x;
    int c8 = (idx % kCG) * 8;
    int rt = idx / kCG;
    int bb = rt >> 7;
    int l0 = (rt & 127) << 4;
    int dir = bb >> 2;
    const float* cw = dir ? cw1 : cw0;
    const float* cb = dir ? cb1 : cb0;
    float wt[8][4];
#pragma unroll
    for (int c = 0; c < 8; c++) {
      float4 w = *(const float4*)&cw[(c8 + c) * 4];
      wt[c][0] = w.x; wt[c][1] = w.y; wt[c][2] = w.z; wt[c][3] = w.w;
    }
    float bias[8];
    {
      float4 b0 = *(const float4*)&cb[c8];
      float4 b1 = *(const float4*)&cb[c8 + 4];
      bias[0] = b0.x; bias[1] = b0.y; bias[2] = b0.z; bias[3] = b0.w;
      bias[4] = b1.x; bias[5] = b1.y; bias[6] = b1.z; bias[7] = b1.w;
    }
    const ushort* base = zxb + ((size_t)(bb * kL)) * kDPROJ + kDI + c8;
    float w0[8], w1[8], w2[8];
    if (l0 == 0) {
#pragma unroll
      for (int c = 0; c < 8; c++) { w0[c] = 0.f; w1[c] = 0.f; w2[c] = 0.f; }
    } else {
      U16x8 a, b, c;
      a.v = *(const int4*)(base + (size_t)(l0 - 3) * kDPROJ);
      b.v = *(const int4*)(base + (size_t)(l0 - 2) * kDPROJ);
      c.v = *(const int4*)(base + (size_t)(l0 - 1) * kDPROJ);
#pragma unroll
      for (int q = 0; q < 8; q++) {
        w0[q] = b2f(a.u[q]); w1[q] = b2f(b.u[q]); w2[q] = b2f(c.u[q]);
      }
    }
    ushort* outp = xcb + (size_t)(bb * kL + l0) * kCDIM + c8;
#pragma unroll
    for (int r = 0; r < 16; r++) {
      U16x8 cu;
      cu.v = *(const int4*)(base + (size_t)(l0 + r) * kDPROJ);
      U16x8 o;
#pragma unroll
      for (int c = 0; c < 8; c++) {
        float cf = b2f(cu.u[c]);
        float a = bias[c] + wt[c][0] * w0[c] + wt[c][1] * w1[c] + wt[c][2] * w2[c] +
                  wt[c][3] * cf;
        o.u[c] = f2b(a / (1.f + __expf(-a)));
        w0[c] = w1[c];
        w1[c] = w2[c];
        w2[c] = cf;
      }
      *(int4*)(outp + (size_t)r * kCDIM) = o.v;
    }
  } else {
    int t = threadIdx.x;
    int c = t & 63;
    int wid = ((int)blockIdx.x - kConvBlocks) * 4 + (t >> 6);
    int h = wid & (kNH - 1);
    int k = (wid >> 4) & (kKC - 1);
    int bb = wid >> 9;
    int dir = bb >> 2;
    int row = bb * kL + k * kCH + c;
    float x = dtraw[(size_t)row * kNH + h] + (dir ? db1 : db0)[h];
    float dtv = (x > 20.f) ? x : log1pf(expf(x));
    dt[(size_t)row * kNH + h] = dtv;
    float A = -__expf((dir ? al1 : al0)[h]);
    float s = dtv * A;
#pragma unroll
    for (int off = 1; off < 64; off <<= 1) {
      float u = __shfl_up(s, off);
      if (c >= off) s += u;
    }
    cs[(size_t)wid * kCH + c] = s;
    if (c == 63) g[wid] = __expf(s);
  }
}

// ---------------- MFMA states: one block per (b,k), wave per head; bf16 out ----------------
__global__ __launch_bounds__(256) void states_kernel(const ushort* __restrict__ xcb,
                                                     const float* __restrict__ dt,
                                                     const float* __restrict__ cs,
                                                     ushort* __restrict__ states) {
  int bk = blockIdx.x;
  int k = bk & (kKC - 1);
  int bb = bk >> 5;
  __shared__ __align__(16) ushort Bstage[64][72];
  __shared__ __align__(16) ushort Bt[64][72];   // Bt[n][j]
  __shared__ __align__(16) ushort Ap[4][32][72];  // per-wave A' = w*xs^T
  __shared__ float w_s[16][64];
  int t = threadIdx.x;
  int lane = t & 63, wv = t >> 6;
  size_t rowbase = (size_t)(bb * kL + k * kCH);
  {
    int j = t >> 2, n0 = (t & 3) * 16;
    const ushort* src = xcb + (rowbase + j) * kCDIM + kDI + n0;
    *(int4*)&Bstage[j][n0] = *(const int4*)src;
    *(int4*)&Bstage[j][n0 + 8] = *(const int4*)(src + 8);
  }
#pragma unroll
  for (int i = 0; i < 4; i++) {
    int e = t + i * 256;
    int h = e >> 6, c = e & 63;
    const float* csb = cs + ((size_t)bk * 16 + h) * kCH;
    w_s[h][c] = __expf(csb[63] - csb[c]) * dt[(rowbase + c) * kNH + h];
  }
  __syncthreads();
#pragma unroll
  for (int i = 0; i < 16; i++) {
    int e = t + i * 256;
    int j = e & 63, n = e >> 6;
    Bt[n][j] = Bstage[j][n];
  }
  __syncthreads();
  int l15 = lane & 15, lk8 = (lane >> 4) * 8;
  for (int hg = 0; hg < 4; hg++) {
    int h = hg * 4 + wv;
    float wl = w_s[h][lane];
    const ushort* xrow = xcb + (rowbase + lane) * kCDIM + h * 32;
#pragma unroll
    for (int q4 = 0; q4 < 4; q4++) {
      U16x8 v;
      v.v = *(const int4*)(xrow + q4 * 8);
#pragma unroll
      for (int q = 0; q < 8; q++)
        Ap[wv][q4 * 8 + q][lane] = f2b(b2f(v.u[q]) * wl);
    }
#pragma unroll
    for (int pt = 0; pt < 2; pt++) {
#pragma unroll
      for (int nt = 0; nt < 4; nt++) {
        f32x4 acc = {0.f, 0.f, 0.f, 0.f};
#pragma unroll
        for (int kt = 0; kt < 2; kt++) {
          bf16x8 a = *(const bf16x8*)&Ap[wv][pt * 16 + l15][kt * 32 + lk8];
          bf16x8 b = *(const bf16x8*)&Bt[nt * 16 + l15][kt * 32 + lk8];
          acc = __builtin_amdgcn_mfma_f32_16x16x32_bf16(a, b, acc, 0, 0, 0);
        }
        size_t base = ((size_t)bk * 16 + h) * 2048;
#pragma unroll
        for (int r = 0; r < 4; r++) {
          int p = pt * 16 + (lane >> 4) * 4 + r;
          states[base + p * 64 + nt * 16 + l15] = f2b(acc[r]);
        }
      }
    }
  }
}

// ---------------- chunk scan (x4 vectorized): sprev=S (bf16); S=g*S+states ----------------
__global__ __launch_bounds__(256) void scan_kernel(const ushort* __restrict__ st,
                                                   const float* __restrict__ g,
                                                   ushort* __restrict__ spbf) {
  int idx = blockIdx.x * 256 + threadIdx.x;
  if (idx >= kBB * kNH * 512) return;
  int pn4 = (idx & 511) * 4;
  int h = (idx >> 9) & (kNH - 1);
  int bb = idx >> 13;
  float S[4] = {0.f, 0.f, 0.f, 0.f};
  for (int k = 0; k < kKC; k++) {
    size_t off = (((size_t)(bb * kKC + k) * kNH + h) * 2048) + pn4;
    ushort4 so = {f2b(S[0]), f2b(S[1]), f2b(S[2]), f2b(S[3])};
    *(ushort4*)&spbf[off] = so;
    ushort4 sv = *(const ushort4*)&st[off];
    float gk = g[(bb * kKC + k) * kNH + h];
    S[0] = gk * S[0] + b2f(sv.x);
    S[1] = gk * S[1] + b2f(sv.y);
    S[2] = gk * S[2] + b2f(sv.z);
    S[3] = gk * S[3] + b2f(sv.w);
  }
}

// ---------------- fused y: per (b,k,half-heads); bf16 out ----------------
__global__ __launch_bounds__(256) void y_kernel(const ushort* __restrict__ xcb,
                                                const float* __restrict__ dt,
                                                const float* __restrict__ cs,
                                                const ushort* __restrict__ spbf,
                                                const float* __restrict__ D0,
                                                const float* __restrict__ D1,
                                                ushort* __restrict__ y) {
  int bid = blockIdx.x;
  int hh = bid & 1;
  int bk = bid >> 1;
  int k = bk & (kKC - 1);
  int bb = bk >> 5;
  int dir = bb >> 2;
  __shared__ __align__(16) ushort Cls[64][72];
  __shared__ __align__(16) ushort Bls[64][72];
  __shared__ float CBT[64][67];  // CBT[j][i] = CB[i][j]
  __shared__ __align__(16) ushort xs_s[64][40];
  __shared__ __align__(16) ushort xsT[32][72];
  __shared__ __align__(16) ushort sp_s[32][72];
  __shared__ float cs_s[64], dt_s[64], ecs_s[64];
  int t = threadIdx.x, lane = t & 63, wv = t >> 6;
  int l15 = lane & 15, lk8 = (lane >> 4) * 8;
  size_t rowbase = (size_t)(bb * kL + k * kCH);
  {
    int j = t >> 2, n0 = (t & 3) * 16;
    const ushort* pB = xcb + (rowbase + j) * kCDIM + kDI;
    *(int4*)&Bls[j][n0] = *(const int4*)(pB + n0);
    *(int4*)&Bls[j][n0 + 8] = *(const int4*)(pB + n0 + 8);
    *(int4*)&Cls[j][n0] = *(const int4*)(pB + kDS + n0);
    *(int4*)&Cls[j][n0 + 8] = *(const int4*)(pB + kDS + n0 + 8);
  }
  __syncthreads();
  {
    int i0 = wv * 16;
#pragma unroll
    for (int jt = 0; jt < 4; jt++) {
      f32x4 acc = {0.f, 0.f, 0.f, 0.f};
#pragma unroll
      for (int kt = 0; kt < 2; kt++) {
        bf16x8 a = *(const bf16x8*)&Cls[i0 + l15][kt * 32 + lk8];
        bf16x8 b = *(const bf16x8*)&Bls[jt * 16 + l15][kt * 32 + lk8];
        acc = __builtin_amdgcn_mfma_f32_16x16x32_bf16(a, b, acc, 0, 0, 0);
      }
#pragma unroll
      for (int r = 0; r < 4; r++)
        CBT[jt * 16 + l15][i0 + (lane >> 4) * 4 + r] = acc[r];
    }
  }
  for (int hi = 0; hi < 8; hi++) {
    int h = hh * 8 + hi;
    int bkh = bk * 16 + h;
    float Dp = (dir ? D1 : D0)[h];
    __syncthreads();
    {
      int j = t >> 2, p0 = (t & 3) * 8;
      U16x8 v;
      v.v = *(const int4*)(xcb + (rowbase + j) * kCDIM + h * 32 + p0);
      *(int4*)&xs_s[j][p0] = v.v;
#pragma unroll
      for (int q = 0; q < 8; q++) xsT[p0 + q][j] = v.u[q];
      int4 s = *(const int4*)(spbf + (size_t)bkh * 2048 + t * 8);
      *(int4*)&sp_s[t >> 3][(t & 7) * 8] = s;
      if (t < 64) {
        float cv = cs[(size_t)bkh * kCH + t];
        cs_s[t] = cv;
        ecs_s[t] = __expf(cv);
        dt_s[t] = dt[(rowbase + t) * kNH + h];
      }
    }
    __syncthreads();
    int i0 = wv * 16;
    int ia = i0 + l15;
    float csi = cs_s[ia];
    U16x8 af[2];
#pragma unroll
    for (int kt = 0; kt < 2; kt++) {
#pragma unroll
      for (int q = 0; q < 8; q++) {
        int j = kt * 32 + lk8 + q;
        float v = 0.f;
        if (j <= ia) v = __expf(csi - cs_s[j]) * dt_s[j] * CBT[j][ia];
        af[kt].u[q] = f2b(v);
      }
    }
#pragma unroll
    for (int pt = 0; pt < 2; pt++) {
      f32x4 acc = {0.f, 0.f, 0.f, 0.f};
      f32x4 acc2 = {0.f, 0.f, 0.f, 0.f};
#pragma unroll
      for (int kt = 0; kt < 2; kt++) {
        bf16x8 bx = *(const bf16x8*)&xsT[pt * 16 + l15][kt * 32 + lk8];
        acc = __builtin_amdgcn_mfma_f32_16x16x32_bf16(af[kt].b, bx, acc, 0, 0, 0);
        bf16x8 ac = *(const bf16x8*)&Cls[i0 + l15][kt * 32 + lk8];
        bf16x8 bs = *(const bf16x8*)&sp_s[pt * 16 + l15][kt * 32 + lk8];
        acc2 = __builtin_amdgcn_mfma_f32_16x16x32_bf16(ac, bs, acc2, 0, 0, 0);
      }
#pragma unroll
      for (int r = 0; r < 4; r++) {
        int io = i0 + (lane >> 4) * 4 + r;
        int p = pt * 16 + l15;
        float xsv = b2f(xs_s[io][p]);
        float v = acc[r] + ecs_s[io] * acc2[r] + Dp * xsv;
        y[(rowbase + io) * kDI + h * 32 + p] = f2b(v);
      }
    }
  }
}

// ---------------- gate+RMSNorm: wave per row; bf16 in/out ----------------
__global__ __launch_bounds__(256) void gate_norm_kernel(const ushort* __restrict__ zxb,
                                                        const float* __restrict__ nw0,
                                                        const float* __restrict__ nw1,
                                                        const ushort* __restrict__ y,
                                                        ushort* __restrict__ ybf) {
  int t = threadIdx.x;
  int lane = t & 63;
  int row = blockIdx.x * 4 + (t >> 6);
  int dir = (row >= kRowsD) ? 1 : 0;
  const float* nw = dir ? nw1 : nw0;
  int e0 = lane * 8;
  U16x8 zu, yu;
  zu.v = *(const int4*)(zxb + (size_t)row * kDPROJ + e0);
  yu.v = *(const int4*)(y + (size_t)row * kDI + e0);
  float v[8];
  float ss = 0.f;
#pragma unroll
  for (int q = 0; q < 8; q++) {
    float z = b2f(zu.u[q]);
    float gz = z / (1.f + __expf(-z));
    v[q] = b2f(yu.u[q]) * gz;
    ss += v[q] * v[q];
  }
#pragma unroll
  for (int o = 32; o > 0; o >>= 1) ss += __shfl_xor(ss, o);
  float scale = rsqrtf(ss * (1.0f / kDI) + 1e-5f);
  float4 n0 = *(const float4*)&nw[e0];
  float4 n1 = *(const float4*)&nw[e0 + 4];
  float na[8] = {n0.x, n0.y, n0.z, n0.w, n1.x, n1.y, n1.z, n1.w};
  U16x8 o;
#pragma unroll
  for (int q = 0; q < 8; q++) o.u[q] = f2b(v[q] * scale * na[q]);
  *(int4*)&ybf[(size_t)row * kDI + e0] = o.v;
}

// ---------------- hcat bf16 ----------------
__global__ __launch_bounds__(256) void concat_kernel(const float* __restrict__ h,
                                                     ushort* __restrict__ hcat) {
  int idx = blockIdx.x * 256 + threadIdx.x;
  if (idx >= 4 * kL * 2 * kDM) return;
  int e = idx & 511;
  int l = (idx >> 9) & (kL - 1);
  int b = idx >> 20;
  float v;
  if (e < kDM)
    v = h[((size_t)(b * kL + l)) * kDM + e];
  else
    v = h[((size_t)((4 + b) * kL + (kL - 1 - l))) * kDM + (e - kDM)];
  hcat[idx] = f2b(v);
}

}  // namespace

extern "C" void kernel_launch(void* const* d_in, const int* in_sizes, int n_in,
                              void* d_out, int out_size, void* d_ws, size_t ws_size,
                              hipStream_t stream) {
  const float* x = (const float*)d_in[0];
  const float* fw_ln_w = (const float*)d_in[1];
  const float* fw_ln_b = (const float*)d_in[2];
  const float* fw_win = (const float*)d_in[3];
  const float* fw_convw = (const float*)d_in[4];
  const float* fw_convb = (const float*)d_in[5];
  const float* fw_alog = (const float*)d_in[6];
  const float* fw_dtb = (const float*)d_in[7];
  const float* fw_D = (const float*)d_in[8];
  const float* fw_nw = (const float*)d_in[9];
  const float* fw_wout = (const float*)d_in[10];
  const float* bw_ln_w = (const float*)d_in[11];
  const float* bw_ln_b = (const float*)d_in[12];
  const float* bw_win = (const float*)d_in[13];
  const float* bw_convw = (const float*)d_in[14];
  const float* bw_convb = (const float*)d_in[15];
  const float* bw_alog = (const float*)d_in[16];
  const float* bw_dtb = (const float*)d_in[17];
  const float* bw_D = (const float*)d_in[18];
  const float* bw_nw = (const float*)d_in[19];
  const float* bw_wout = (const float*)d_in[20];
  const float* fusion_w = (const float*)d_in[21];
  float* out = (float*)d_out;

  float* ws = (float*)d_ws;
  float* h = ws;                                   // 16384*256 f32
  float* dtraw = h + (size_t)kRows * kDM;          // 16384*16 f32
  float* dt = dtraw + (size_t)kRows * kNH;         // 16384*16 f32
  float* cs = dt + (size_t)kRows * kNH;            // 4096*64 f32
  float* g = cs + (size_t)kBB * kKC * kNH * kCH;   // 4096 f32
  ushort* zxb = (ushort*)(g + (size_t)kBB * kKC * kNH);  // 16384*1168 bf16
  ushort* xcb = zxb + (size_t)kRows * kDPROJ;            // 16384*640
  ushort* states = xcb + (size_t)kRows * kCDIM;          // 4096*2048
  ushort* spbf = states + (size_t)kBB * kKC * kNH * 2048;  // 4096*2048
  ushort* ybuf = spbf + (size_t)kBB * kKC * kNH * 2048;    // 16384*512
  ushort* xnbf = ybuf + (size_t)kRows * kDI;               // 16384*256 (also hcat)
  ushort* ybf = xnbf + (size_t)kRows * kDM;                // 16384*512
  ushort* winbf = ybf + (size_t)kRows * kDI;               // 2*8*1168*256
  ushort* woutbf = winbf + (size_t)2 * 8 * kDPROJ * kDM;   // 2*8*256*512
  ushort* fusbf = woutbf + (size_t)2 * 8 * kDM * kDI;      // 256*512
  ushort* hcatbf = xnbf;

  f2b_all_kernel<<<(kQtot + 255) / 256, 256, 0, stream>>>(fw_win, bw_win, fw_wout,
                                                          bw_wout, fusion_w, winbf);
  init_h_kernel<<<(4 * kL * kDM + 255) / 256, 256, 0, stream>>>(x, h);

  for (int i = 0; i < 8; i++) {
    const size_t oLN = (size_t)i * kDM;
    const size_t oCW = (size_t)i * kCDIM * 4;
    const size_t oCB = (size_t)i * kCDIM;
    const size_t oH = (size_t)i * kNH;
    const size_t oNW = (size_t)i * kDI;
    const ushort* win0 = winbf + (size_t)i * kDPROJ * kDM;
    const ushort* win1 = winbf + (size_t)(8 + i) * kDPROJ * kDM;
    const ushort* wout0 = woutbf + (size_t)i * kDM * kDI;
    const ushort* wout1 = woutbf + (size_t)(8 + i) * kDM * kDI;

    ln_kernel<<<kRows / 4, 256, 0, stream>>>(h, fw_ln_w + oLN, fw_ln_b + oLN,
                                             bw_ln_w + oLN, bw_ln_b + oLN, xnbf);
    {
      // 10 n-tiles x 64 m-tiles = 640 blocks per dir (640 % 8 == 0)
      dim3 grid(10 * 64, 1, 2);
      gemm_bf16<<<grid, 256, 0, stream>>>(xnbf, win0, win1, zxb, dtraw, kRowsD,
                                          kDPROJ, kDM, 10);
    }
    {
      int cumsumBlocks = kBB * kKC * kNH / 4;
      conv_cumsum_kernel<<<kConvBlocks + cumsumBlocks, 256, 0, stream>>>(
          zxb, fw_convw + oCW, fw_convb + oCB, bw_convw + oCW, bw_convb + oCB, xcb,
          dtraw, fw_dtb + oH, bw_dtb + oH, fw_alog + oH, bw_alog + oH, dt, cs, g);
    }
    states_kernel<<<kBB * kKC, 256, 0, stream>>>(xcb, dt, cs, states);
    scan_kernel<<<(kBB * kNH * 512 + 255) / 256, 256, 0, stream>>>(states, g, spbf);
    y_kernel<<<kBB * kKC * 2, 256, 0, stream>>>(xcb, dt, cs, spbf, fw_D + oH,
                                                bw_D + oH, ybuf);
    gate_norm_kernel<<<kRows / 4, 256, 0, stream>>>(zxb, fw_nw + oNW, bw_nw + oNW,
                                                    ybuf, ybf);
    {
      // 4 n-tiles x 128 m-tiles = 512 blocks per dir (512 % 8 == 0)
      dim3 grid(4 * 128, 1, 2);
      gemm_bf16_64<<<grid, 256, 0, stream>>>(ybf, wout0, wout1, h, kRowsD, kDM, kDI,
                                             4, 1);
    }
  }

  concat_kernel<<<(4 * kL * 2 * kDM + 255) / 256, 256, 0, stream>>>(h, hcatbf);
  {
    dim3 grid(4 * 128, 1, 1);
    gemm_bf16_64<<<grid, 256, 0, stream>>>(hcatbf, fusbf, fusbf, out, kRowsD, kDM,
                                           2 * kDM, 4, 0);
  }
}